// Round 7
// baseline (556.119 us; speedup 1.0000x reference)
//
#include <hip/hip_runtime.h>
#include <hip/hip_bf16.h>

typedef __hip_bfloat16 bf16;
typedef __attribute__((ext_vector_type(8))) short short8;
typedef __attribute__((ext_vector_type(4))) float f32x4;
typedef __attribute__((ext_vector_type(2))) unsigned uv2;   // nontemporal-compatible
typedef __attribute__((ext_vector_type(4))) unsigned uv4;   // nontemporal-compatible
union V8 { uint4 u; short8 v; };

__device__ __forceinline__ float bf2f(bf16 v) { return __bfloat162float(v); }
__device__ __forceinline__ float lo16(unsigned u) { return __uint_as_float((u & 0xffffu) << 16); }
__device__ __forceinline__ float hi16(unsigned u) { return __uint_as_float(u & 0xffff0000u); }
__device__ __forceinline__ unsigned short f2bfbits(float f) {
    return (unsigned short)(__hip_bfloat16_raw(__float2bfloat16(f)).x);
}
__device__ __forceinline__ unsigned pack2(float a, float b) {
    return (unsigned)f2bfbits(a) | ((unsigned)f2bfbits(b) << 16);
}

// dtype-dispatching loads (flag-driven, uniform branch)
__device__ __forceinline__ float ldf(const void* p, size_t i, bool isbf) {
    return isbf ? bf2f(((const bf16*)p)[i]) : ((const float*)p)[i];
}
__device__ __forceinline__ int ldi(const void* p, size_t i, bool is64) {
    return is64 ? (int)((const long long*)p)[i] : ((const int*)p)[i];
}
__device__ __forceinline__ float sane(float v) {
    return (v == v && fabsf(v) < 1e30f) ? v : 0.f;
}

// nontemporal helpers over HIP vector structs
__device__ __forceinline__ uint2 nt_ld2(const uint2* p) {
    uv2 v = __builtin_nontemporal_load((const uv2*)p);
    return make_uint2(v.x, v.y);
}
__device__ __forceinline__ void nt_st4(uint4* p, uint4 v) {
    uv4 t; t.x = v.x; t.y = v.y; t.z = v.z; t.w = v.w;
    __builtin_nontemporal_store(t, (uv4*)p);
}

// dc[node] packed layout (built by degcntB / legacy degcnt):
//   bits [44:63] : in-degree count (20 bits)
//   bits [ 0:43] : weighted degree, 22.22 unsigned fixed point
// After scan3:
//   bits [44:63] : in-degree count (still valid, for sortk)
//   bits [ 0:31] : dinv as f32 bits  -> readable as ((const float*)dc)[2*node]
#define DC_CNT_SHIFT 44
#define DC_FIX_MASK  0xFFFFFFFFFFFULL
#define DC_FIX_SCALE 4194304.0f   /* 2^22 */

// ---------------- dtype detection ----------------
__global__ void detect(const unsigned* __restrict__ w1w, const unsigned* __restrict__ eiw,
                       int* __restrict__ flags) {
    __shared__ int cnt[2];
    if (threadIdx.x < 2) cnt[threadIdx.x] = 0;
    __syncthreads();
    int c0 = 0;
    for (int i = threadIdx.x; i < 4096; i += 256) {
        unsigned u = w1w[i];
        unsigned e0 = (u >> 7) & 0xFFu, e1 = (u >> 23) & 0xFFu;
        if (e0 <= 125u && e1 <= 125u) c0++;
    }
    int c1 = 0;
    for (int i = threadIdx.x; i < 2048; i += 256)
        if (eiw[2 * i + 1] == 0u) c1++;
    atomicAdd(&cnt[0], c0);
    atomicAdd(&cnt[1], c1);
    __syncthreads();
    if (threadIdx.x == 0) {
        flags[0] = (cnt[0] >= 3072) ? 1 : 0;
        flags[1] = (cnt[1] >= 1024) ? 1 : 0;
    }
}

// ---------------- init: optional dc=1.0, hist=0, bcnt=0 ----------------
__global__ void initk(unsigned long long* __restrict__ dc, int* __restrict__ hist,
                      int* __restrict__ bcnt, int n, int initdc) {
    int i = blockIdx.x * blockDim.x + threadIdx.x;
    if (initdc && i < n) dc[i] = (unsigned long long)(1u << 22);  // deg = 1.0
    if (i < 256) { hist[i] = 0; bcnt[i] = 0; }
}

// ------------- legacy degcnt (fallback path only): one u64 atomic/edge -------
__global__ void degcnt(const void* __restrict__ ei, const void* __restrict__ w,
                       unsigned long long* __restrict__ dc,
                       const int* __restrict__ flags, int e, int n) {
    const bool isbf = flags[0] != 0;
    const bool is64 = flags[1] != 0;
    int i = blockIdx.x * blockDim.x + threadIdx.x;
    if (i < e) {
        int c = ldi(ei, (size_t)e + i, is64);
        if ((unsigned)c < (unsigned)n) {
            float wv = sane(ldf(w, i, isbf));
            wv = fminf(fmaxf(wv, 0.f), 1024.f);   // keep fixed-point in range
            unsigned long long pk = (1ULL << DC_CNT_SHIFT)
                                  + (unsigned long long)llrintf(wv * DC_FIX_SCALE);
            atomicAdd(&dc[c], pk);
        }
    }
}

// ---------------- binA: bin edges by node-bucket, coalesced stage writes -----
__global__ __launch_bounds__(1024) void binA(const void* __restrict__ ei,
                                             const void* __restrict__ w,
                                             int* __restrict__ bcnt,
                                             uint2* __restrict__ stage,
                                             const int* __restrict__ flags,
                                             int e, int n, int k, int cap) {
    __shared__ uint2 recs[4096];
    __shared__ unsigned tgt[4096];
    __shared__ int lh[256], loff[256], lbase[256];
    const bool isbf = flags[0] != 0;
    const bool is64 = flags[1] != 0;
    const int t = threadIdx.x;
    if (t < 256) lh[t] = 0;
    __syncthreads();

    int b_[4], lr_[4], valid_[4];
    uint2 rec_[4];
    const int base = blockIdx.x * 4096;
#pragma unroll
    for (int u = 0; u < 4; ++u) {
        int i = base + u * 1024 + t;
        valid_[u] = 0;
        if (i < e) {
            int r = ldi(ei, (size_t)i, is64);
            int c = ldi(ei, (size_t)e + i, is64);
            if ((unsigned)c < (unsigned)n) {
                bool rv = (unsigned)r < (unsigned)n;
                float wv = rv ? sane(ldf(w, i, isbf)) : 0.f;
                int b = c >> k;
                unsigned cloc = (unsigned)(c - (b << k));
                rec_[u] = make_uint2((cloc << 20) | (rv ? (unsigned)r : 0u),
                                     __float_as_uint(wv));
                b_[u] = b;
                lr_[u] = atomicAdd(&lh[b], 1);
                valid_[u] = 1;
            }
        }
    }
    __syncthreads();

    // exclusive scan of lh -> loff; reserve per-bucket global ranges
    if (t < 256) loff[t] = lh[t];
    __syncthreads();
    for (int off = 1; off < 256; off <<= 1) {
        int v = 0;
        if (t < 256 && t >= off) v = loff[t - off];
        __syncthreads();
        if (t < 256 && t >= off) loff[t] += v;
        __syncthreads();
    }
    if (t < 256) {
        int c = lh[t];
        loff[t] -= c;  // inclusive -> exclusive
        lbase[t] = (c > 0) ? atomicAdd(&bcnt[t], c) : 0;
    }
    __syncthreads();

    // place records grouped by bucket in LDS; remember global target
#pragma unroll
    for (int u = 0; u < 4; ++u)
        if (valid_[u]) {
            int slot = loff[b_[u]] + lr_[u];
            recs[slot] = rec_[u];
            unsigned gi = (unsigned)(lbase[b_[u]] + lr_[u]);
            tgt[slot] = (gi < (unsigned)cap)
                          ? (unsigned)b_[u] * (unsigned)cap + gi
                          : 0xFFFFFFFFu;   // clamp: drop on (impossible) overflow
        }
    __syncthreads();

    // flush: consecutive slots within a bucket-run -> consecutive global addrs
    const int total = loff[255] + lh[255];
    for (int s = t; s < total; s += 1024) {
        unsigned g = tgt[s];
        if (g != 0xFFFFFFFFu) stage[g] = recs[s];
    }
}

// ---------------- degcntB: per-bucket count+degree, zero global atomics ------
__global__ __launch_bounds__(1024) void degcntB(const uint2* __restrict__ stage,
                                                const int* __restrict__ bcnt,
                                                unsigned long long* __restrict__ dc,
                                                int n, int k, int cap) {
    __shared__ unsigned long long dcl[4096];
    const int b  = blockIdx.x;
    const int lo = b << k;
    const int hi = min(n, lo + (1 << k));
    const int bs = hi - lo;
    const int t  = threadIdx.x;
    for (int j = t; j < bs; j += 1024)
        dcl[j] = (unsigned long long)(1u << 22);   // self-loop: deg = 1.0
    __syncthreads();
    const uint2* sb = stage + (size_t)b * cap;
    const int cnt_b = min(bcnt[b], cap);
    for (int s = t; s < cnt_b; s += 1024) {
        uint2 rec = sb[s];
        int cloc  = (int)(rec.x >> 20);
        float wv  = __uint_as_float(rec.y);
        wv = fminf(fmaxf(wv, 0.f), 1024.f);
        unsigned long long pk = (1ULL << DC_CNT_SHIFT)
                              + (unsigned long long)llrintf(wv * DC_FIX_SCALE);
        atomicAdd(&dcl[cloc], pk);                 // LDS atomic, intra-CU
    }
    __syncthreads();
    for (int j = t; j < bs; j += 1024) dc[lo + j] = dcl[j];
}

// ---------------- scans ----------------
__global__ __launch_bounds__(1024) void scan1(const unsigned long long* __restrict__ dc,
                                              int* __restrict__ rp,
                                              int* __restrict__ bsum, int n) {
    __shared__ int s[1024];
    int gid = blockIdx.x * 1024 + threadIdx.x;
    int v = (gid < n) ? (int)(dc[gid] >> DC_CNT_SHIFT) : 0;
    s[threadIdx.x] = v;
    __syncthreads();
    for (int off = 1; off < 1024; off <<= 1) {
        int t = 0;
        if (threadIdx.x >= off) t = s[threadIdx.x - off];
        __syncthreads();
        if (threadIdx.x >= off) s[threadIdx.x] += t;
        __syncthreads();
    }
    if (gid < n) rp[gid] = s[threadIdx.x] - v;
    if (threadIdx.x == 1023) bsum[blockIdx.x] = s[1023];
}

__global__ __launch_bounds__(1024) void scan2(const int* __restrict__ bsum,
                                              int* __restrict__ bsx, int nb) {
    __shared__ int s[1024];
    int v = (threadIdx.x < nb) ? bsum[threadIdx.x] : 0;
    s[threadIdx.x] = v;
    __syncthreads();
    for (int off = 1; off < 1024; off <<= 1) {
        int t = 0;
        if (threadIdx.x >= off) t = s[threadIdx.x - off];
        __syncthreads();
        if (threadIdx.x >= off) s[threadIdx.x] += t;
        __syncthreads();
    }
    if (threadIdx.x < nb) bsx[threadIdx.x] = s[threadIdx.x] - v;
}

// scan3: finalize rowptr, unpack dc -> dinv (repacked into low 32 bits of dc,
// cnt preserved in high bits for sortk), degree histogram via LDS aggregation.
__global__ __launch_bounds__(1024) void scan3(int* __restrict__ rp, int* __restrict__ cursor,
                                              const int* __restrict__ bsx,
                                              unsigned long long* __restrict__ dc,
                                              int* __restrict__ hist,
                                              int n, int e) {
    __shared__ int lh[256];
    const int t = threadIdx.x;
    if (t < 256) lh[t] = 0;
    __syncthreads();
    int i = blockIdx.x * 1024 + t;
    if (i < n) {
        int v = rp[i] + bsx[i >> 10];
        rp[i] = v;
        cursor[i] = v;
        unsigned long long dv = dc[i];
        int c = (int)(dv >> DC_CNT_SHIFT);
        float d = (float)(dv & DC_FIX_MASK) * (1.0f / DC_FIX_SCALE);
        float di = d > 0.f ? rsqrtf(d) : 0.f;
        dc[i] = (dv & ~DC_FIX_MASK) | (unsigned long long)__float_as_uint(di);
        atomicAdd(&lh[min(c, 255)], 1);        // LDS atomic: intra-block aggregate
    }
    __syncthreads();
    if (t < 256) {
        int c = lh[t];
        if (c > 0) atomicAdd(&hist[t], c);     // one global atomic per (block, bin)
    }
    if (i == 0) rp[n] = e;
}

// ---------------- fill CSR: legacy one-pass fallback ----------------
__global__ void fill(const void* __restrict__ ei, const void* __restrict__ w,
                     int* __restrict__ cursor, uint2* __restrict__ epack,
                     const int* __restrict__ flags, int e, int n) {
    const bool isbf = flags[0] != 0;
    const bool is64 = flags[1] != 0;
    int i = blockIdx.x * blockDim.x + threadIdx.x;
    if (i < e) {
        int r = ldi(ei, (size_t)i, is64);
        int c = ldi(ei, (size_t)e + i, is64);
        if ((unsigned)c < (unsigned)n) {
            bool rv = (unsigned)r < (unsigned)n;
            float wv = rv ? sane(ldf(w, i, isbf)) : 0.f;
            int pos = atomicAdd(&cursor[c], 1);
            epack[pos] = make_uint2(rv ? (unsigned)r : 0u, __float_as_uint(wv));
        }
    }
}

// ---------------- fillB: per-bucket placement with LDS cursors ----------------
__global__ __launch_bounds__(1024) void fillB(const int* __restrict__ rp,
                                              const uint2* __restrict__ stage,
                                              const int* __restrict__ bcnt,
                                              uint2* __restrict__ epack,
                                              int n, int k, int cap) {
    __shared__ int ncur[4096];
    const int b  = blockIdx.x;
    const int lo = b << k;
    const int hi = min(n, lo + (1 << k));
    const int t  = threadIdx.x;
    for (int j = t; j < hi - lo; j += 1024) ncur[j] = rp[lo + j];
    __syncthreads();
    const uint2* sb = stage + (size_t)b * cap;
    const int cnt_b = min(bcnt[b], cap);
    for (int s = t; s < cnt_b; s += 1024) {
        uint2 rec = sb[s];
        int cloc  = (int)(rec.x >> 20);
        unsigned r = rec.x & 0xFFFFFu;
        int pos = atomicAdd(&ncur[cloc], 1);
        epack[pos] = make_uint2(r, rec.y);
    }
}

// ---------------- degree-bucket scan ----------------
__global__ void hscan(const int* __restrict__ hist, int* __restrict__ hcur) {
    __shared__ int s[256];
    int v = hist[threadIdx.x];
    s[threadIdx.x] = v;
    __syncthreads();
    for (int off = 1; off < 256; off <<= 1) {
        int t = 0;
        if (threadIdx.x >= off) t = s[threadIdx.x - off];
        __syncthreads();
        if (threadIdx.x >= off) s[threadIdx.x] += t;
        __syncthreads();
    }
    hcur[threadIdx.x] = s[threadIdx.x] - v;  // exclusive
}

// ---------------- counting-sort placement, block-aggregated ----------------
__global__ __launch_bounds__(1024) void sortk(const unsigned long long* __restrict__ dc,
                                              int* __restrict__ hcur,
                                              int* __restrict__ order, int n) {
    __shared__ int lh[256];     // local histogram
    __shared__ int lbase[256];  // global base per bin for this block
    const int t = threadIdx.x;
    for (int b = t; b < 256; b += 1024) lh[b] = 0;
    __syncthreads();
    const int i = blockIdx.x * 1024 + t;
    int b = 0, lrank = 0;
    if (i < n) {
        b = min((int)(dc[i] >> DC_CNT_SHIFT), 255);
        lrank = atomicAdd(&lh[b], 1);  // LDS atomic: intra-block rank
    }
    __syncthreads();
    for (int bb = t; bb < 256; bb += 1024) {
        int c = lh[bb];
        lbase[bb] = (c > 0) ? atomicAdd(&hcur[bb], c) : 0;  // range reservation
    }
    __syncthreads();
    if (i < n) order[lbase[b] + lrank] = i;
}

// ---- layer1 GEMM via MFMA: G1 = bf16(dinv ⊙ (X[n,128] @ W1[128,64])) ----
__global__ __launch_bounds__(256) void gemm1_mfma(const void* __restrict__ x,
                                                  const void* __restrict__ W1,
                                                  const float* __restrict__ dinvp,
                                                  const int* __restrict__ flags,
                                                  unsigned short* __restrict__ G1,
                                                  int n) {
    const bool isbf = flags[0] != 0;
    __shared__ uint4 bfr[16 * 64];  // [ct*4+ks][lane], 16 KB
    for (int idx = threadIdx.x; idx < 16 * 64; idx += 256) {
        int lane = idx & 63, fr = idx >> 6;
        int ct = fr >> 2, ks = fr & 3;
        int k0 = ks * 32 + (lane >> 4) * 8;
        int col = ct * 16 + (lane & 15);
        unsigned short h[8];
#pragma unroll
        for (int j = 0; j < 8; ++j)
            h[j] = f2bfbits(ldf(W1, (size_t)(k0 + j) * 64 + col, isbf));
        bfr[idx] = make_uint4((unsigned)h[0] | ((unsigned)h[1] << 16),
                              (unsigned)h[2] | ((unsigned)h[3] << 16),
                              (unsigned)h[4] | ((unsigned)h[5] << 16),
                              (unsigned)h[6] | ((unsigned)h[7] << 16));
    }
    __syncthreads();

    const int lane = threadIdx.x & 63;
    const int m = lane & 15, q = lane >> 4;
    const int wid = (blockIdx.x * 256 + threadIdx.x) >> 6;
    const int nw  = (gridDim.x * 256) >> 6;
    const int nchunk = (n + 15) >> 4;

    for (int ch = wid; ch < nchunk; ch += nw) {
        const int row0 = ch * 16;
        const int rA = min(row0 + m, n - 1);
        V8 a[4];
        if (isbf) {
            const uint4* xr = (const uint4*)((const bf16*)x + (size_t)rA * 128);
#pragma unroll
            for (int ks = 0; ks < 4; ++ks) a[ks].u = xr[ks * 4 + q];
        } else {
            const float* xr = (const float*)x + (size_t)rA * 128;
#pragma unroll
            for (int ks = 0; ks < 4; ++ks) {
                unsigned short h[8];
#pragma unroll
                for (int j = 0; j < 8; ++j) h[j] = f2bfbits(xr[ks * 32 + q * 8 + j]);
                a[ks].u = make_uint4((unsigned)h[0] | ((unsigned)h[1] << 16),
                                     (unsigned)h[2] | ((unsigned)h[3] << 16),
                                     (unsigned)h[4] | ((unsigned)h[5] << 16),
                                     (unsigned)h[6] | ((unsigned)h[7] << 16));
            }
        }
#pragma unroll
        for (int ct = 0; ct < 4; ++ct) {
            f32x4 acc = {0.f, 0.f, 0.f, 0.f};
#pragma unroll
            for (int ks = 0; ks < 4; ++ks) {
                V8 b; b.u = bfr[(ct * 4 + ks) * 64 + lane];
                acc = __builtin_amdgcn_mfma_f32_16x16x32_bf16(a[ks].v, b.v, acc, 0, 0, 0);
            }
#pragma unroll
            for (int r = 0; r < 4; ++r) {
                int row = row0 + q * 4 + r;
                if (row < n)
                    G1[(size_t)row * 64 + ct * 16 + m] = f2bfbits(dinvp[2 * (size_t)row] * acc[r]);
            }
        }
    }
}

// ---- gather core: 8 lanes/node, uint4/lane, depth-8 + epack prefetch ----
// epack reads are nontemporal (streaming; keep L2 lines for the G-row gathers).
__device__ __forceinline__ void gacc8(const int* __restrict__ rp,
                                      const uint2* __restrict__ epack,
                                      const uint4* __restrict__ Gv,
                                      int node, int sub, float acc[8]) {
    uint4 self = Gv[(size_t)node * 8 + sub];
    acc[0] = lo16(self.x); acc[1] = hi16(self.x);
    acc[2] = lo16(self.y); acc[3] = hi16(self.y);
    acc[4] = lo16(self.z); acc[5] = hi16(self.z);
    acc[6] = lo16(self.w); acc[7] = hi16(self.w);

    const int s0 = rp[node], s1 = rp[node + 1];
    const uint2 fb = make_uint2((unsigned)node, 0u);
    int idx = s0 + sub;
    uint2 ld = (idx < s1) ? nt_ld2(&epack[idx]) : fb;
    for (int base = s0; base < s1; base += 8) {
        int nidx = base + 8 + sub;
        uint2 nld = (nidx < s1) ? nt_ld2(&epack[nidx]) : fb;  // prefetch next batch
        int rr[8]; float wv[8];
#pragma unroll
        for (int u = 0; u < 8; ++u) {
            rr[u] = __shfl((int)ld.x, u, 8);
            wv[u] = __uint_as_float((unsigned)__shfl((int)ld.y, u, 8));
        }
        uint4 gp[8];
#pragma unroll
        for (int u = 0; u < 8; ++u) gp[u] = Gv[(size_t)rr[u] * 8 + sub];
#pragma unroll
        for (int u = 0; u < 8; ++u) {
            acc[0] = fmaf(wv[u], lo16(gp[u].x), acc[0]);
            acc[1] = fmaf(wv[u], hi16(gp[u].x), acc[1]);
            acc[2] = fmaf(wv[u], lo16(gp[u].y), acc[2]);
            acc[3] = fmaf(wv[u], hi16(gp[u].y), acc[3]);
            acc[4] = fmaf(wv[u], lo16(gp[u].z), acc[4]);
            acc[5] = fmaf(wv[u], hi16(gp[u].z), acc[5]);
            acc[6] = fmaf(wv[u], lo16(gp[u].w), acc[6]);
            acc[7] = fmaf(wv[u], hi16(gp[u].w), acc[7]);
        }
        ld = nld;
    }
}

// ---- agg1: acc -> relu/bias/dinv -> G2 ----
__global__ __launch_bounds__(256, 8) void agg1(const int* __restrict__ rp,
                                               const uint2* __restrict__ epack,
                                               const int* __restrict__ order,
                                               const uint4* __restrict__ G1v,
                                               const float* __restrict__ dinvp,
                                               const void* __restrict__ b1,
                                               const int* __restrict__ flags,
                                               uint4* __restrict__ G2v, int n) {
    const bool isbf = flags[0] != 0;
    const int sub = threadIdx.x & 7;
    const int g   = (blockIdx.x * 256 + threadIdx.x) >> 3;
    if (g >= n) return;
    const int node = order[g];

    float acc[8];
    gacc8(rp, epack, G1v, node, sub, acc);

    const float dv = dinvp[2 * (size_t)node];
    unsigned o[4];
#pragma unroll
    for (int t = 0; t < 4; ++t) {
        float h0 = dv * acc[2 * t]     + ldf(b1, 8 * sub + 2 * t, isbf);
        float h1 = dv * acc[2 * t + 1] + ldf(b1, 8 * sub + 2 * t + 1, isbf);
        h0 = h0 > 0.f ? h0 : 0.f;
        h1 = h1 > 0.f ? h1 : 0.f;
        o[t] = pack2(dv * h0, dv * h1);
    }
    nt_st4(&G2v[(size_t)node * 8 + sub], make_uint4(o[0], o[1], o[2], o[3]));
}

// ---- agg2: acc -> T = bf16(dinv * acc) ----
__global__ __launch_bounds__(256, 8) void agg2(const int* __restrict__ rp,
                                               const uint2* __restrict__ epack,
                                               const int* __restrict__ order,
                                               const uint4* __restrict__ G2v,
                                               const float* __restrict__ dinvp,
                                               uint4* __restrict__ Tv, int n) {
    const int sub = threadIdx.x & 7;
    const int g   = (blockIdx.x * 256 + threadIdx.x) >> 3;
    if (g >= n) return;
    const int node = order[g];

    float acc[8];
    gacc8(rp, epack, G2v, node, sub, acc);

    const float dv = dinvp[2 * (size_t)node];
    uint4 o;
    o.x = pack2(dv * acc[0], dv * acc[1]);
    o.y = pack2(dv * acc[2], dv * acc[3]);
    o.z = pack2(dv * acc[4], dv * acc[5]);
    o.w = pack2(dv * acc[6], dv * acc[7]);
    nt_st4(&Tv[(size_t)node * 8 + sub], o);
}

// ---- outgemm via MFMA: out = T[n,64] @ W2[64,128] + b2 ----
__global__ __launch_bounds__(256) void outgemm_mfma(const bf16* __restrict__ T,
                                                    const void* __restrict__ W2,
                                                    const void* __restrict__ b2,
                                                    const int* __restrict__ flags,
                                                    void* __restrict__ outp, int n) {
    const bool isbf = flags[0] != 0;
    __shared__ uint4 bfr[16 * 64];   // [ct*2+ks][lane], 16 KB
    __shared__ float b2s[128];
    for (int idx = threadIdx.x; idx < 16 * 64; idx += 256) {
        int lane = idx & 63, fr = idx >> 6;
        int ct = fr >> 1, ks = fr & 1;
        int k0 = ks * 32 + (lane >> 4) * 8;
        int col = ct * 16 + (lane & 15);
        unsigned short h[8];
#pragma unroll
        for (int j = 0; j < 8; ++j)
            h[j] = f2bfbits(ldf(W2, (size_t)(k0 + j) * 128 + col, isbf));
        bfr[idx] = make_uint4((unsigned)h[0] | ((unsigned)h[1] << 16),
                              (unsigned)h[2] | ((unsigned)h[3] << 16),
                              (unsigned)h[4] | ((unsigned)h[5] << 16),
                              (unsigned)h[6] | ((unsigned)h[7] << 16));
    }
    for (int i = threadIdx.x; i < 128; i += 256) b2s[i] = ldf(b2, i, isbf);
    __syncthreads();

    const int lane = threadIdx.x & 63;
    const int m = lane & 15, q = lane >> 4;
    const int wid = (blockIdx.x * 256 + threadIdx.x) >> 6;
    const int nw  = (gridDim.x * 256) >> 6;
    const int nchunk = (n + 15) >> 4;

    for (int ch = wid; ch < nchunk; ch += nw) {
        const int row0 = ch * 16;
        const int rA = min(row0 + m, n - 1);
        const uint4* tr = (const uint4*)(T + (size_t)rA * 64);
        V8 a[2];
        a[0].u = tr[q];        // k = 0*32 + q*8 + j
        a[1].u = tr[4 + q];    // k = 32 + q*8 + j
#pragma unroll
        for (int ct = 0; ct < 8; ++ct) {
            f32x4 acc = {0.f, 0.f, 0.f, 0.f};
#pragma unroll
            for (int ks = 0; ks < 2; ++ks) {
                V8 b; b.u = bfr[(ct * 2 + ks) * 64 + lane];
                acc = __builtin_amdgcn_mfma_f32_16x16x32_bf16(a[ks].v, b.v, acc, 0, 0, 0);
            }
            const int col = ct * 16 + m;
            const float bb = b2s[col];
#pragma unroll
            for (int r = 0; r < 4; ++r) {
                int row = row0 + q * 4 + r;
                if (row < n) {
                    float o = acc[r] + bb;
                    if (isbf) ((bf16*)outp)[(size_t)row * 128 + col] = __float2bfloat16(o);
                    else      ((float*)outp)[(size_t)row * 128 + col] = o;
                }
            }
        }
    }
}

extern "C" void kernel_launch(void* const* d_in, const int* in_sizes, int n_in,
                              void* d_out, int out_size, void* d_ws, size_t ws_size,
                              hipStream_t stream) {
    const void* x  = d_in[0];
    const void* ei = d_in[1];
    const void* ew = d_in[2];
    const void* W1 = d_in[3];
    const void* b1 = d_in[4];
    const void* W2 = d_in[5];
    const void* b2 = d_in[6];

    const int n = in_sizes[0] / 128;   // 100000
    const int e = in_sizes[2];         // 1600000
    const int nb = (n + 1023) / 1024;

    // ws layout (4B words) -- identical footprint to the round-4 passing build:
    // flags(8) | dc(2n, u64) | rp(n+1) | cursor(n) | bsum(1024) | bsx(1024)
    // | pad | epack(2e) | G1/T(32n) | G2(32n)
    // aliases: hist = bsum+512, hcur = bsx+512, bcnt = bsx+256;
    //          order = cursor (dead after fillB); stage = G1 region (G1+G2).
    int*   flags  = (int*)d_ws;
    unsigned long long* dc = (unsigned long long*)((int*)d_ws + 8);
    int*   rp     = (int*)d_ws + 8 + 2 * (size_t)n;
    int*   cursor = rp + n + 1;
    int*   bsum   = cursor + n;
    int*   bsx    = bsum + 1024;
    int*   hist   = bsum + 512;
    int*   hcur   = bsx + 512;
    int*   bcnt   = bsx + 256;
    int*   order  = cursor;                      // alias, valid post-fill
    size_t w_off  = (size_t)(8 + 4 * (size_t)n + 1 + 2048);
    w_off = (w_off + 3) & ~(size_t)3;            // 16B align
    uint2*    epack = (uint2*)((int*)d_ws + w_off);
    size_t g_off = w_off + 2 * (size_t)e;
    g_off = (g_off + 3) & ~(size_t)3;
    unsigned* G1 = (unsigned*)d_ws + g_off;      // 32n uints (bf16x2), 16B aligned
    unsigned* G2 = G1 + (size_t)n * 32;

    const float* dinvp = (const float*)dc;       // dinv at dinvp[2*node] after scan3
    uint2* stage = (uint2*)G1;                   // alias: G1+G2, dead until gemm1

    // bucket parameters: bucket = 2^k node range, beff buckets (<=256)
    int bs0 = (n + 255) / 256;
    int k = 0;
    while ((1 << k) < bs0) ++k;
    int beff = (n + (1 << k) - 1) >> k;          // <= 256
    int cap  = (int)((32 * (size_t)n) / (size_t)beff);   // stage records/bucket
    size_t mean = ((size_t)e + beff - 1) / beff;
    bool fastfill = (n <= (1 << 18)) && (k <= 12) &&
                    ((size_t)cap >= mean + mean / 2 + 1024);

    detect<<<1, 256, 0, stream>>>((const unsigned*)W1, (const unsigned*)ei, flags);
    initk<<<(n + 255) / 256, 256, 0, stream>>>(dc, hist, bcnt, n, fastfill ? 0 : 1);
    if (fastfill) {
        binA<<<(e + 4095) / 4096, 1024, 0, stream>>>(ei, ew, bcnt, stage, flags, e, n, k, cap);
        degcntB<<<beff, 1024, 0, stream>>>(stage, bcnt, dc, n, k, cap);
    } else {
        degcnt<<<(e + 255) / 256, 256, 0, stream>>>(ei, ew, dc, flags, e, n);
    }
    scan1<<<nb, 1024, 0, stream>>>(dc, rp, bsum, n);
    scan2<<<1, 1024, 0, stream>>>(bsum, bsx, nb);
    scan3<<<nb, 1024, 0, stream>>>(rp, cursor, bsx, dc, hist, n, e);
    if (fastfill) {
        fillB<<<beff, 1024, 0, stream>>>(rp, stage, bcnt, epack, n, k, cap);
    } else {
        fill<<<(e + 255) / 256, 256, 0, stream>>>(ei, ew, cursor, epack, flags, e, n);
    }
    hscan<<<1, 256, 0, stream>>>(hist, hcur);
    sortk<<<nb, 1024, 0, stream>>>(dc, hcur, order, n);

    gemm1_mfma<<<192, 256, 0, stream>>>(x, W1, dinvp, flags, (unsigned short*)G1, n);
    agg1<<<(n * 8 + 255) / 256, 256, 0, stream>>>(rp, epack, order, (const uint4*)G1,
                                                  dinvp, b1, flags, (uint4*)G2, n);
    agg2<<<(n * 8 + 255) / 256, 256, 0, stream>>>(rp, epack, order, (const uint4*)G2,
                                                  dinvp, (uint4*)G1, n);
    outgemm_mfma<<<192, 256, 0, stream>>>((const bf16*)G1, W2, b2, flags, d_out, n);
}

// Round 8
// 369.496 us; speedup vs baseline: 1.5051x; 1.5051x over previous
//
#include <hip/hip_runtime.h>
#include <hip/hip_bf16.h>

typedef __hip_bfloat16 bf16;
typedef __attribute__((ext_vector_type(8))) short short8;
typedef __attribute__((ext_vector_type(4))) float f32x4;
typedef __attribute__((ext_vector_type(2))) unsigned uv2;   // nontemporal-compatible
typedef __attribute__((ext_vector_type(4))) unsigned uv4;   // nontemporal-compatible
union V8 { uint4 u; short8 v; };

__device__ __forceinline__ float bf2f(bf16 v) { return __bfloat162float(v); }
__device__ __forceinline__ float lo16(unsigned u) { return __uint_as_float((u & 0xffffu) << 16); }
__device__ __forceinline__ float hi16(unsigned u) { return __uint_as_float(u & 0xffff0000u); }
__device__ __forceinline__ unsigned short f2bfbits(float f) {
    return (unsigned short)(__hip_bfloat16_raw(__float2bfloat16(f)).x);
}
__device__ __forceinline__ unsigned pack2(float a, float b) {
    return (unsigned)f2bfbits(a) | ((unsigned)f2bfbits(b) << 16);
}

// dtype-dispatching loads (flag-driven, uniform branch)
__device__ __forceinline__ float ldf(const void* p, size_t i, bool isbf) {
    return isbf ? bf2f(((const bf16*)p)[i]) : ((const float*)p)[i];
}
__device__ __forceinline__ int ldi(const void* p, size_t i, bool is64) {
    return is64 ? (int)((const long long*)p)[i] : ((const int*)p)[i];
}
__device__ __forceinline__ float sane(float v) {
    return (v == v && fabsf(v) < 1e30f) ? v : 0.f;
}

// nontemporal helpers over HIP vector structs
__device__ __forceinline__ uint2 nt_ld2(const uint2* p) {
    uv2 v = __builtin_nontemporal_load((const uv2*)p);
    return make_uint2(v.x, v.y);
}
__device__ __forceinline__ void nt_st4(uint4* p, uint4 v) {
    uv4 t; t.x = v.x; t.y = v.y; t.z = v.z; t.w = v.w;
    __builtin_nontemporal_store(t, (uv4*)p);
}

// dc[node] packed layout (built by degcntB / legacy degcnt):
//   bits [44:63] : in-degree count (20 bits)
//   bits [ 0:43] : weighted degree, 22.22 unsigned fixed point
// After scan3:
//   bits [44:63] : in-degree count (still valid, for sortk)
//   bits [ 0:31] : dinv as f32 bits  -> readable as ((const float*)dc)[2*node]
#define DC_CNT_SHIFT 44
#define DC_FIX_MASK  0xFFFFFFFFFFFULL
#define DC_FIX_SCALE 4194304.0f   /* 2^22 */

// ---------------- dtype detection ----------------
__global__ void detect(const unsigned* __restrict__ w1w, const unsigned* __restrict__ eiw,
                       int* __restrict__ flags) {
    __shared__ int cnt[2];
    if (threadIdx.x < 2) cnt[threadIdx.x] = 0;
    __syncthreads();
    int c0 = 0;
    for (int i = threadIdx.x; i < 4096; i += 256) {
        unsigned u = w1w[i];
        unsigned e0 = (u >> 7) & 0xFFu, e1 = (u >> 23) & 0xFFu;
        if (e0 <= 125u && e1 <= 125u) c0++;
    }
    int c1 = 0;
    for (int i = threadIdx.x; i < 2048; i += 256)
        if (eiw[2 * i + 1] == 0u) c1++;
    atomicAdd(&cnt[0], c0);
    atomicAdd(&cnt[1], c1);
    __syncthreads();
    if (threadIdx.x == 0) {
        flags[0] = (cnt[0] >= 3072) ? 1 : 0;
        flags[1] = (cnt[1] >= 1024) ? 1 : 0;
    }
}

// ---------------- init: optional dc=1.0, hist=0, bcnt=0 ----------------
__global__ void initk(unsigned long long* __restrict__ dc, int* __restrict__ hist,
                      int* __restrict__ bcnt, int n, int initdc) {
    int i = blockIdx.x * blockDim.x + threadIdx.x;
    if (initdc && i < n) dc[i] = (unsigned long long)(1u << 22);  // deg = 1.0
    if (i < 256) { hist[i] = 0; bcnt[i] = 0; }
}

// ------------- legacy degcnt (fallback path only): one u64 atomic/edge -------
__global__ void degcnt(const void* __restrict__ ei, const void* __restrict__ w,
                       unsigned long long* __restrict__ dc,
                       const int* __restrict__ flags, int e, int n) {
    const bool isbf = flags[0] != 0;
    const bool is64 = flags[1] != 0;
    int i = blockIdx.x * blockDim.x + threadIdx.x;
    if (i < e) {
        int c = ldi(ei, (size_t)e + i, is64);
        if ((unsigned)c < (unsigned)n) {
            float wv = sane(ldf(w, i, isbf));
            wv = fminf(fmaxf(wv, 0.f), 1024.f);   // keep fixed-point in range
            unsigned long long pk = (1ULL << DC_CNT_SHIFT)
                                  + (unsigned long long)llrintf(wv * DC_FIX_SCALE);
            atomicAdd(&dc[c], pk);
        }
    }
}

// ---------------- binA: bin edges by node-bucket, coalesced stage writes -----
__global__ __launch_bounds__(1024) void binA(const void* __restrict__ ei,
                                             const void* __restrict__ w,
                                             int* __restrict__ bcnt,
                                             uint2* __restrict__ stage,
                                             const int* __restrict__ flags,
                                             int e, int n, int k, int cap) {
    __shared__ uint2 recs[4096];
    __shared__ unsigned tgt[4096];
    __shared__ int lh[256], loff[256], lbase[256];
    const bool isbf = flags[0] != 0;
    const bool is64 = flags[1] != 0;
    const int t = threadIdx.x;
    if (t < 256) lh[t] = 0;
    __syncthreads();

    int b_[4], lr_[4], valid_[4];
    uint2 rec_[4];
    const int base = blockIdx.x * 4096;
#pragma unroll
    for (int u = 0; u < 4; ++u) {
        int i = base + u * 1024 + t;
        valid_[u] = 0;
        if (i < e) {
            int r = ldi(ei, (size_t)i, is64);
            int c = ldi(ei, (size_t)e + i, is64);
            if ((unsigned)c < (unsigned)n) {
                bool rv = (unsigned)r < (unsigned)n;
                float wv = rv ? sane(ldf(w, i, isbf)) : 0.f;
                int b = c >> k;
                unsigned cloc = (unsigned)(c - (b << k));
                rec_[u] = make_uint2((cloc << 20) | (rv ? (unsigned)r : 0u),
                                     __float_as_uint(wv));
                b_[u] = b;
                lr_[u] = atomicAdd(&lh[b], 1);
                valid_[u] = 1;
            }
        }
    }
    __syncthreads();

    // exclusive scan of lh -> loff; reserve per-bucket global ranges
    if (t < 256) loff[t] = lh[t];
    __syncthreads();
    for (int off = 1; off < 256; off <<= 1) {
        int v = 0;
        if (t < 256 && t >= off) v = loff[t - off];
        __syncthreads();
        if (t < 256 && t >= off) loff[t] += v;
        __syncthreads();
    }
    if (t < 256) {
        int c = lh[t];
        loff[t] -= c;  // inclusive -> exclusive
        lbase[t] = (c > 0) ? atomicAdd(&bcnt[t], c) : 0;
    }
    __syncthreads();

    // place records grouped by bucket in LDS; remember global target
#pragma unroll
    for (int u = 0; u < 4; ++u)
        if (valid_[u]) {
            int slot = loff[b_[u]] + lr_[u];
            recs[slot] = rec_[u];
            unsigned gi = (unsigned)(lbase[b_[u]] + lr_[u]);
            tgt[slot] = (gi < (unsigned)cap)
                          ? (unsigned)b_[u] * (unsigned)cap + gi
                          : 0xFFFFFFFFu;   // clamp: drop on (impossible) overflow
        }
    __syncthreads();

    // flush: consecutive slots within a bucket-run -> consecutive global addrs
    const int total = loff[255] + lh[255];
    for (int s = t; s < total; s += 1024) {
        unsigned g = tgt[s];
        if (g != 0xFFFFFFFFu) stage[g] = recs[s];
    }
}

// ---------------- degcntB: per-bucket count+degree, zero global atomics ------
__global__ __launch_bounds__(1024) void degcntB(const uint2* __restrict__ stage,
                                                const int* __restrict__ bcnt,
                                                unsigned long long* __restrict__ dc,
                                                int n, int k, int cap) {
    __shared__ unsigned long long dcl[4096];
    const int b  = blockIdx.x;
    const int lo = b << k;
    const int hi = min(n, lo + (1 << k));
    const int bs = hi - lo;
    const int t  = threadIdx.x;
    for (int j = t; j < bs; j += 1024)
        dcl[j] = (unsigned long long)(1u << 22);   // self-loop: deg = 1.0
    __syncthreads();
    const uint2* sb = stage + (size_t)b * cap;
    const int cnt_b = min(bcnt[b], cap);
    for (int s = t; s < cnt_b; s += 1024) {
        uint2 rec = sb[s];
        int cloc  = (int)(rec.x >> 20);
        float wv  = __uint_as_float(rec.y);
        wv = fminf(fmaxf(wv, 0.f), 1024.f);
        unsigned long long pk = (1ULL << DC_CNT_SHIFT)
                              + (unsigned long long)llrintf(wv * DC_FIX_SCALE);
        atomicAdd(&dcl[cloc], pk);                 // LDS atomic, intra-CU
    }
    __syncthreads();
    for (int j = t; j < bs; j += 1024) dc[lo + j] = dcl[j];
}

// ---------------- scans ----------------
__global__ __launch_bounds__(1024) void scan1(const unsigned long long* __restrict__ dc,
                                              int* __restrict__ rp,
                                              int* __restrict__ bsum, int n) {
    __shared__ int s[1024];
    int gid = blockIdx.x * 1024 + threadIdx.x;
    int v = (gid < n) ? (int)(dc[gid] >> DC_CNT_SHIFT) : 0;
    s[threadIdx.x] = v;
    __syncthreads();
    for (int off = 1; off < 1024; off <<= 1) {
        int t = 0;
        if (threadIdx.x >= off) t = s[threadIdx.x - off];
        __syncthreads();
        if (threadIdx.x >= off) s[threadIdx.x] += t;
        __syncthreads();
    }
    if (gid < n) rp[gid] = s[threadIdx.x] - v;
    if (threadIdx.x == 1023) bsum[blockIdx.x] = s[1023];
}

__global__ __launch_bounds__(1024) void scan2(const int* __restrict__ bsum,
                                              int* __restrict__ bsx, int nb) {
    __shared__ int s[1024];
    int v = (threadIdx.x < nb) ? bsum[threadIdx.x] : 0;
    s[threadIdx.x] = v;
    __syncthreads();
    for (int off = 1; off < 1024; off <<= 1) {
        int t = 0;
        if (threadIdx.x >= off) t = s[threadIdx.x - off];
        __syncthreads();
        if (threadIdx.x >= off) s[threadIdx.x] += t;
        __syncthreads();
    }
    if (threadIdx.x < nb) bsx[threadIdx.x] = s[threadIdx.x] - v;
}

// scan3: finalize rowptr, unpack dc -> dinv (repacked into low 32 bits of dc,
// cnt preserved in high bits for sortk), degree histogram via LDS aggregation.
__global__ __launch_bounds__(1024) void scan3(int* __restrict__ rp, int* __restrict__ cursor,
                                              const int* __restrict__ bsx,
                                              unsigned long long* __restrict__ dc,
                                              int* __restrict__ hist,
                                              int n, int e) {
    __shared__ int lh[256];
    const int t = threadIdx.x;
    if (t < 256) lh[t] = 0;
    __syncthreads();
    int i = blockIdx.x * 1024 + t;
    if (i < n) {
        int v = rp[i] + bsx[i >> 10];
        rp[i] = v;
        cursor[i] = v;
        unsigned long long dv = dc[i];
        int c = (int)(dv >> DC_CNT_SHIFT);
        float d = (float)(dv & DC_FIX_MASK) * (1.0f / DC_FIX_SCALE);
        float di = d > 0.f ? rsqrtf(d) : 0.f;
        dc[i] = (dv & ~DC_FIX_MASK) | (unsigned long long)__float_as_uint(di);
        atomicAdd(&lh[min(c, 255)], 1);        // LDS atomic: intra-block aggregate
    }
    __syncthreads();
    if (t < 256) {
        int c = lh[t];
        if (c > 0) atomicAdd(&hist[t], c);     // one global atomic per (block, bin)
    }
    if (i == 0) rp[n] = e;
}

// ---------------- fill CSR: legacy one-pass fallback ----------------
__global__ void fill(const void* __restrict__ ei, const void* __restrict__ w,
                     int* __restrict__ cursor, uint2* __restrict__ epack,
                     const int* __restrict__ flags, int e, int n) {
    const bool isbf = flags[0] != 0;
    const bool is64 = flags[1] != 0;
    int i = blockIdx.x * blockDim.x + threadIdx.x;
    if (i < e) {
        int r = ldi(ei, (size_t)i, is64);
        int c = ldi(ei, (size_t)e + i, is64);
        if ((unsigned)c < (unsigned)n) {
            bool rv = (unsigned)r < (unsigned)n;
            float wv = rv ? sane(ldf(w, i, isbf)) : 0.f;
            int pos = atomicAdd(&cursor[c], 1);
            epack[pos] = make_uint2(rv ? (unsigned)r : 0u, __float_as_uint(wv));
        }
    }
}

// ---------------- fillB: per-bucket placement with LDS cursors ----------------
__global__ __launch_bounds__(1024) void fillB(const int* __restrict__ rp,
                                              const uint2* __restrict__ stage,
                                              const int* __restrict__ bcnt,
                                              uint2* __restrict__ epack,
                                              int n, int k, int cap) {
    __shared__ int ncur[4096];
    const int b  = blockIdx.x;
    const int lo = b << k;
    const int hi = min(n, lo + (1 << k));
    const int t  = threadIdx.x;
    for (int j = t; j < hi - lo; j += 1024) ncur[j] = rp[lo + j];
    __syncthreads();
    const uint2* sb = stage + (size_t)b * cap;
    const int cnt_b = min(bcnt[b], cap);
    for (int s = t; s < cnt_b; s += 1024) {
        uint2 rec = sb[s];
        int cloc  = (int)(rec.x >> 20);
        unsigned r = rec.x & 0xFFFFFu;
        int pos = atomicAdd(&ncur[cloc], 1);
        epack[pos] = make_uint2(r, rec.y);
    }
}

// ---------------- degree-bucket scan ----------------
__global__ void hscan(const int* __restrict__ hist, int* __restrict__ hcur) {
    __shared__ int s[256];
    int v = hist[threadIdx.x];
    s[threadIdx.x] = v;
    __syncthreads();
    for (int off = 1; off < 256; off <<= 1) {
        int t = 0;
        if (threadIdx.x >= off) t = s[threadIdx.x - off];
        __syncthreads();
        if (threadIdx.x >= off) s[threadIdx.x] += t;
        __syncthreads();
    }
    hcur[threadIdx.x] = s[threadIdx.x] - v;  // exclusive
}

// ---------------- counting-sort placement, block-aggregated ----------------
__global__ __launch_bounds__(1024) void sortk(const unsigned long long* __restrict__ dc,
                                              int* __restrict__ hcur,
                                              int* __restrict__ order, int n) {
    __shared__ int lh[256];     // local histogram
    __shared__ int lbase[256];  // global base per bin for this block
    const int t = threadIdx.x;
    for (int b = t; b < 256; b += 1024) lh[b] = 0;
    __syncthreads();
    const int i = blockIdx.x * 1024 + t;
    int b = 0, lrank = 0;
    if (i < n) {
        b = min((int)(dc[i] >> DC_CNT_SHIFT), 255);
        lrank = atomicAdd(&lh[b], 1);  // LDS atomic: intra-block rank
    }
    __syncthreads();
    for (int bb = t; bb < 256; bb += 1024) {
        int c = lh[bb];
        lbase[bb] = (c > 0) ? atomicAdd(&hcur[bb], c) : 0;  // range reservation
    }
    __syncthreads();
    if (i < n) order[lbase[b] + lrank] = i;
}

// ---- layer1 GEMM via MFMA: G1 = bf16(dinv ⊙ (X[n,128] @ W1[128,64])) ----
__global__ __launch_bounds__(256) void gemm1_mfma(const void* __restrict__ x,
                                                  const void* __restrict__ W1,
                                                  const float* __restrict__ dinvp,
                                                  const int* __restrict__ flags,
                                                  unsigned short* __restrict__ G1,
                                                  int n) {
    const bool isbf = flags[0] != 0;
    __shared__ uint4 bfr[16 * 64];  // [ct*4+ks][lane], 16 KB
    for (int idx = threadIdx.x; idx < 16 * 64; idx += 256) {
        int lane = idx & 63, fr = idx >> 6;
        int ct = fr >> 2, ks = fr & 3;
        int k0 = ks * 32 + (lane >> 4) * 8;
        int col = ct * 16 + (lane & 15);
        unsigned short h[8];
#pragma unroll
        for (int j = 0; j < 8; ++j)
            h[j] = f2bfbits(ldf(W1, (size_t)(k0 + j) * 64 + col, isbf));
        bfr[idx] = make_uint4((unsigned)h[0] | ((unsigned)h[1] << 16),
                              (unsigned)h[2] | ((unsigned)h[3] << 16),
                              (unsigned)h[4] | ((unsigned)h[5] << 16),
                              (unsigned)h[6] | ((unsigned)h[7] << 16));
    }
    __syncthreads();

    const int lane = threadIdx.x & 63;
    const int m = lane & 15, q = lane >> 4;
    const int wid = (blockIdx.x * 256 + threadIdx.x) >> 6;
    const int nw  = (gridDim.x * 256) >> 6;
    const int nchunk = (n + 15) >> 4;

    for (int ch = wid; ch < nchunk; ch += nw) {
        const int row0 = ch * 16;
        const int rA = min(row0 + m, n - 1);
        V8 a[4];
        if (isbf) {
            const uint4* xr = (const uint4*)((const bf16*)x + (size_t)rA * 128);
#pragma unroll
            for (int ks = 0; ks < 4; ++ks) a[ks].u = xr[ks * 4 + q];
        } else {
            const float* xr = (const float*)x + (size_t)rA * 128;
#pragma unroll
            for (int ks = 0; ks < 4; ++ks) {
                unsigned short h[8];
#pragma unroll
                for (int j = 0; j < 8; ++j) h[j] = f2bfbits(xr[ks * 32 + q * 8 + j]);
                a[ks].u = make_uint4((unsigned)h[0] | ((unsigned)h[1] << 16),
                                     (unsigned)h[2] | ((unsigned)h[3] << 16),
                                     (unsigned)h[4] | ((unsigned)h[5] << 16),
                                     (unsigned)h[6] | ((unsigned)h[7] << 16));
            }
        }
#pragma unroll
        for (int ct = 0; ct < 4; ++ct) {
            f32x4 acc = {0.f, 0.f, 0.f, 0.f};
#pragma unroll
            for (int ks = 0; ks < 4; ++ks) {
                V8 b; b.u = bfr[(ct * 4 + ks) * 64 + lane];
                acc = __builtin_amdgcn_mfma_f32_16x16x32_bf16(a[ks].v, b.v, acc, 0, 0, 0);
            }
#pragma unroll
            for (int r = 0; r < 4; ++r) {
                int row = row0 + q * 4 + r;
                if (row < n)
                    G1[(size_t)row * 64 + ct * 16 + m] = f2bfbits(dinvp[2 * (size_t)row] * acc[r]);
            }
        }
    }
}

// ---- gather core: 8 lanes/node, uint4/lane, depth-8 + epack prefetch ----
// epack reads are nontemporal (streaming; keep L2 lines for the G-row gathers).
__device__ __forceinline__ void gacc8(const int* __restrict__ rp,
                                      const uint2* __restrict__ epack,
                                      const uint4* __restrict__ Gv,
                                      int node, int sub, float acc[8]) {
    uint4 self = Gv[(size_t)node * 8 + sub];
    acc[0] = lo16(self.x); acc[1] = hi16(self.x);
    acc[2] = lo16(self.y); acc[3] = hi16(self.y);
    acc[4] = lo16(self.z); acc[5] = hi16(self.z);
    acc[6] = lo16(self.w); acc[7] = hi16(self.w);

    const int s0 = rp[node], s1 = rp[node + 1];
    const uint2 fb = make_uint2((unsigned)node, 0u);
    int idx = s0 + sub;
    uint2 ld = (idx < s1) ? nt_ld2(&epack[idx]) : fb;
    for (int base = s0; base < s1; base += 8) {
        int nidx = base + 8 + sub;
        uint2 nld = (nidx < s1) ? nt_ld2(&epack[nidx]) : fb;  // prefetch next batch
        int rr[8]; float wv[8];
#pragma unroll
        for (int u = 0; u < 8; ++u) {
            rr[u] = __shfl((int)ld.x, u, 8);
            wv[u] = __uint_as_float((unsigned)__shfl((int)ld.y, u, 8));
        }
        uint4 gp[8];
#pragma unroll
        for (int u = 0; u < 8; ++u) gp[u] = Gv[(size_t)rr[u] * 8 + sub];
#pragma unroll
        for (int u = 0; u < 8; ++u) {
            acc[0] = fmaf(wv[u], lo16(gp[u].x), acc[0]);
            acc[1] = fmaf(wv[u], hi16(gp[u].x), acc[1]);
            acc[2] = fmaf(wv[u], lo16(gp[u].y), acc[2]);
            acc[3] = fmaf(wv[u], hi16(gp[u].y), acc[3]);
            acc[4] = fmaf(wv[u], lo16(gp[u].z), acc[4]);
            acc[5] = fmaf(wv[u], hi16(gp[u].z), acc[5]);
            acc[6] = fmaf(wv[u], lo16(gp[u].w), acc[6]);
            acc[7] = fmaf(wv[u], hi16(gp[u].w), acc[7]);
        }
        ld = nld;
    }
}

// ---- agg1: acc -> relu/bias/dinv -> G2 ----
// NOTE: (256,4) NOT (256,8) -- the tighter bound forces VGPR<=64 and spills
// gp[8] to scratch (round 7: VGPR 56->32, +410MB scratch traffic, 2.5x slower).
__global__ __launch_bounds__(256, 4) void agg1(const int* __restrict__ rp,
                                               const uint2* __restrict__ epack,
                                               const int* __restrict__ order,
                                               const uint4* __restrict__ G1v,
                                               const float* __restrict__ dinvp,
                                               const void* __restrict__ b1,
                                               const int* __restrict__ flags,
                                               uint4* __restrict__ G2v, int n) {
    const bool isbf = flags[0] != 0;
    const int sub = threadIdx.x & 7;
    const int g   = (blockIdx.x * 256 + threadIdx.x) >> 3;
    if (g >= n) return;
    const int node = order[g];

    float acc[8];
    gacc8(rp, epack, G1v, node, sub, acc);

    const float dv = dinvp[2 * (size_t)node];
    unsigned o[4];
#pragma unroll
    for (int t = 0; t < 4; ++t) {
        float h0 = dv * acc[2 * t]     + ldf(b1, 8 * sub + 2 * t, isbf);
        float h1 = dv * acc[2 * t + 1] + ldf(b1, 8 * sub + 2 * t + 1, isbf);
        h0 = h0 > 0.f ? h0 : 0.f;
        h1 = h1 > 0.f ? h1 : 0.f;
        o[t] = pack2(dv * h0, dv * h1);
    }
    nt_st4(&G2v[(size_t)node * 8 + sub], make_uint4(o[0], o[1], o[2], o[3]));
}

// ---- agg2: acc -> T = bf16(dinv * acc) ----
__global__ __launch_bounds__(256, 4) void agg2(const int* __restrict__ rp,
                                               const uint2* __restrict__ epack,
                                               const int* __restrict__ order,
                                               const uint4* __restrict__ G2v,
                                               const float* __restrict__ dinvp,
                                               uint4* __restrict__ Tv, int n) {
    const int sub = threadIdx.x & 7;
    const int g   = (blockIdx.x * 256 + threadIdx.x) >> 3;
    if (g >= n) return;
    const int node = order[g];

    float acc[8];
    gacc8(rp, epack, G2v, node, sub, acc);

    const float dv = dinvp[2 * (size_t)node];
    uint4 o;
    o.x = pack2(dv * acc[0], dv * acc[1]);
    o.y = pack2(dv * acc[2], dv * acc[3]);
    o.z = pack2(dv * acc[4], dv * acc[5]);
    o.w = pack2(dv * acc[6], dv * acc[7]);
    nt_st4(&Tv[(size_t)node * 8 + sub], o);
}

// ---- outgemm via MFMA: out = T[n,64] @ W2[64,128] + b2 ----
__global__ __launch_bounds__(256) void outgemm_mfma(const bf16* __restrict__ T,
                                                    const void* __restrict__ W2,
                                                    const void* __restrict__ b2,
                                                    const int* __restrict__ flags,
                                                    void* __restrict__ outp, int n) {
    const bool isbf = flags[0] != 0;
    __shared__ uint4 bfr[16 * 64];   // [ct*2+ks][lane], 16 KB
    __shared__ float b2s[128];
    for (int idx = threadIdx.x; idx < 16 * 64; idx += 256) {
        int lane = idx & 63, fr = idx >> 6;
        int ct = fr >> 1, ks = fr & 1;
        int k0 = ks * 32 + (lane >> 4) * 8;
        int col = ct * 16 + (lane & 15);
        unsigned short h[8];
#pragma unroll
        for (int j = 0; j < 8; ++j)
            h[j] = f2bfbits(ldf(W2, (size_t)(k0 + j) * 128 + col, isbf));
        bfr[idx] = make_uint4((unsigned)h[0] | ((unsigned)h[1] << 16),
                              (unsigned)h[2] | ((unsigned)h[3] << 16),
                              (unsigned)h[4] | ((unsigned)h[5] << 16),
                              (unsigned)h[6] | ((unsigned)h[7] << 16));
    }
    for (int i = threadIdx.x; i < 128; i += 256) b2s[i] = ldf(b2, i, isbf);
    __syncthreads();

    const int lane = threadIdx.x & 63;
    const int m = lane & 15, q = lane >> 4;
    const int wid = (blockIdx.x * 256 + threadIdx.x) >> 6;
    const int nw  = (gridDim.x * 256) >> 6;
    const int nchunk = (n + 15) >> 4;

    for (int ch = wid; ch < nchunk; ch += nw) {
        const int row0 = ch * 16;
        const int rA = min(row0 + m, n - 1);
        const uint4* tr = (const uint4*)(T + (size_t)rA * 64);
        V8 a[2];
        a[0].u = tr[q];        // k = 0*32 + q*8 + j
        a[1].u = tr[4 + q];    // k = 32 + q*8 + j
#pragma unroll
        for (int ct = 0; ct < 8; ++ct) {
            f32x4 acc = {0.f, 0.f, 0.f, 0.f};
#pragma unroll
            for (int ks = 0; ks < 2; ++ks) {
                V8 b; b.u = bfr[(ct * 2 + ks) * 64 + lane];
                acc = __builtin_amdgcn_mfma_f32_16x16x32_bf16(a[ks].v, b.v, acc, 0, 0, 0);
            }
            const int col = ct * 16 + m;
            const float bb = b2s[col];
#pragma unroll
            for (int r = 0; r < 4; ++r) {
                int row = row0 + q * 4 + r;
                if (row < n) {
                    float o = acc[r] + bb;
                    if (isbf) ((bf16*)outp)[(size_t)row * 128 + col] = __float2bfloat16(o);
                    else      ((float*)outp)[(size_t)row * 128 + col] = o;
                }
            }
        }
    }
}

extern "C" void kernel_launch(void* const* d_in, const int* in_sizes, int n_in,
                              void* d_out, int out_size, void* d_ws, size_t ws_size,
                              hipStream_t stream) {
    const void* x  = d_in[0];
    const void* ei = d_in[1];
    const void* ew = d_in[2];
    const void* W1 = d_in[3];
    const void* b1 = d_in[4];
    const void* W2 = d_in[5];
    const void* b2 = d_in[6];

    const int n = in_sizes[0] / 128;   // 100000
    const int e = in_sizes[2];         // 1600000
    const int nb = (n + 1023) / 1024;

    // ws layout (4B words) -- identical footprint to the round-4 passing build:
    // flags(8) | dc(2n, u64) | rp(n+1) | cursor(n) | bsum(1024) | bsx(1024)
    // | pad | epack(2e) | G1/T(32n) | G2(32n)
    // aliases: hist = bsum+512, hcur = bsx+512, bcnt = bsx+256;
    //          order = cursor (dead after fillB); stage = G1 region (G1+G2).
    int*   flags  = (int*)d_ws;
    unsigned long long* dc = (unsigned long long*)((int*)d_ws + 8);
    int*   rp     = (int*)d_ws + 8 + 2 * (size_t)n;
    int*   cursor = rp + n + 1;
    int*   bsum   = cursor + n;
    int*   bsx    = bsum + 1024;
    int*   hist   = bsum + 512;
    int*   hcur   = bsx + 512;
    int*   bcnt   = bsx + 256;
    int*   order  = cursor;                      // alias, valid post-fill
    size_t w_off  = (size_t)(8 + 4 * (size_t)n + 1 + 2048);
    w_off = (w_off + 3) & ~(size_t)3;            // 16B align
    uint2*    epack = (uint2*)((int*)d_ws + w_off);
    size_t g_off = w_off + 2 * (size_t)e;
    g_off = (g_off + 3) & ~(size_t)3;
    unsigned* G1 = (unsigned*)d_ws + g_off;      // 32n uints (bf16x2), 16B aligned
    unsigned* G2 = G1 + (size_t)n * 32;

    const float* dinvp = (const float*)dc;       // dinv at dinvp[2*node] after scan3
    uint2* stage = (uint2*)G1;                   // alias: G1+G2, dead until gemm1

    // bucket parameters: bucket = 2^k node range, beff buckets (<=256)
    int bs0 = (n + 255) / 256;
    int k = 0;
    while ((1 << k) < bs0) ++k;
    int beff = (n + (1 << k) - 1) >> k;          // <= 256
    int cap  = (int)((32 * (size_t)n) / (size_t)beff);   // stage records/bucket
    size_t mean = ((size_t)e + beff - 1) / beff;
    bool fastfill = (n <= (1 << 18)) && (k <= 12) &&
                    ((size_t)cap >= mean + mean / 2 + 1024);

    detect<<<1, 256, 0, stream>>>((const unsigned*)W1, (const unsigned*)ei, flags);
    initk<<<(n + 255) / 256, 256, 0, stream>>>(dc, hist, bcnt, n, fastfill ? 0 : 1);
    if (fastfill) {
        binA<<<(e + 4095) / 4096, 1024, 0, stream>>>(ei, ew, bcnt, stage, flags, e, n, k, cap);
        degcntB<<<beff, 1024, 0, stream>>>(stage, bcnt, dc, n, k, cap);
    } else {
        degcnt<<<(e + 255) / 256, 256, 0, stream>>>(ei, ew, dc, flags, e, n);
    }
    scan1<<<nb, 1024, 0, stream>>>(dc, rp, bsum, n);
    scan2<<<1, 1024, 0, stream>>>(bsum, bsx, nb);
    scan3<<<nb, 1024, 0, stream>>>(rp, cursor, bsx, dc, hist, n, e);
    if (fastfill) {
        fillB<<<beff, 1024, 0, stream>>>(rp, stage, bcnt, epack, n, k, cap);
    } else {
        fill<<<(e + 255) / 256, 256, 0, stream>>>(ei, ew, cursor, epack, flags, e, n);
    }
    hscan<<<1, 256, 0, stream>>>(hist, hcur);
    sortk<<<nb, 1024, 0, stream>>>(dc, hcur, order, n);

    gemm1_mfma<<<192, 256, 0, stream>>>(x, W1, dinvp, flags, (unsigned short*)G1, n);
    agg1<<<(n * 8 + 255) / 256, 256, 0, stream>>>(rp, epack, order, (const uint4*)G1,
                                                  dinvp, b1, flags, (uint4*)G2, n);
    agg2<<<(n * 8 + 255) / 256, 256, 0, stream>>>(rp, epack, order, (const uint4*)G2,
                                                  dinvp, (uint4*)G1, n);
    outgemm_mfma<<<192, 256, 0, stream>>>((const bf16*)G1, W2, b2, flags, d_out, n);
}

// Round 9
// 350.602 us; speedup vs baseline: 1.5862x; 1.0539x over previous
//
#include <hip/hip_runtime.h>
#include <hip/hip_bf16.h>

typedef __hip_bfloat16 bf16;
typedef __attribute__((ext_vector_type(8))) short short8;
typedef __attribute__((ext_vector_type(4))) float f32x4;
typedef __attribute__((ext_vector_type(2))) unsigned uv2;   // nontemporal-compatible
typedef __attribute__((ext_vector_type(4))) unsigned uv4;   // nontemporal-compatible
union V8 { uint4 u; short8 v; };

__device__ __forceinline__ float bf2f(bf16 v) { return __bfloat162float(v); }
__device__ __forceinline__ float lo16(unsigned u) { return __uint_as_float((u & 0xffffu) << 16); }
__device__ __forceinline__ float hi16(unsigned u) { return __uint_as_float(u & 0xffff0000u); }
__device__ __forceinline__ unsigned short f2bfbits(float f) {
    return (unsigned short)(__hip_bfloat16_raw(__float2bfloat16(f)).x);
}
__device__ __forceinline__ unsigned pack2(float a, float b) {
    return (unsigned)f2bfbits(a) | ((unsigned)f2bfbits(b) << 16);
}

// dtype-dispatching loads (flag-driven, uniform branch)
__device__ __forceinline__ float ldf(const void* p, size_t i, bool isbf) {
    return isbf ? bf2f(((const bf16*)p)[i]) : ((const float*)p)[i];
}
__device__ __forceinline__ int ldi(const void* p, size_t i, bool is64) {
    return is64 ? (int)((const long long*)p)[i] : ((const int*)p)[i];
}
__device__ __forceinline__ float sane(float v) {
    return (v == v && fabsf(v) < 1e30f) ? v : 0.f;
}

// nontemporal helpers over HIP vector structs
__device__ __forceinline__ uint2 nt_ld2(const uint2* p) {
    uv2 v = __builtin_nontemporal_load((const uv2*)p);
    return make_uint2(v.x, v.y);
}
__device__ __forceinline__ void nt_st4(uint4* p, uint4 v) {
    uv4 t; t.x = v.x; t.y = v.y; t.z = v.z; t.w = v.w;
    __builtin_nontemporal_store(t, (uv4*)p);
}

// dc[node] packed layout (built by degcntB / legacy degcnt):
//   bits [44:63] : in-degree count (20 bits)
//   bits [ 0:43] : weighted degree, 22.22 unsigned fixed point
// After scan3:
//   bits [44:63] : in-degree count (still valid, for sortk)
//   bits [ 0:31] : dinv as f32 bits  -> readable as ((const float*)dc)[2*node]
#define DC_CNT_SHIFT 44
#define DC_FIX_MASK  0xFFFFFFFFFFFULL
#define DC_FIX_SCALE 4194304.0f   /* 2^22 */

// ---------------- init (+ fused dtype detection in block 0) ----------------
__global__ void initk(unsigned long long* __restrict__ dc, int* __restrict__ hist,
                      int* __restrict__ bcnt, int n, int initdc,
                      const unsigned* __restrict__ w1w, const unsigned* __restrict__ eiw,
                      int* __restrict__ flags) {
    int i = blockIdx.x * blockDim.x + threadIdx.x;
    if (initdc && i < n) dc[i] = (unsigned long long)(1u << 22);  // deg = 1.0
    if (i < 256) { hist[i] = 0; bcnt[i] = 0; }
    if (blockIdx.x == 0) {
        __shared__ int cnt[2];
        if (threadIdx.x < 2) cnt[threadIdx.x] = 0;
        __syncthreads();
        int c0 = 0;
        for (int j = threadIdx.x; j < 4096; j += 256) {
            unsigned u = w1w[j];
            unsigned e0 = (u >> 7) & 0xFFu, e1 = (u >> 23) & 0xFFu;
            if (e0 <= 125u && e1 <= 125u) c0++;
        }
        int c1 = 0;
        for (int j = threadIdx.x; j < 2048; j += 256)
            if (eiw[2 * j + 1] == 0u) c1++;
        atomicAdd(&cnt[0], c0);
        atomicAdd(&cnt[1], c1);
        __syncthreads();
        if (threadIdx.x == 0) {
            flags[0] = (cnt[0] >= 3072) ? 1 : 0;
            flags[1] = (cnt[1] >= 1024) ? 1 : 0;
        }
    }
}

// ------------- legacy degcnt (fallback path only): one u64 atomic/edge -------
__global__ void degcnt(const void* __restrict__ ei, const void* __restrict__ w,
                       unsigned long long* __restrict__ dc,
                       const int* __restrict__ flags, int e, int n) {
    const bool isbf = flags[0] != 0;
    const bool is64 = flags[1] != 0;
    int i = blockIdx.x * blockDim.x + threadIdx.x;
    if (i < e) {
        int c = ldi(ei, (size_t)e + i, is64);
        if ((unsigned)c < (unsigned)n) {
            float wv = sane(ldf(w, i, isbf));
            wv = fminf(fmaxf(wv, 0.f), 1024.f);   // keep fixed-point in range
            unsigned long long pk = (1ULL << DC_CNT_SHIFT)
                                  + (unsigned long long)llrintf(wv * DC_FIX_SCALE);
            atomicAdd(&dc[c], pk);
        }
    }
}

// ---------------- binA: bin edges by node-bucket, coalesced stage writes -----
__global__ __launch_bounds__(1024) void binA(const void* __restrict__ ei,
                                             const void* __restrict__ w,
                                             int* __restrict__ bcnt,
                                             uint2* __restrict__ stage,
                                             const int* __restrict__ flags,
                                             int e, int n, int k, int cap) {
    __shared__ uint2 recs[4096];
    __shared__ unsigned tgt[4096];
    __shared__ int lh[256], loff[256], lbase[256];
    const bool isbf = flags[0] != 0;
    const bool is64 = flags[1] != 0;
    const int t = threadIdx.x;
    if (t < 256) lh[t] = 0;
    __syncthreads();

    int b_[4], lr_[4], valid_[4];
    uint2 rec_[4];
    const int base = blockIdx.x * 4096;
#pragma unroll
    for (int u = 0; u < 4; ++u) {
        int i = base + u * 1024 + t;
        valid_[u] = 0;
        if (i < e) {
            int r = ldi(ei, (size_t)i, is64);
            int c = ldi(ei, (size_t)e + i, is64);
            if ((unsigned)c < (unsigned)n) {
                bool rv = (unsigned)r < (unsigned)n;
                float wv = rv ? sane(ldf(w, i, isbf)) : 0.f;
                int b = c >> k;
                unsigned cloc = (unsigned)(c - (b << k));
                rec_[u] = make_uint2((cloc << 20) | (rv ? (unsigned)r : 0u),
                                     __float_as_uint(wv));
                b_[u] = b;
                lr_[u] = atomicAdd(&lh[b], 1);
                valid_[u] = 1;
            }
        }
    }
    __syncthreads();

    // exclusive scan of lh -> loff; reserve per-bucket global ranges
    if (t < 256) loff[t] = lh[t];
    __syncthreads();
    for (int off = 1; off < 256; off <<= 1) {
        int v = 0;
        if (t < 256 && t >= off) v = loff[t - off];
        __syncthreads();
        if (t < 256 && t >= off) loff[t] += v;
        __syncthreads();
    }
    if (t < 256) {
        int c = lh[t];
        loff[t] -= c;  // inclusive -> exclusive
        lbase[t] = (c > 0) ? atomicAdd(&bcnt[t], c) : 0;
    }
    __syncthreads();

    // place records grouped by bucket in LDS; remember global target
#pragma unroll
    for (int u = 0; u < 4; ++u)
        if (valid_[u]) {
            int slot = loff[b_[u]] + lr_[u];
            recs[slot] = rec_[u];
            unsigned gi = (unsigned)(lbase[b_[u]] + lr_[u]);
            tgt[slot] = (gi < (unsigned)cap)
                          ? (unsigned)b_[u] * (unsigned)cap + gi
                          : 0xFFFFFFFFu;   // clamp: drop on (impossible) overflow
        }
    __syncthreads();

    // flush: consecutive slots within a bucket-run -> consecutive global addrs
    const int total = loff[255] + lh[255];
    for (int s = t; s < total; s += 1024) {
        unsigned g = tgt[s];
        if (g != 0xFFFFFFFFu) stage[g] = recs[s];
    }
}

// ---------------- degcntB: per-bucket count+degree, zero global atomics ------
__global__ __launch_bounds__(1024) void degcntB(const uint2* __restrict__ stage,
                                                const int* __restrict__ bcnt,
                                                unsigned long long* __restrict__ dc,
                                                int n, int k, int cap) {
    __shared__ unsigned long long dcl[4096];
    const int b  = blockIdx.x;
    const int lo = b << k;
    const int hi = min(n, lo + (1 << k));
    const int bs = hi - lo;
    const int t  = threadIdx.x;
    for (int j = t; j < bs; j += 1024)
        dcl[j] = (unsigned long long)(1u << 22);   // self-loop: deg = 1.0
    __syncthreads();
    const uint2* sb = stage + (size_t)b * cap;
    const int cnt_b = min(bcnt[b], cap);
    for (int s = t; s < cnt_b; s += 1024) {
        uint2 rec = sb[s];
        int cloc  = (int)(rec.x >> 20);
        float wv  = __uint_as_float(rec.y);
        wv = fminf(fmaxf(wv, 0.f), 1024.f);
        unsigned long long pk = (1ULL << DC_CNT_SHIFT)
                              + (unsigned long long)llrintf(wv * DC_FIX_SCALE);
        atomicAdd(&dcl[cloc], pk);                 // LDS atomic, intra-CU
    }
    __syncthreads();
    for (int j = t; j < bs; j += 1024) dc[lo + j] = dcl[j];
}

// ---------------- scans ----------------
__global__ __launch_bounds__(1024) void scan1(const unsigned long long* __restrict__ dc,
                                              int* __restrict__ rp,
                                              int* __restrict__ bsum, int n) {
    __shared__ int s[1024];
    int gid = blockIdx.x * 1024 + threadIdx.x;
    int v = (gid < n) ? (int)(dc[gid] >> DC_CNT_SHIFT) : 0;
    s[threadIdx.x] = v;
    __syncthreads();
    for (int off = 1; off < 1024; off <<= 1) {
        int t = 0;
        if (threadIdx.x >= off) t = s[threadIdx.x - off];
        __syncthreads();
        if (threadIdx.x >= off) s[threadIdx.x] += t;
        __syncthreads();
    }
    if (gid < n) rp[gid] = s[threadIdx.x] - v;
    if (threadIdx.x == 1023) bsum[blockIdx.x] = s[1023];
}

__global__ __launch_bounds__(1024) void scan2(const int* __restrict__ bsum,
                                              int* __restrict__ bsx, int nb) {
    __shared__ int s[1024];
    int v = (threadIdx.x < nb) ? bsum[threadIdx.x] : 0;
    s[threadIdx.x] = v;
    __syncthreads();
    for (int off = 1; off < 1024; off <<= 1) {
        int t = 0;
        if (threadIdx.x >= off) t = s[threadIdx.x - off];
        __syncthreads();
        if (threadIdx.x >= off) s[threadIdx.x] += t;
        __syncthreads();
    }
    if (threadIdx.x < nb) bsx[threadIdx.x] = s[threadIdx.x] - v;
}

// scan3: finalize rowptr, unpack dc -> dinv (repacked into low 32 bits of dc,
// cnt preserved in high bits for sortk), degree histogram via LDS aggregation.
__global__ __launch_bounds__(1024) void scan3(int* __restrict__ rp, int* __restrict__ cursor,
                                              const int* __restrict__ bsx,
                                              unsigned long long* __restrict__ dc,
                                              int* __restrict__ hist,
                                              int n, int e) {
    __shared__ int lh[256];
    const int t = threadIdx.x;
    if (t < 256) lh[t] = 0;
    __syncthreads();
    int i = blockIdx.x * 1024 + t;
    if (i < n) {
        int v = rp[i] + bsx[i >> 10];
        rp[i] = v;
        cursor[i] = v;
        unsigned long long dv = dc[i];
        int c = (int)(dv >> DC_CNT_SHIFT);
        float d = (float)(dv & DC_FIX_MASK) * (1.0f / DC_FIX_SCALE);
        float di = d > 0.f ? rsqrtf(d) : 0.f;
        dc[i] = (dv & ~DC_FIX_MASK) | (unsigned long long)__float_as_uint(di);
        atomicAdd(&lh[min(c, 255)], 1);        // LDS atomic: intra-block aggregate
    }
    __syncthreads();
    if (t < 256) {
        int c = lh[t];
        if (c > 0) atomicAdd(&hist[t], c);     // one global atomic per (block, bin)
    }
    if (i == 0) rp[n] = e;
}

// ---------------- fill CSR: legacy one-pass fallback ----------------
__global__ void fill(const void* __restrict__ ei, const void* __restrict__ w,
                     int* __restrict__ cursor, uint2* __restrict__ epack,
                     const int* __restrict__ flags, int e, int n) {
    const bool isbf = flags[0] != 0;
    const bool is64 = flags[1] != 0;
    int i = blockIdx.x * blockDim.x + threadIdx.x;
    if (i < e) {
        int r = ldi(ei, (size_t)i, is64);
        int c = ldi(ei, (size_t)e + i, is64);
        if ((unsigned)c < (unsigned)n) {
            bool rv = (unsigned)r < (unsigned)n;
            float wv = rv ? sane(ldf(w, i, isbf)) : 0.f;
            int pos = atomicAdd(&cursor[c], 1);
            epack[pos] = make_uint2(rv ? (unsigned)r : 0u, __float_as_uint(wv));
        }
    }
}

// ---------------- fillB: per-bucket placement with LDS cursors ----------------
__global__ __launch_bounds__(1024) void fillB(const int* __restrict__ rp,
                                              const uint2* __restrict__ stage,
                                              const int* __restrict__ bcnt,
                                              uint2* __restrict__ epack,
                                              int n, int k, int cap) {
    __shared__ int ncur[4096];
    const int b  = blockIdx.x;
    const int lo = b << k;
    const int hi = min(n, lo + (1 << k));
    const int t  = threadIdx.x;
    for (int j = t; j < hi - lo; j += 1024) ncur[j] = rp[lo + j];
    __syncthreads();
    const uint2* sb = stage + (size_t)b * cap;
    const int cnt_b = min(bcnt[b], cap);
    for (int s = t; s < cnt_b; s += 1024) {
        uint2 rec = sb[s];
        int cloc  = (int)(rec.x >> 20);
        unsigned r = rec.x & 0xFFFFFu;
        int pos = atomicAdd(&ncur[cloc], 1);
        epack[pos] = make_uint2(r, rec.y);
    }
}

// ---------------- degree-bucket scan ----------------
__global__ void hscan(const int* __restrict__ hist, int* __restrict__ hcur) {
    __shared__ int s[256];
    int v = hist[threadIdx.x];
    s[threadIdx.x] = v;
    __syncthreads();
    for (int off = 1; off < 256; off <<= 1) {
        int t = 0;
        if (threadIdx.x >= off) t = s[threadIdx.x - off];
        __syncthreads();
        if (threadIdx.x >= off) s[threadIdx.x] += t;
        __syncthreads();
    }
    hcur[threadIdx.x] = s[threadIdx.x] - v;  // exclusive
}

// ---------------- counting-sort placement, block-aggregated ----------------
__global__ __launch_bounds__(1024) void sortk(const unsigned long long* __restrict__ dc,
                                              int* __restrict__ hcur,
                                              int* __restrict__ order, int n) {
    __shared__ int lh[256];     // local histogram
    __shared__ int lbase[256];  // global base per bin for this block
    const int t = threadIdx.x;
    for (int b = t; b < 256; b += 1024) lh[b] = 0;
    __syncthreads();
    const int i = blockIdx.x * 1024 + t;
    int b = 0, lrank = 0;
    if (i < n) {
        b = min((int)(dc[i] >> DC_CNT_SHIFT), 255);
        lrank = atomicAdd(&lh[b], 1);  // LDS atomic: intra-block rank
    }
    __syncthreads();
    for (int bb = t; bb < 256; bb += 1024) {
        int c = lh[bb];
        lbase[bb] = (c > 0) ? atomicAdd(&hcur[bb], c) : 0;  // range reservation
    }
    __syncthreads();
    if (i < n) order[lbase[b] + lrank] = i;
}

// ---- layer1 GEMM via MFMA: G1 = bf16(dinv ⊙ (X[n,128] @ W1[128,64])) ----
// grid sized to ~1 chunk/wave (was 192 blocks = 0.75/CU, half the SIMDs idle)
__global__ __launch_bounds__(256) void gemm1_mfma(const void* __restrict__ x,
                                                  const void* __restrict__ W1,
                                                  const float* __restrict__ dinvp,
                                                  const int* __restrict__ flags,
                                                  unsigned short* __restrict__ G1,
                                                  int n) {
    const bool isbf = flags[0] != 0;
    __shared__ uint4 bfr[16 * 64];  // [ct*4+ks][lane], 16 KB
    for (int idx = threadIdx.x; idx < 16 * 64; idx += 256) {
        int lane = idx & 63, fr = idx >> 6;
        int ct = fr >> 2, ks = fr & 3;
        int k0 = ks * 32 + (lane >> 4) * 8;
        int col = ct * 16 + (lane & 15);
        unsigned short h[8];
#pragma unroll
        for (int j = 0; j < 8; ++j)
            h[j] = f2bfbits(ldf(W1, (size_t)(k0 + j) * 64 + col, isbf));
        bfr[idx] = make_uint4((unsigned)h[0] | ((unsigned)h[1] << 16),
                              (unsigned)h[2] | ((unsigned)h[3] << 16),
                              (unsigned)h[4] | ((unsigned)h[5] << 16),
                              (unsigned)h[6] | ((unsigned)h[7] << 16));
    }
    __syncthreads();

    const int lane = threadIdx.x & 63;
    const int m = lane & 15, q = lane >> 4;
    const int wid = (blockIdx.x * 256 + threadIdx.x) >> 6;
    const int nw  = (gridDim.x * 256) >> 6;
    const int nchunk = (n + 15) >> 4;

    for (int ch = wid; ch < nchunk; ch += nw) {
        const int row0 = ch * 16;
        const int rA = min(row0 + m, n - 1);
        V8 a[4];
        if (isbf) {
            const uint4* xr = (const uint4*)((const bf16*)x + (size_t)rA * 128);
#pragma unroll
            for (int ks = 0; ks < 4; ++ks) a[ks].u = xr[ks * 4 + q];
        } else {
            // float4-vectorized f32 path (was 32 scalar loads/chunk)
            const float4* xr4 = (const float4*)((const float*)x + (size_t)rA * 128);
#pragma unroll
            for (int ks = 0; ks < 4; ++ks) {
                float4 v0 = xr4[ks * 8 + q * 2];
                float4 v1 = xr4[ks * 8 + q * 2 + 1];
                a[ks].u = make_uint4(pack2(v0.x, v0.y), pack2(v0.z, v0.w),
                                     pack2(v1.x, v1.y), pack2(v1.z, v1.w));
            }
        }
#pragma unroll
        for (int ct = 0; ct < 4; ++ct) {
            f32x4 acc = {0.f, 0.f, 0.f, 0.f};
#pragma unroll
            for (int ks = 0; ks < 4; ++ks) {
                V8 b; b.u = bfr[(ct * 4 + ks) * 64 + lane];
                acc = __builtin_amdgcn_mfma_f32_16x16x32_bf16(a[ks].v, b.v, acc, 0, 0, 0);
            }
#pragma unroll
            for (int r = 0; r < 4; ++r) {
                int row = row0 + q * 4 + r;
                if (row < n)
                    G1[(size_t)row * 64 + ct * 16 + m] = f2bfbits(dinvp[2 * (size_t)row] * acc[r]);
            }
        }
    }
}

// ---- gather core: 8 lanes/node, uint4/lane, depth-8 + epack prefetch ----
// epack reads are nontemporal (streaming; keep L2 lines for the G-row gathers).
__device__ __forceinline__ void gacc8(const int* __restrict__ rp,
                                      const uint2* __restrict__ epack,
                                      const uint4* __restrict__ Gv,
                                      int node, int sub, float acc[8]) {
    uint4 self = Gv[(size_t)node * 8 + sub];
    acc[0] = lo16(self.x); acc[1] = hi16(self.x);
    acc[2] = lo16(self.y); acc[3] = hi16(self.y);
    acc[4] = lo16(self.z); acc[5] = hi16(self.z);
    acc[6] = lo16(self.w); acc[7] = hi16(self.w);

    const int s0 = rp[node], s1 = rp[node + 1];
    const uint2 fb = make_uint2((unsigned)node, 0u);
    int idx = s0 + sub;
    uint2 ld = (idx < s1) ? nt_ld2(&epack[idx]) : fb;
    for (int base = s0; base < s1; base += 8) {
        int nidx = base + 8 + sub;
        uint2 nld = (nidx < s1) ? nt_ld2(&epack[nidx]) : fb;  // prefetch next batch
        int rr[8]; float wv[8];
#pragma unroll
        for (int u = 0; u < 8; ++u) {
            rr[u] = __shfl((int)ld.x, u, 8);
            wv[u] = __uint_as_float((unsigned)__shfl((int)ld.y, u, 8));
        }
        uint4 gp[8];
#pragma unroll
        for (int u = 0; u < 8; ++u) gp[u] = Gv[(size_t)rr[u] * 8 + sub];
#pragma unroll
        for (int u = 0; u < 8; ++u) {
            acc[0] = fmaf(wv[u], lo16(gp[u].x), acc[0]);
            acc[1] = fmaf(wv[u], hi16(gp[u].x), acc[1]);
            acc[2] = fmaf(wv[u], lo16(gp[u].y), acc[2]);
            acc[3] = fmaf(wv[u], hi16(gp[u].y), acc[3]);
            acc[4] = fmaf(wv[u], lo16(gp[u].z), acc[4]);
            acc[5] = fmaf(wv[u], hi16(gp[u].z), acc[5]);
            acc[6] = fmaf(wv[u], lo16(gp[u].w), acc[6]);
            acc[7] = fmaf(wv[u], hi16(gp[u].w), acc[7]);
        }
        ld = nld;
    }
}

// ---- agg1: acc -> relu/bias/dinv -> G2 ----
// (256,4): the (256,8) bound forces VGPR<=32 and spills gp[8] (round 7: 2.5x slower)
__global__ __launch_bounds__(256, 4) void agg1(const int* __restrict__ rp,
                                               const uint2* __restrict__ epack,
                                               const int* __restrict__ order,
                                               const uint4* __restrict__ G1v,
                                               const float* __restrict__ dinvp,
                                               const void* __restrict__ b1,
                                               const int* __restrict__ flags,
                                               uint4* __restrict__ G2v, int n) {
    const bool isbf = flags[0] != 0;
    const int sub = threadIdx.x & 7;
    const int g   = (blockIdx.x * 256 + threadIdx.x) >> 3;
    if (g >= n) return;
    const int node = order[g];

    float acc[8];
    gacc8(rp, epack, G1v, node, sub, acc);

    const float dv = dinvp[2 * (size_t)node];
    unsigned o[4];
#pragma unroll
    for (int t = 0; t < 4; ++t) {
        float h0 = dv * acc[2 * t]     + ldf(b1, 8 * sub + 2 * t, isbf);
        float h1 = dv * acc[2 * t + 1] + ldf(b1, 8 * sub + 2 * t + 1, isbf);
        h0 = h0 > 0.f ? h0 : 0.f;
        h1 = h1 > 0.f ? h1 : 0.f;
        o[t] = pack2(dv * h0, dv * h1);
    }
    nt_st4(&G2v[(size_t)node * 8 + sub], make_uint4(o[0], o[1], o[2], o[3]));
}

// ---- agg2: acc -> T = bf16(dinv * acc) ----
__global__ __launch_bounds__(256, 4) void agg2(const int* __restrict__ rp,
                                               const uint2* __restrict__ epack,
                                               const int* __restrict__ order,
                                               const uint4* __restrict__ G2v,
                                               const float* __restrict__ dinvp,
                                               uint4* __restrict__ Tv, int n) {
    const int sub = threadIdx.x & 7;
    const int g   = (blockIdx.x * 256 + threadIdx.x) >> 3;
    if (g >= n) return;
    const int node = order[g];

    float acc[8];
    gacc8(rp, epack, G2v, node, sub, acc);

    const float dv = dinvp[2 * (size_t)node];
    uint4 o;
    o.x = pack2(dv * acc[0], dv * acc[1]);
    o.y = pack2(dv * acc[2], dv * acc[3]);
    o.z = pack2(dv * acc[4], dv * acc[5]);
    o.w = pack2(dv * acc[6], dv * acc[7]);
    nt_st4(&Tv[(size_t)node * 8 + sub], o);
}

// ---- outgemm via MFMA: out = T[n,64] @ W2[64,128] + b2 ----
__global__ __launch_bounds__(256) void outgemm_mfma(const bf16* __restrict__ T,
                                                    const void* __restrict__ W2,
                                                    const void* __restrict__ b2,
                                                    const int* __restrict__ flags,
                                                    void* __restrict__ outp, int n) {
    const bool isbf = flags[0] != 0;
    __shared__ uint4 bfr[16 * 64];   // [ct*2+ks][lane], 16 KB
    __shared__ float b2s[128];
    for (int idx = threadIdx.x; idx < 16 * 64; idx += 256) {
        int lane = idx & 63, fr = idx >> 6;
        int ct = fr >> 1, ks = fr & 1;
        int k0 = ks * 32 + (lane >> 4) * 8;
        int col = ct * 16 + (lane & 15);
        unsigned short h[8];
#pragma unroll
        for (int j = 0; j < 8; ++j)
            h[j] = f2bfbits(ldf(W2, (size_t)(k0 + j) * 128 + col, isbf));
        bfr[idx] = make_uint4((unsigned)h[0] | ((unsigned)h[1] << 16),
                              (unsigned)h[2] | ((unsigned)h[3] << 16),
                              (unsigned)h[4] | ((unsigned)h[5] << 16),
                              (unsigned)h[6] | ((unsigned)h[7] << 16));
    }
    for (int i = threadIdx.x; i < 128; i += 256) b2s[i] = ldf(b2, i, isbf);
    __syncthreads();

    const int lane = threadIdx.x & 63;
    const int m = lane & 15, q = lane >> 4;
    const int wid = (blockIdx.x * 256 + threadIdx.x) >> 6;
    const int nw  = (gridDim.x * 256) >> 6;
    const int nchunk = (n + 15) >> 4;

    for (int ch = wid; ch < nchunk; ch += nw) {
        const int row0 = ch * 16;
        const int rA = min(row0 + m, n - 1);
        const uint4* tr = (const uint4*)(T + (size_t)rA * 64);
        V8 a[2];
        a[0].u = tr[q];        // k = 0*32 + q*8 + j
        a[1].u = tr[4 + q];    // k = 32 + q*8 + j
#pragma unroll
        for (int ct = 0; ct < 8; ++ct) {
            f32x4 acc = {0.f, 0.f, 0.f, 0.f};
#pragma unroll
            for (int ks = 0; ks < 2; ++ks) {
                V8 b; b.u = bfr[(ct * 2 + ks) * 64 + lane];
                acc = __builtin_amdgcn_mfma_f32_16x16x32_bf16(a[ks].v, b.v, acc, 0, 0, 0);
            }
            const int col = ct * 16 + m;
            const float bb = b2s[col];
#pragma unroll
            for (int r = 0; r < 4; ++r) {
                int row = row0 + q * 4 + r;
                if (row < n) {
                    float o = acc[r] + bb;
                    if (isbf) ((bf16*)outp)[(size_t)row * 128 + col] = __float2bfloat16(o);
                    else      ((float*)outp)[(size_t)row * 128 + col] = o;
                }
            }
        }
    }
}

extern "C" void kernel_launch(void* const* d_in, const int* in_sizes, int n_in,
                              void* d_out, int out_size, void* d_ws, size_t ws_size,
                              hipStream_t stream) {
    const void* x  = d_in[0];
    const void* ei = d_in[1];
    const void* ew = d_in[2];
    const void* W1 = d_in[3];
    const void* b1 = d_in[4];
    const void* W2 = d_in[5];
    const void* b2 = d_in[6];

    const int n = in_sizes[0] / 128;   // 100000
    const int e = in_sizes[2];         // 1600000
    const int nb = (n + 1023) / 1024;

    // ws layout (4B words) -- identical footprint to the round-4 passing build:
    // flags(8) | dc(2n, u64) | rp(n+1) | cursor(n) | bsum(1024) | bsx(1024)
    // | pad | epack(2e) | G1/T(32n) | G2(32n)
    // aliases: hist = bsum+512, hcur = bsx+512, bcnt = bsx+256;
    //          order = cursor (dead after fillB); stage = G1 region (G1+G2).
    int*   flags  = (int*)d_ws;
    unsigned long long* dc = (unsigned long long*)((int*)d_ws + 8);
    int*   rp     = (int*)d_ws + 8 + 2 * (size_t)n;
    int*   cursor = rp + n + 1;
    int*   bsum   = cursor + n;
    int*   bsx    = bsum + 1024;
    int*   hist   = bsum + 512;
    int*   hcur   = bsx + 512;
    int*   bcnt   = bsx + 256;
    int*   order  = cursor;                      // alias, valid post-fill
    size_t w_off  = (size_t)(8 + 4 * (size_t)n + 1 + 2048);
    w_off = (w_off + 3) & ~(size_t)3;            // 16B align
    uint2*    epack = (uint2*)((int*)d_ws + w_off);
    size_t g_off = w_off + 2 * (size_t)e;
    g_off = (g_off + 3) & ~(size_t)3;
    unsigned* G1 = (unsigned*)d_ws + g_off;      // 32n uints (bf16x2), 16B aligned
    unsigned* G2 = G1 + (size_t)n * 32;

    const float* dinvp = (const float*)dc;       // dinv at dinvp[2*node] after scan3
    uint2* stage = (uint2*)G1;                   // alias: G1+G2, dead until gemm1

    // bucket parameters: bucket = 2^k node range, beff buckets (<=256)
    int bs0 = (n + 255) / 256;
    int k = 0;
    while ((1 << k) < bs0) ++k;
    int beff = (n + (1 << k) - 1) >> k;          // <= 256
    int cap  = (int)((32 * (size_t)n) / (size_t)beff);   // stage records/bucket
    size_t mean = ((size_t)e + beff - 1) / beff;
    bool fastfill = (n <= (1 << 18)) && (k <= 12) &&
                    ((size_t)cap >= mean + mean / 2 + 1024);

    // gemm grids: ~1 chunk per wave, capped (was 192 blocks = 0.75/CU)
    const int nchunk = (n + 15) >> 4;
    int ggrid = (nchunk + 3) / 4;                // 4 waves/block, 1 chunk/wave
    if (ggrid > 2048) ggrid = 2048;
    if (ggrid < 192)  ggrid = 192;

    initk<<<(n + 255) / 256, 256, 0, stream>>>(dc, hist, bcnt, n, fastfill ? 0 : 1,
                                               (const unsigned*)W1, (const unsigned*)ei, flags);
    if (fastfill) {
        binA<<<(e + 4095) / 4096, 1024, 0, stream>>>(ei, ew, bcnt, stage, flags, e, n, k, cap);
        degcntB<<<beff, 1024, 0, stream>>>(stage, bcnt, dc, n, k, cap);
    } else {
        degcnt<<<(e + 255) / 256, 256, 0, stream>>>(ei, ew, dc, flags, e, n);
    }
    scan1<<<nb, 1024, 0, stream>>>(dc, rp, bsum, n);
    scan2<<<1, 1024, 0, stream>>>(bsum, bsx, nb);
    scan3<<<nb, 1024, 0, stream>>>(rp, cursor, bsx, dc, hist, n, e);
    if (fastfill) {
        fillB<<<beff, 1024, 0, stream>>>(rp, stage, bcnt, epack, n, k, cap);
    } else {
        fill<<<(e + 255) / 256, 256, 0, stream>>>(ei, ew, cursor, epack, flags, e, n);
    }
    hscan<<<1, 256, 0, stream>>>(hist, hcur);
    sortk<<<nb, 1024, 0, stream>>>(dc, hcur, order, n);

    gemm1_mfma<<<ggrid, 256, 0, stream>>>(x, W1, dinvp, flags, (unsigned short*)G1, n);
    agg1<<<(n * 8 + 255) / 256, 256, 0, stream>>>(rp, epack, order, (const uint4*)G1,
                                                  dinvp, b1, flags, (uint4*)G2, n);
    agg2<<<(n * 8 + 255) / 256, 256, 0, stream>>>(rp, epack, order, (const uint4*)G2,
                                                  dinvp, (uint4*)G1, n);
    outgemm_mfma<<<ggrid, 256, 0, stream>>>((const bf16*)G1, W2, b2, flags, d_out, n);
}

// Round 10
// 337.660 us; speedup vs baseline: 1.6470x; 1.0383x over previous
//
#include <hip/hip_runtime.h>
#include <hip/hip_bf16.h>

typedef __hip_bfloat16 bf16;
typedef __attribute__((ext_vector_type(8))) short short8;
typedef __attribute__((ext_vector_type(4))) float f32x4;
typedef __attribute__((ext_vector_type(2))) unsigned uv2;   // nontemporal-compatible
typedef __attribute__((ext_vector_type(4))) unsigned uv4;   // nontemporal-compatible
union V8 { uint4 u; short8 v; };

__device__ __forceinline__ float bf2f(bf16 v) { return __bfloat162float(v); }
__device__ __forceinline__ float lo16(unsigned u) { return __uint_as_float((u & 0xffffu) << 16); }
__device__ __forceinline__ float hi16(unsigned u) { return __uint_as_float(u & 0xffff0000u); }
__device__ __forceinline__ unsigned short f2bfbits(float f) {
    return (unsigned short)(__hip_bfloat16_raw(__float2bfloat16(f)).x);
}
__device__ __forceinline__ unsigned pack2(float a, float b) {
    return (unsigned)f2bfbits(a) | ((unsigned)f2bfbits(b) << 16);
}

// dtype-dispatching loads (flag-driven, uniform branch)
__device__ __forceinline__ float ldf(const void* p, size_t i, bool isbf) {
    return isbf ? bf2f(((const bf16*)p)[i]) : ((const float*)p)[i];
}
__device__ __forceinline__ int ldi(const void* p, size_t i, bool is64) {
    return is64 ? (int)((const long long*)p)[i] : ((const int*)p)[i];
}
__device__ __forceinline__ float sane(float v) {
    return (v == v && fabsf(v) < 1e30f) ? v : 0.f;
}

// nontemporal helpers over HIP vector structs
__device__ __forceinline__ uint2 nt_ld2(const uint2* p) {
    uv2 v = __builtin_nontemporal_load((const uv2*)p);
    return make_uint2(v.x, v.y);
}
__device__ __forceinline__ void nt_st4(uint4* p, uint4 v) {
    uv4 t; t.x = v.x; t.y = v.y; t.z = v.z; t.w = v.w;
    __builtin_nontemporal_store(t, (uv4*)p);
}

// dc[node] packed layout (built by degcntB / legacy degcnt):
//   bits [44:63] : in-degree count (20 bits)
//   bits [ 0:43] : weighted degree, 22.22 unsigned fixed point
// After scan3:
//   bits [44:63] : in-degree count (still valid, for sortk)
//   bits [ 0:31] : dinv as f32 bits  -> readable as ((const float*)dc)[2*node]
#define DC_CNT_SHIFT 44
#define DC_FIX_MASK  0xFFFFFFFFFFFULL
#define DC_FIX_SCALE 4194304.0f   /* 2^22 */

// ---------------- init (+ fused dtype detection in block 0) ----------------
// In the fastpath initdc==0 -> launched with ONE block (only hist/bcnt/detect).
__global__ void initk(unsigned long long* __restrict__ dc, int* __restrict__ hist,
                      int* __restrict__ bcnt, int n, int initdc,
                      const unsigned* __restrict__ w1w, const unsigned* __restrict__ eiw,
                      int* __restrict__ flags) {
    int i = blockIdx.x * blockDim.x + threadIdx.x;
    if (initdc && i < n) dc[i] = (unsigned long long)(1u << 22);  // deg = 1.0
    if (i < 256) { hist[i] = 0; bcnt[i] = 0; }
    if (blockIdx.x == 0) {
        __shared__ int cnt[2];
        if (threadIdx.x < 2) cnt[threadIdx.x] = 0;
        __syncthreads();
        int c0 = 0;
        for (int j = threadIdx.x; j < 4096; j += 256) {
            unsigned u = w1w[j];
            unsigned e0 = (u >> 7) & 0xFFu, e1 = (u >> 23) & 0xFFu;
            if (e0 <= 125u && e1 <= 125u) c0++;
        }
        int c1 = 0;
        for (int j = threadIdx.x; j < 2048; j += 256)
            if (eiw[2 * j + 1] == 0u) c1++;
        atomicAdd(&cnt[0], c0);
        atomicAdd(&cnt[1], c1);
        __syncthreads();
        if (threadIdx.x == 0) {
            flags[0] = (cnt[0] >= 3072) ? 1 : 0;
            flags[1] = (cnt[1] >= 1024) ? 1 : 0;
        }
    }
}

// ------------- legacy degcnt (fallback path only): one u64 atomic/edge -------
__global__ void degcnt(const void* __restrict__ ei, const void* __restrict__ w,
                       unsigned long long* __restrict__ dc,
                       const int* __restrict__ flags, int e, int n) {
    const bool isbf = flags[0] != 0;
    const bool is64 = flags[1] != 0;
    int i = blockIdx.x * blockDim.x + threadIdx.x;
    if (i < e) {
        int c = ldi(ei, (size_t)e + i, is64);
        if ((unsigned)c < (unsigned)n) {
            float wv = sane(ldf(w, i, isbf));
            wv = fminf(fmaxf(wv, 0.f), 1024.f);   // keep fixed-point in range
            unsigned long long pk = (1ULL << DC_CNT_SHIFT)
                                  + (unsigned long long)llrintf(wv * DC_FIX_SCALE);
            atomicAdd(&dc[c], pk);
        }
    }
}

// ---------------- binA: bin edges by node-bucket, coalesced stage writes -----
__global__ __launch_bounds__(1024) void binA(const void* __restrict__ ei,
                                             const void* __restrict__ w,
                                             int* __restrict__ bcnt,
                                             uint2* __restrict__ stage,
                                             const int* __restrict__ flags,
                                             int e, int n, int k, int cap) {
    __shared__ uint2 recs[4096];
    __shared__ unsigned tgt[4096];
    __shared__ int lh[256], loff[256], lbase[256];
    const bool isbf = flags[0] != 0;
    const bool is64 = flags[1] != 0;
    const int t = threadIdx.x;
    if (t < 256) lh[t] = 0;
    __syncthreads();

    int b_[4], lr_[4], valid_[4];
    uint2 rec_[4];
    const int base = blockIdx.x * 4096;
#pragma unroll
    for (int u = 0; u < 4; ++u) {
        int i = base + u * 1024 + t;
        valid_[u] = 0;
        if (i < e) {
            int r = ldi(ei, (size_t)i, is64);
            int c = ldi(ei, (size_t)e + i, is64);
            if ((unsigned)c < (unsigned)n) {
                bool rv = (unsigned)r < (unsigned)n;
                float wv = rv ? sane(ldf(w, i, isbf)) : 0.f;
                int b = c >> k;
                unsigned cloc = (unsigned)(c - (b << k));
                rec_[u] = make_uint2((cloc << 20) | (rv ? (unsigned)r : 0u),
                                     __float_as_uint(wv));
                b_[u] = b;
                lr_[u] = atomicAdd(&lh[b], 1);
                valid_[u] = 1;
            }
        }
    }
    __syncthreads();

    // exclusive scan of lh -> loff; reserve per-bucket global ranges
    if (t < 256) loff[t] = lh[t];
    __syncthreads();
    for (int off = 1; off < 256; off <<= 1) {
        int v = 0;
        if (t < 256 && t >= off) v = loff[t - off];
        __syncthreads();
        if (t < 256 && t >= off) loff[t] += v;
        __syncthreads();
    }
    if (t < 256) {
        int c = lh[t];
        loff[t] -= c;  // inclusive -> exclusive
        lbase[t] = (c > 0) ? atomicAdd(&bcnt[t], c) : 0;
    }
    __syncthreads();

    // place records grouped by bucket in LDS; remember global target
#pragma unroll
    for (int u = 0; u < 4; ++u)
        if (valid_[u]) {
            int slot = loff[b_[u]] + lr_[u];
            recs[slot] = rec_[u];
            unsigned gi = (unsigned)(lbase[b_[u]] + lr_[u]);
            tgt[slot] = (gi < (unsigned)cap)
                          ? (unsigned)b_[u] * (unsigned)cap + gi
                          : 0xFFFFFFFFu;   // clamp: drop on (impossible) overflow
        }
    __syncthreads();

    // flush: consecutive slots within a bucket-run -> consecutive global addrs
    const int total = loff[255] + lh[255];
    for (int s = t; s < total; s += 1024) {
        unsigned g = tgt[s];
        if (g != 0xFFFFFFFFu) stage[g] = recs[s];
    }
}

// ---------------- degcntB: per-bucket count+degree, zero global atomics ------
__global__ __launch_bounds__(1024) void degcntB(const uint2* __restrict__ stage,
                                                const int* __restrict__ bcnt,
                                                unsigned long long* __restrict__ dc,
                                                int n, int k, int cap) {
    __shared__ unsigned long long dcl[4096];
    const int b  = blockIdx.x;
    const int lo = b << k;
    const int hi = min(n, lo + (1 << k));
    const int bs = hi - lo;
    const int t  = threadIdx.x;
    for (int j = t; j < bs; j += 1024)
        dcl[j] = (unsigned long long)(1u << 22);   // self-loop: deg = 1.0
    __syncthreads();
    const uint2* sb = stage + (size_t)b * cap;
    const int cnt_b = min(bcnt[b], cap);
    for (int s = t; s < cnt_b; s += 1024) {
        uint2 rec = sb[s];
        int cloc  = (int)(rec.x >> 20);
        float wv  = __uint_as_float(rec.y);
        wv = fminf(fmaxf(wv, 0.f), 1024.f);
        unsigned long long pk = (1ULL << DC_CNT_SHIFT)
                              + (unsigned long long)llrintf(wv * DC_FIX_SCALE);
        atomicAdd(&dcl[cloc], pk);                 // LDS atomic, intra-CU
    }
    __syncthreads();
    for (int j = t; j < bs; j += 1024) dc[lo + j] = dcl[j];
}

// ---------------- scans ----------------
__global__ __launch_bounds__(1024) void scan1(const unsigned long long* __restrict__ dc,
                                              int* __restrict__ rp,
                                              int* __restrict__ bsum, int n) {
    __shared__ int s[1024];
    int gid = blockIdx.x * 1024 + threadIdx.x;
    // read only the high 32-bit word of dc (cnt = hi >> 12)
    int v = (gid < n) ? (int)(((const unsigned*)dc)[2 * (size_t)gid + 1] >> (DC_CNT_SHIFT - 32)) : 0;
    s[threadIdx.x] = v;
    __syncthreads();
    for (int off = 1; off < 1024; off <<= 1) {
        int t = 0;
        if (threadIdx.x >= off) t = s[threadIdx.x - off];
        __syncthreads();
        if (threadIdx.x >= off) s[threadIdx.x] += t;
        __syncthreads();
    }
    if (gid < n) rp[gid] = s[threadIdx.x] - v;
    if (threadIdx.x == 1023) bsum[blockIdx.x] = s[1023];
}

__global__ __launch_bounds__(1024) void scan2(const int* __restrict__ bsum,
                                              int* __restrict__ bsx, int nb) {
    __shared__ int s[1024];
    int v = (threadIdx.x < nb) ? bsum[threadIdx.x] : 0;
    s[threadIdx.x] = v;
    __syncthreads();
    for (int off = 1; off < 1024; off <<= 1) {
        int t = 0;
        if (threadIdx.x >= off) t = s[threadIdx.x - off];
        __syncthreads();
        if (threadIdx.x >= off) s[threadIdx.x] += t;
        __syncthreads();
    }
    if (threadIdx.x < nb) bsx[threadIdx.x] = s[threadIdx.x] - v;
}

// scan3: finalize rowptr, unpack dc -> dinv (repacked into low 32 bits of dc,
// cnt preserved in high bits for sortk), degree histogram via LDS aggregation.
__global__ __launch_bounds__(1024) void scan3(int* __restrict__ rp, int* __restrict__ cursor,
                                              const int* __restrict__ bsx,
                                              unsigned long long* __restrict__ dc,
                                              int* __restrict__ hist,
                                              int n, int e) {
    __shared__ int lh[256];
    const int t = threadIdx.x;
    if (t < 256) lh[t] = 0;
    __syncthreads();
    int i = blockIdx.x * 1024 + t;
    if (i < n) {
        int v = rp[i] + bsx[i >> 10];
        rp[i] = v;
        cursor[i] = v;
        unsigned long long dv = dc[i];
        int c = (int)(dv >> DC_CNT_SHIFT);
        float d = (float)(dv & DC_FIX_MASK) * (1.0f / DC_FIX_SCALE);
        float di = d > 0.f ? rsqrtf(d) : 0.f;
        dc[i] = (dv & ~DC_FIX_MASK) | (unsigned long long)__float_as_uint(di);
        atomicAdd(&lh[min(c, 255)], 1);        // LDS atomic: intra-block aggregate
    }
    __syncthreads();
    if (t < 256) {
        int c = lh[t];
        if (c > 0) atomicAdd(&hist[t], c);     // one global atomic per (block, bin)
    }
    if (i == 0) rp[n] = e;
}

// ---------------- fill CSR: legacy one-pass fallback ----------------
__global__ void fill(const void* __restrict__ ei, const void* __restrict__ w,
                     int* __restrict__ cursor, uint2* __restrict__ epack,
                     const int* __restrict__ flags, int e, int n) {
    const bool isbf = flags[0] != 0;
    const bool is64 = flags[1] != 0;
    int i = blockIdx.x * blockDim.x + threadIdx.x;
    if (i < e) {
        int r = ldi(ei, (size_t)i, is64);
        int c = ldi(ei, (size_t)e + i, is64);
        if ((unsigned)c < (unsigned)n) {
            bool rv = (unsigned)r < (unsigned)n;
            float wv = rv ? sane(ldf(w, i, isbf)) : 0.f;
            int pos = atomicAdd(&cursor[c], 1);
            epack[pos] = make_uint2(rv ? (unsigned)r : 0u, __float_as_uint(wv));
        }
    }
}

// ---------------- fillB: per-bucket placement with LDS cursors ----------------
__global__ __launch_bounds__(1024) void fillB(const int* __restrict__ rp,
                                              const uint2* __restrict__ stage,
                                              const int* __restrict__ bcnt,
                                              uint2* __restrict__ epack,
                                              int n, int k, int cap) {
    __shared__ int ncur[4096];
    const int b  = blockIdx.x;
    const int lo = b << k;
    const int hi = min(n, lo + (1 << k));
    const int t  = threadIdx.x;
    for (int j = t; j < hi - lo; j += 1024) ncur[j] = rp[lo + j];
    __syncthreads();
    const uint2* sb = stage + (size_t)b * cap;
    const int cnt_b = min(bcnt[b], cap);
    for (int s = t; s < cnt_b; s += 1024) {
        uint2 rec = sb[s];
        int cloc  = (int)(rec.x >> 20);
        unsigned r = rec.x & 0xFFFFFu;
        int pos = atomicAdd(&ncur[cloc], 1);
        epack[pos] = make_uint2(r, rec.y);
    }
}

// ---------------- degree-bucket scan ----------------
__global__ void hscan(const int* __restrict__ hist, int* __restrict__ hcur) {
    __shared__ int s[256];
    int v = hist[threadIdx.x];
    s[threadIdx.x] = v;
    __syncthreads();
    for (int off = 1; off < 256; off <<= 1) {
        int t = 0;
        if (threadIdx.x >= off) t = s[threadIdx.x - off];
        __syncthreads();
        if (threadIdx.x >= off) s[threadIdx.x] += t;
        __syncthreads();
    }
    hcur[threadIdx.x] = s[threadIdx.x] - v;  // exclusive
}

// ---------------- counting-sort placement, block-aggregated ----------------
__global__ __launch_bounds__(1024) void sortk(const unsigned long long* __restrict__ dc,
                                              int* __restrict__ hcur,
                                              int* __restrict__ order, int n) {
    __shared__ int lh[256];     // local histogram
    __shared__ int lbase[256];  // global base per bin for this block
    const int t = threadIdx.x;
    for (int b = t; b < 256; b += 1024) lh[b] = 0;
    __syncthreads();
    const int i = blockIdx.x * 1024 + t;
    int b = 0, lrank = 0;
    if (i < n) {
        b = min((int)(dc[i] >> DC_CNT_SHIFT), 255);
        lrank = atomicAdd(&lh[b], 1);  // LDS atomic: intra-block rank
    }
    __syncthreads();
    for (int bb = t; bb < 256; bb += 1024) {
        int c = lh[bb];
        lbase[bb] = (c > 0) ? atomicAdd(&hcur[bb], c) : 0;  // range reservation
    }
    __syncthreads();
    if (i < n) order[lbase[b] + lrank] = i;
}

// ---- layer1 GEMM via MFMA: G1 = bf16(dinv ⊙ (X[n,128] @ W1[128,64])) ----
__global__ __launch_bounds__(256) void gemm1_mfma(const void* __restrict__ x,
                                                  const void* __restrict__ W1,
                                                  const float* __restrict__ dinvp,
                                                  const int* __restrict__ flags,
                                                  unsigned short* __restrict__ G1,
                                                  int n) {
    const bool isbf = flags[0] != 0;
    __shared__ uint4 bfr[16 * 64];  // [ct*4+ks][lane], 16 KB
    for (int idx = threadIdx.x; idx < 16 * 64; idx += 256) {
        int lane = idx & 63, fr = idx >> 6;
        int ct = fr >> 2, ks = fr & 3;
        int k0 = ks * 32 + (lane >> 4) * 8;
        int col = ct * 16 + (lane & 15);
        unsigned short h[8];
#pragma unroll
        for (int j = 0; j < 8; ++j)
            h[j] = f2bfbits(ldf(W1, (size_t)(k0 + j) * 64 + col, isbf));
        bfr[idx] = make_uint4((unsigned)h[0] | ((unsigned)h[1] << 16),
                              (unsigned)h[2] | ((unsigned)h[3] << 16),
                              (unsigned)h[4] | ((unsigned)h[5] << 16),
                              (unsigned)h[6] | ((unsigned)h[7] << 16));
    }
    __syncthreads();

    const int lane = threadIdx.x & 63;
    const int m = lane & 15, q = lane >> 4;
    const int wid = (blockIdx.x * 256 + threadIdx.x) >> 6;
    const int nw  = (gridDim.x * 256) >> 6;
    const int nchunk = (n + 15) >> 4;

    for (int ch = wid; ch < nchunk; ch += nw) {
        const int row0 = ch * 16;
        const int rA = min(row0 + m, n - 1);
        V8 a[4];
        if (isbf) {
            const uint4* xr = (const uint4*)((const bf16*)x + (size_t)rA * 128);
#pragma unroll
            for (int ks = 0; ks < 4; ++ks) a[ks].u = xr[ks * 4 + q];
        } else {
            const float4* xr4 = (const float4*)((const float*)x + (size_t)rA * 128);
#pragma unroll
            for (int ks = 0; ks < 4; ++ks) {
                float4 v0 = xr4[ks * 8 + q * 2];
                float4 v1 = xr4[ks * 8 + q * 2 + 1];
                a[ks].u = make_uint4(pack2(v0.x, v0.y), pack2(v0.z, v0.w),
                                     pack2(v1.x, v1.y), pack2(v1.z, v1.w));
            }
        }
#pragma unroll
        for (int ct = 0; ct < 4; ++ct) {
            f32x4 acc = {0.f, 0.f, 0.f, 0.f};
#pragma unroll
            for (int ks = 0; ks < 4; ++ks) {
                V8 b; b.u = bfr[(ct * 4 + ks) * 64 + lane];
                acc = __builtin_amdgcn_mfma_f32_16x16x32_bf16(a[ks].v, b.v, acc, 0, 0, 0);
            }
#pragma unroll
            for (int r = 0; r < 4; ++r) {
                int row = row0 + q * 4 + r;
                if (row < n)
                    G1[(size_t)row * 64 + ct * 16 + m] = f2bfbits(dinvp[2 * (size_t)row] * acc[r]);
            }
        }
    }
}

// ---- gather core: 8 lanes/node, uint4/lane, depth-8 + epack prefetch ----
__device__ __forceinline__ void gacc8(const int* __restrict__ rp,
                                      const uint2* __restrict__ epack,
                                      const uint4* __restrict__ Gv,
                                      int node, int sub, float acc[8]) {
    uint4 self = Gv[(size_t)node * 8 + sub];
    acc[0] = lo16(self.x); acc[1] = hi16(self.x);
    acc[2] = lo16(self.y); acc[3] = hi16(self.y);
    acc[4] = lo16(self.z); acc[5] = hi16(self.z);
    acc[6] = lo16(self.w); acc[7] = hi16(self.w);

    const int s0 = rp[node], s1 = rp[node + 1];
    const uint2 fb = make_uint2((unsigned)node, 0u);
    int idx = s0 + sub;
    uint2 ld = (idx < s1) ? nt_ld2(&epack[idx]) : fb;
    for (int base = s0; base < s1; base += 8) {
        int nidx = base + 8 + sub;
        uint2 nld = (nidx < s1) ? nt_ld2(&epack[nidx]) : fb;  // prefetch next batch
        int rr[8]; float wv[8];
#pragma unroll
        for (int u = 0; u < 8; ++u) {
            rr[u] = __shfl((int)ld.x, u, 8);
            wv[u] = __uint_as_float((unsigned)__shfl((int)ld.y, u, 8));
        }
        uint4 gp[8];
#pragma unroll
        for (int u = 0; u < 8; ++u) gp[u] = Gv[(size_t)rr[u] * 8 + sub];
#pragma unroll
        for (int u = 0; u < 8; ++u) {
            acc[0] = fmaf(wv[u], lo16(gp[u].x), acc[0]);
            acc[1] = fmaf(wv[u], hi16(gp[u].x), acc[1]);
            acc[2] = fmaf(wv[u], lo16(gp[u].y), acc[2]);
            acc[3] = fmaf(wv[u], hi16(gp[u].y), acc[3]);
            acc[4] = fmaf(wv[u], lo16(gp[u].z), acc[4]);
            acc[5] = fmaf(wv[u], hi16(gp[u].z), acc[5]);
            acc[6] = fmaf(wv[u], lo16(gp[u].w), acc[6]);
            acc[7] = fmaf(wv[u], hi16(gp[u].w), acc[7]);
        }
        ld = nld;
    }
}

// ---- agg1: acc -> relu/bias/dinv -> G2 ----
// (256,4): the (256,8) bound forces VGPR<=32 and spills gp[8] (round 7: 2.5x slower)
__global__ __launch_bounds__(256, 4) void agg1(const int* __restrict__ rp,
                                               const uint2* __restrict__ epack,
                                               const int* __restrict__ order,
                                               const uint4* __restrict__ G1v,
                                               const float* __restrict__ dinvp,
                                               const void* __restrict__ b1,
                                               const int* __restrict__ flags,
                                               uint4* __restrict__ G2v, int n) {
    const bool isbf = flags[0] != 0;
    const int sub = threadIdx.x & 7;
    const int g   = (blockIdx.x * 256 + threadIdx.x) >> 3;
    if (g >= n) return;
    const int node = order[g];

    float acc[8];
    gacc8(rp, epack, G1v, node, sub, acc);

    const float dv = dinvp[2 * (size_t)node];
    unsigned o[4];
#pragma unroll
    for (int t = 0; t < 4; ++t) {
        float h0 = dv * acc[2 * t]     + ldf(b1, 8 * sub + 2 * t, isbf);
        float h1 = dv * acc[2 * t + 1] + ldf(b1, 8 * sub + 2 * t + 1, isbf);
        h0 = h0 > 0.f ? h0 : 0.f;
        h1 = h1 > 0.f ? h1 : 0.f;
        o[t] = pack2(dv * h0, dv * h1);
    }
    nt_st4(&G2v[(size_t)node * 8 + sub], make_uint4(o[0], o[1], o[2], o[3]));
}

// ---- agg2out: gather (agg2) fused with out = T @ W2 + b2 (outgemm) ----
// Eliminates the 25.6 MB T round-trip and the separate outgemm launch.
// Numerically identical composition: T rows are bf16-packed into an LDS tile
// in exactly the layout outgemm read from global; same MFMA epilogue.
__global__ __launch_bounds__(256, 4) void agg2out(const int* __restrict__ rp,
                                                  const uint2* __restrict__ epack,
                                                  const int* __restrict__ order,
                                                  const uint4* __restrict__ G2v,
                                                  const float* __restrict__ dinvp,
                                                  const void* __restrict__ W2,
                                                  const void* __restrict__ b2,
                                                  const int* __restrict__ flags,
                                                  void* __restrict__ outp, int n) {
    const bool isbf = flags[0] != 0;
    __shared__ uint4 bfr[16 * 64];   // W2 fragments [ct*2+ks][lane], 16 KB
    __shared__ float b2s[128];
    __shared__ uint4 tls[32 * 8];    // 32 node-rows of bf16 T, 4 KB
    __shared__ int   nds[32];
    for (int idx = threadIdx.x; idx < 16 * 64; idx += 256) {
        int lane = idx & 63, fr = idx >> 6;
        int ct = fr >> 1, ks = fr & 1;
        int k0 = ks * 32 + (lane >> 4) * 8;
        int col = ct * 16 + (lane & 15);
        unsigned short h[8];
#pragma unroll
        for (int j = 0; j < 8; ++j)
            h[j] = f2bfbits(ldf(W2, (size_t)(k0 + j) * 128 + col, isbf));
        bfr[idx] = make_uint4((unsigned)h[0] | ((unsigned)h[1] << 16),
                              (unsigned)h[2] | ((unsigned)h[3] << 16),
                              (unsigned)h[4] | ((unsigned)h[5] << 16),
                              (unsigned)h[6] | ((unsigned)h[7] << 16));
    }
    for (int i = threadIdx.x; i < 128; i += 256) b2s[i] = ldf(b2, i, isbf);
    __syncthreads();

    const int sub  = threadIdx.x & 7;
    const int lg   = threadIdx.x >> 3;         // local node 0..31
    const int lane = threadIdx.x & 63;
    const int m = lane & 15, q = lane >> 4;
    const int wid = threadIdx.x >> 6;          // wave 0..3
    const int ntile = (n + 31) >> 5;

    for (int tile = blockIdx.x; tile < ntile; tile += gridDim.x) {
        const int g = tile * 32 + lg;
        uint4 o = make_uint4(0u, 0u, 0u, 0u);
        int node = 0;
        if (g < n) {                            // group-uniform (8 lanes share g)
            node = order[g];
            float acc[8];
            gacc8(rp, epack, G2v, node, sub, acc);
            const float dv = dinvp[2 * (size_t)node];
            o.x = pack2(dv * acc[0], dv * acc[1]);
            o.y = pack2(dv * acc[2], dv * acc[3]);
            o.z = pack2(dv * acc[4], dv * acc[5]);
            o.w = pack2(dv * acc[6], dv * acc[7]);
        }
        tls[lg * 8 + sub] = o;
        if (sub == 0) nds[lg] = node;
        __syncthreads();

        // MFMA epilogue: waves 0,1 -> rows [0,16), waves 2,3 -> rows [16,32)
        const int chunk = wid >> 1;
        const int lrow  = chunk * 16 + m;
        V8 a0, a1;
        a0.u = tls[lrow * 8 + q];
        a1.u = tls[lrow * 8 + 4 + q];
#pragma unroll
        for (int c8 = 0; c8 < 4; ++c8) {
            const int ct = (wid & 1) * 4 + c8;
            f32x4 acc4 = {0.f, 0.f, 0.f, 0.f};
            V8 b0; b0.u = bfr[(ct * 2 + 0) * 64 + lane];
            acc4 = __builtin_amdgcn_mfma_f32_16x16x32_bf16(a0.v, b0.v, acc4, 0, 0, 0);
            V8 b1; b1.u = bfr[(ct * 2 + 1) * 64 + lane];
            acc4 = __builtin_amdgcn_mfma_f32_16x16x32_bf16(a1.v, b1.v, acc4, 0, 0, 0);
            const int col = ct * 16 + m;
            const float bb = b2s[col];
#pragma unroll
            for (int r = 0; r < 4; ++r) {
                int lr = chunk * 16 + q * 4 + r;
                int gg = tile * 32 + lr;
                if (gg < n) {
                    float ov = acc4[r] + bb;
                    int nd = nds[lr];
                    if (isbf) ((bf16*)outp)[(size_t)nd * 128 + col] = __float2bfloat16(ov);
                    else      ((float*)outp)[(size_t)nd * 128 + col] = ov;
                }
            }
        }
        __syncthreads();   // protect tls/nds for next tile
    }
}

extern "C" void kernel_launch(void* const* d_in, const int* in_sizes, int n_in,
                              void* d_out, int out_size, void* d_ws, size_t ws_size,
                              hipStream_t stream) {
    const void* x  = d_in[0];
    const void* ei = d_in[1];
    const void* ew = d_in[2];
    const void* W1 = d_in[3];
    const void* b1 = d_in[4];
    const void* W2 = d_in[5];
    const void* b2 = d_in[6];

    const int n = in_sizes[0] / 128;   // 100000
    const int e = in_sizes[2];         // 1600000
    const int nb = (n + 1023) / 1024;

    // ws layout (4B words) -- identical footprint to the round-4 passing build:
    // flags(8) | dc(2n, u64) | rp(n+1) | cursor(n) | bsum(1024) | bsx(1024)
    // | pad | epack(2e) | G1/T(32n) | G2(32n)
    // aliases: hist = bsum+512, hcur = bsx+512, bcnt = bsx+256;
    //          order = cursor (dead after fillB); stage = G1 region (G1+G2).
    int*   flags  = (int*)d_ws;
    unsigned long long* dc = (unsigned long long*)((int*)d_ws + 8);
    int*   rp     = (int*)d_ws + 8 + 2 * (size_t)n;
    int*   cursor = rp + n + 1;
    int*   bsum   = cursor + n;
    int*   bsx    = bsum + 1024;
    int*   hist   = bsum + 512;
    int*   hcur   = bsx + 512;
    int*   bcnt   = bsx + 256;
    int*   order  = cursor;                      // alias, valid post-fill
    size_t w_off  = (size_t)(8 + 4 * (size_t)n + 1 + 2048);
    w_off = (w_off + 3) & ~(size_t)3;            // 16B align
    uint2*    epack = (uint2*)((int*)d_ws + w_off);
    size_t g_off = w_off + 2 * (size_t)e;
    g_off = (g_off + 3) & ~(size_t)3;
    unsigned* G1 = (unsigned*)d_ws + g_off;      // 32n uints (bf16x2), 16B aligned
    unsigned* G2 = G1 + (size_t)n * 32;

    const float* dinvp = (const float*)dc;       // dinv at dinvp[2*node] after scan3
    uint2* stage = (uint2*)G1;                   // alias: G1+G2, dead until gemm1

    // bucket parameters: bucket = 2^k node range, beff buckets (<=256)
    int bs0 = (n + 255) / 256;
    int k = 0;
    while ((1 << k) < bs0) ++k;
    int beff = (n + (1 << k) - 1) >> k;          // <= 256
    int cap  = (int)((32 * (size_t)n) / (size_t)beff);   // stage records/bucket
    size_t mean = ((size_t)e + beff - 1) / beff;
    bool fastfill = (n <= (1 << 18)) && (k <= 12) &&
                    ((size_t)cap >= mean + mean / 2 + 1024);

    // gemm grid: ~1 chunk per wave, capped
    const int nchunk = (n + 15) >> 4;
    int ggrid = (nchunk + 3) / 4;
    if (ggrid > 2048) ggrid = 2048;
    if (ggrid < 192)  ggrid = 192;

    initk<<<fastfill ? 1 : (n + 255) / 256, 256, 0, stream>>>(
        dc, hist, bcnt, n, fastfill ? 0 : 1,
        (const unsigned*)W1, (const unsigned*)ei, flags);
    if (fastfill) {
        binA<<<(e + 4095) / 4096, 1024, 0, stream>>>(ei, ew, bcnt, stage, flags, e, n, k, cap);
        degcntB<<<beff, 1024, 0, stream>>>(stage, bcnt, dc, n, k, cap);
    } else {
        degcnt<<<(e + 255) / 256, 256, 0, stream>>>(ei, ew, dc, flags, e, n);
    }
    scan1<<<nb, 1024, 0, stream>>>(dc, rp, bsum, n);
    scan2<<<1, 1024, 0, stream>>>(bsum, bsx, nb);
    scan3<<<nb, 1024, 0, stream>>>(rp, cursor, bsx, dc, hist, n, e);
    if (fastfill) {
        fillB<<<beff, 1024, 0, stream>>>(rp, stage, bcnt, epack, n, k, cap);
    } else {
        fill<<<(e + 255) / 256, 256, 0, stream>>>(ei, ew, cursor, epack, flags, e, n);
    }
    hscan<<<1, 256, 0, stream>>>(hist, hcur);
    sortk<<<nb, 1024, 0, stream>>>(dc, hcur, order, n);

    gemm1_mfma<<<ggrid, 256, 0, stream>>>(x, W1, dinvp, flags, (unsigned short*)G1, n);
    agg1<<<(n * 8 + 255) / 256, 256, 0, stream>>>(rp, epack, order, (const uint4*)G1,
                                                  dinvp, b1, flags, (uint4*)G2, n);
    int a2grid = (n + 31) / 32;
    if (a2grid > 1024) a2grid = 1024;            // grid-stride: stage W2 once/block
    agg2out<<<a2grid, 256, 0, stream>>>(rp, epack, order, (const uint4*)G2,
                                        dinvp, W2, b2, flags, d_out, n);
}

// Round 11
// 335.208 us; speedup vs baseline: 1.6590x; 1.0073x over previous
//
#include <hip/hip_runtime.h>
#include <hip/hip_bf16.h>

typedef __hip_bfloat16 bf16;
typedef __attribute__((ext_vector_type(8))) short short8;
typedef __attribute__((ext_vector_type(4))) float f32x4;
typedef __attribute__((ext_vector_type(2))) unsigned uv2;   // nontemporal-compatible
typedef __attribute__((ext_vector_type(4))) unsigned uv4;   // nontemporal-compatible
union V8 { uint4 u; short8 v; };

__device__ __forceinline__ float bf2f(bf16 v) { return __bfloat162float(v); }
__device__ __forceinline__ float lo16(unsigned u) { return __uint_as_float((u & 0xffffu) << 16); }
__device__ __forceinline__ float hi16(unsigned u) { return __uint_as_float(u & 0xffff0000u); }
__device__ __forceinline__ unsigned short f2bfbits(float f) {
    return (unsigned short)(__hip_bfloat16_raw(__float2bfloat16(f)).x);
}
__device__ __forceinline__ unsigned pack2(float a, float b) {
    return (unsigned)f2bfbits(a) | ((unsigned)f2bfbits(b) << 16);
}

// dtype-dispatching loads (flag-driven, uniform branch)
__device__ __forceinline__ float ldf(const void* p, size_t i, bool isbf) {
    return isbf ? bf2f(((const bf16*)p)[i]) : ((const float*)p)[i];
}
__device__ __forceinline__ int ldi(const void* p, size_t i, bool is64) {
    return is64 ? (int)((const long long*)p)[i] : ((const int*)p)[i];
}
__device__ __forceinline__ float sane(float v) {
    return (v == v && fabsf(v) < 1e30f) ? v : 0.f;
}

// nontemporal helpers over HIP vector structs
__device__ __forceinline__ uint2 nt_ld2(const uint2* p) {
    uv2 v = __builtin_nontemporal_load((const uv2*)p);
    return make_uint2(v.x, v.y);
}
__device__ __forceinline__ void nt_st4(uint4* p, uint4 v) {
    uv4 t; t.x = v.x; t.y = v.y; t.z = v.z; t.w = v.w;
    __builtin_nontemporal_store(t, (uv4*)p);
}

// dc[node] packed layout (built by degscanB / legacy degcnt):
//   bits [44:63] : in-degree count (20 bits)
//   bits [ 0:43] : weighted degree, 22.22 unsigned fixed point
// After degscanB/scan3:
//   bits [44:63] : in-degree count (still valid, for sortk)
//   bits [ 0:31] : dinv as f32 bits  -> readable as ((const float*)dc)[2*node]
#define DC_CNT_SHIFT 44
#define DC_FIX_MASK  0xFFFFFFFFFFFULL
#define DC_FIX_SCALE 4194304.0f   /* 2^22 */

// ---------------- init (+ fused dtype detection in block 0) ----------------
// In the fastpath initdc==0 -> launched with ONE block (only hist/bcnt/detect).
__global__ void initk(unsigned long long* __restrict__ dc, int* __restrict__ hist,
                      int* __restrict__ bcnt, int n, int initdc,
                      const unsigned* __restrict__ w1w, const unsigned* __restrict__ eiw,
                      int* __restrict__ flags) {
    int i = blockIdx.x * blockDim.x + threadIdx.x;
    if (initdc && i < n) dc[i] = (unsigned long long)(1u << 22);  // deg = 1.0
    if (i < 256) { hist[i] = 0; bcnt[i] = 0; }
    if (blockIdx.x == 0) {
        __shared__ int cnt[2];
        if (threadIdx.x < 2) cnt[threadIdx.x] = 0;
        __syncthreads();
        int c0 = 0;
        for (int j = threadIdx.x; j < 4096; j += 256) {
            unsigned u = w1w[j];
            unsigned e0 = (u >> 7) & 0xFFu, e1 = (u >> 23) & 0xFFu;
            if (e0 <= 125u && e1 <= 125u) c0++;
        }
        int c1 = 0;
        for (int j = threadIdx.x; j < 2048; j += 256)
            if (eiw[2 * j + 1] == 0u) c1++;
        atomicAdd(&cnt[0], c0);
        atomicAdd(&cnt[1], c1);
        __syncthreads();
        if (threadIdx.x == 0) {
            flags[0] = (cnt[0] >= 3072) ? 1 : 0;
            flags[1] = (cnt[1] >= 1024) ? 1 : 0;
        }
    }
}

// ------------- legacy degcnt (fallback path only): one u64 atomic/edge -------
__global__ void degcnt(const void* __restrict__ ei, const void* __restrict__ w,
                       unsigned long long* __restrict__ dc,
                       const int* __restrict__ flags, int e, int n) {
    const bool isbf = flags[0] != 0;
    const bool is64 = flags[1] != 0;
    int i = blockIdx.x * blockDim.x + threadIdx.x;
    if (i < e) {
        int c = ldi(ei, (size_t)e + i, is64);
        if ((unsigned)c < (unsigned)n) {
            float wv = sane(ldf(w, i, isbf));
            wv = fminf(fmaxf(wv, 0.f), 1024.f);   // keep fixed-point in range
            unsigned long long pk = (1ULL << DC_CNT_SHIFT)
                                  + (unsigned long long)llrintf(wv * DC_FIX_SCALE);
            atomicAdd(&dc[c], pk);
        }
    }
}

// ---------------- binA: bin edges by node-bucket, DIRECT stage writes --------
// Position b*cap + lbase[b] + lrank is fully determined after range
// reservation, so the LDS reorder + 256-wide scan of the old version was
// only a write-coalescing device. With 256 bucket frontiers (~2 hot lines
// each, L2-combined) the direct 8B scatter is cheap; this drops 48KB LDS
// and ~20 barriers per block.
__global__ __launch_bounds__(1024) void binA(const void* __restrict__ ei,
                                             const void* __restrict__ w,
                                             int* __restrict__ bcnt,
                                             uint2* __restrict__ stage,
                                             const int* __restrict__ flags,
                                             int e, int n, int k, int cap) {
    __shared__ int lh[256], lbase[256];
    const bool isbf = flags[0] != 0;
    const bool is64 = flags[1] != 0;
    const int t = threadIdx.x;
    if (t < 256) lh[t] = 0;
    __syncthreads();

    int b_[4], lr_[4], valid_[4];
    uint2 rec_[4];
    const int base = blockIdx.x * 4096;
#pragma unroll
    for (int u = 0; u < 4; ++u) {
        int i = base + u * 1024 + t;
        valid_[u] = 0;
        if (i < e) {
            int r = ldi(ei, (size_t)i, is64);
            int c = ldi(ei, (size_t)e + i, is64);
            if ((unsigned)c < (unsigned)n) {
                bool rv = (unsigned)r < (unsigned)n;
                float wv = rv ? sane(ldf(w, i, isbf)) : 0.f;
                int b = c >> k;
                unsigned cloc = (unsigned)(c - (b << k));
                rec_[u] = make_uint2((cloc << 20) | (rv ? (unsigned)r : 0u),
                                     __float_as_uint(wv));
                b_[u] = b;
                lr_[u] = atomicAdd(&lh[b], 1);
                valid_[u] = 1;
            }
        }
    }
    __syncthreads();
    if (t < 256) {
        int c = lh[t];
        lbase[t] = (c > 0) ? atomicAdd(&bcnt[t], c) : 0;   // range reservation
    }
    __syncthreads();
#pragma unroll
    for (int u = 0; u < 4; ++u)
        if (valid_[u]) {
            unsigned gi = (unsigned)(lbase[b_[u]] + lr_[u]);
            if (gi < (unsigned)cap)                         // clamp (impossible)
                stage[(size_t)b_[u] * cap + gi] = rec_[u];
        }
}

// ---------------- bscan: bucket-level exclusive scan (1 block) ---------------
// bbase[b] = sum of bcnt[0..b); rp[n] = total valid edges.
__global__ void bscan(const int* __restrict__ bcnt, int* __restrict__ bbase,
                      int* __restrict__ rp, int n, int beff) {
    __shared__ int s[256];
    const int t = threadIdx.x;
    int v = (t < beff) ? bcnt[t] : 0;
    s[t] = v;
    __syncthreads();
    for (int off = 1; off < 256; off <<= 1) {
        int x = 0;
        if (t >= off) x = s[t - off];
        __syncthreads();
        if (t >= off) s[t] += x;
        __syncthreads();
    }
    bbase[t] = s[t] - v;
    if (t == 255) rp[n] = s[255];
}

// ---- degscanB: per-bucket count+degree + LOCAL prefix scan -> rp, dinv, hist.
// Replaces degcntB + scan1 + scan2 + scan3: bucket base comes from bscan,
// intra-bucket prefix from an LDS scan over the counts already resident here.
// dinv computation instruction-identical to old scan3 (same fixed-point
// unpack + rsqrtf) -> bit-identical results.
__global__ __launch_bounds__(1024) void degscanB(const uint2* __restrict__ stage,
                                                 const int* __restrict__ bcnt,
                                                 const int* __restrict__ bbase,
                                                 unsigned long long* __restrict__ dc,
                                                 int* __restrict__ rp,
                                                 int* __restrict__ hist,
                                                 int n, int k, int cap) {
    __shared__ unsigned long long dcl[4096];
    __shared__ int pfx[1024];
    __shared__ int lh[256];
    const int b  = blockIdx.x;
    const int lo = b << k;
    const int hi = min(n, lo + (1 << k));
    const int bs = hi - lo;
    const int t  = threadIdx.x;
    if (t < 256) lh[t] = 0;
    for (int j = t; j < bs; j += 1024)
        dcl[j] = (unsigned long long)(1u << 22);   // self-loop: deg = 1.0
    __syncthreads();
    const uint2* sb = stage + (size_t)b * cap;
    const int cnt_b = min(bcnt[b], cap);
    for (int s = t; s < cnt_b; s += 1024) {
        uint2 rec = sb[s];
        int cloc  = (int)(rec.x >> 20);
        float wv  = __uint_as_float(rec.y);
        wv = fminf(fmaxf(wv, 0.f), 1024.f);
        unsigned long long pk = (1ULL << DC_CNT_SHIFT)
                              + (unsigned long long)llrintf(wv * DC_FIX_SCALE);
        atomicAdd(&dcl[cloc], pk);                 // LDS atomic, intra-CU
    }
    __syncthreads();

    // per-node: cnt, dinv pack, hist; thread-local sums for prefix scan
    int c[4];
    int lsum = 0;
    const int j0 = 4 * t;
#pragma unroll
    for (int i2 = 0; i2 < 4; ++i2) {
        int j = j0 + i2;
        int cv = 0;
        if (j < bs) {
            unsigned long long dv = dcl[j];
            cv = (int)(dv >> DC_CNT_SHIFT);
            float d  = (float)(dv & DC_FIX_MASK) * (1.0f / DC_FIX_SCALE);
            float di = d > 0.f ? rsqrtf(d) : 0.f;
            dc[lo + j] = (dv & ~DC_FIX_MASK) | (unsigned long long)__float_as_uint(di);
            atomicAdd(&lh[min(cv, 255)], 1);
        }
        c[i2] = cv;
        lsum += cv;
    }
    pfx[t] = lsum;
    __syncthreads();
    for (int off = 1; off < 1024; off <<= 1) {
        int v = 0;
        if (t >= off) v = pfx[t - off];
        __syncthreads();
        if (t >= off) pfx[t] += v;
        __syncthreads();
    }
    int run = bbase[b] + pfx[t] - lsum;   // exclusive prefix for node j0
#pragma unroll
    for (int i2 = 0; i2 < 4; ++i2) {
        int j = j0 + i2;
        if (j < bs) rp[lo + j] = run;
        run += c[i2];
    }
    __syncthreads();
    if (t < 256) {
        int cc = lh[t];
        if (cc > 0) atomicAdd(&hist[t], cc);       // one global atomic per bin
    }
}

// ---------------- scans (fallback path only) ----------------
__global__ __launch_bounds__(1024) void scan1(const unsigned long long* __restrict__ dc,
                                              int* __restrict__ rp,
                                              int* __restrict__ bsum, int n) {
    __shared__ int s[1024];
    int gid = blockIdx.x * 1024 + threadIdx.x;
    int v = (gid < n) ? (int)(((const unsigned*)dc)[2 * (size_t)gid + 1] >> (DC_CNT_SHIFT - 32)) : 0;
    s[threadIdx.x] = v;
    __syncthreads();
    for (int off = 1; off < 1024; off <<= 1) {
        int t = 0;
        if (threadIdx.x >= off) t = s[threadIdx.x - off];
        __syncthreads();
        if (threadIdx.x >= off) s[threadIdx.x] += t;
        __syncthreads();
    }
    if (gid < n) rp[gid] = s[threadIdx.x] - v;
    if (threadIdx.x == 1023) bsum[blockIdx.x] = s[1023];
}

__global__ __launch_bounds__(1024) void scan2(const int* __restrict__ bsum,
                                              int* __restrict__ bsx, int nb) {
    __shared__ int s[1024];
    int v = (threadIdx.x < nb) ? bsum[threadIdx.x] : 0;
    s[threadIdx.x] = v;
    __syncthreads();
    for (int off = 1; off < 1024; off <<= 1) {
        int t = 0;
        if (threadIdx.x >= off) t = s[threadIdx.x - off];
        __syncthreads();
        if (threadIdx.x >= off) s[threadIdx.x] += t;
        __syncthreads();
    }
    if (threadIdx.x < nb) bsx[threadIdx.x] = s[threadIdx.x] - v;
}

__global__ __launch_bounds__(1024) void scan3(int* __restrict__ rp, int* __restrict__ cursor,
                                              const int* __restrict__ bsx,
                                              unsigned long long* __restrict__ dc,
                                              int* __restrict__ hist,
                                              int n, int e) {
    __shared__ int lh[256];
    const int t = threadIdx.x;
    if (t < 256) lh[t] = 0;
    __syncthreads();
    int i = blockIdx.x * 1024 + t;
    if (i < n) {
        int v = rp[i] + bsx[i >> 10];
        rp[i] = v;
        cursor[i] = v;
        unsigned long long dv = dc[i];
        int c = (int)(dv >> DC_CNT_SHIFT);
        float d = (float)(dv & DC_FIX_MASK) * (1.0f / DC_FIX_SCALE);
        float di = d > 0.f ? rsqrtf(d) : 0.f;
        dc[i] = (dv & ~DC_FIX_MASK) | (unsigned long long)__float_as_uint(di);
        atomicAdd(&lh[min(c, 255)], 1);
    }
    __syncthreads();
    if (t < 256) {
        int c = lh[t];
        if (c > 0) atomicAdd(&hist[t], c);
    }
    if (i == 0) rp[n] = e;
}

// ---------------- fill CSR: legacy one-pass fallback ----------------
__global__ void fill(const void* __restrict__ ei, const void* __restrict__ w,
                     int* __restrict__ cursor, uint2* __restrict__ epack,
                     const int* __restrict__ flags, int e, int n) {
    const bool isbf = flags[0] != 0;
    const bool is64 = flags[1] != 0;
    int i = blockIdx.x * blockDim.x + threadIdx.x;
    if (i < e) {
        int r = ldi(ei, (size_t)i, is64);
        int c = ldi(ei, (size_t)e + i, is64);
        if ((unsigned)c < (unsigned)n) {
            bool rv = (unsigned)r < (unsigned)n;
            float wv = rv ? sane(ldf(w, i, isbf)) : 0.f;
            int pos = atomicAdd(&cursor[c], 1);
            epack[pos] = make_uint2(rv ? (unsigned)r : 0u, __float_as_uint(wv));
        }
    }
}

// ---------------- fillB: per-bucket placement with LDS cursors ----------------
__global__ __launch_bounds__(1024) void fillB(const int* __restrict__ rp,
                                              const uint2* __restrict__ stage,
                                              const int* __restrict__ bcnt,
                                              uint2* __restrict__ epack,
                                              int n, int k, int cap) {
    __shared__ int ncur[4096];
    const int b  = blockIdx.x;
    const int lo = b << k;
    const int hi = min(n, lo + (1 << k));
    const int t  = threadIdx.x;
    for (int j = t; j < hi - lo; j += 1024) ncur[j] = rp[lo + j];
    __syncthreads();
    const uint2* sb = stage + (size_t)b * cap;
    const int cnt_b = min(bcnt[b], cap);
    for (int s = t; s < cnt_b; s += 1024) {
        uint2 rec = sb[s];
        int cloc  = (int)(rec.x >> 20);
        unsigned r = rec.x & 0xFFFFFu;
        int pos = atomicAdd(&ncur[cloc], 1);
        epack[pos] = make_uint2(r, rec.y);
    }
}

// ---------------- degree-bucket scan ----------------
__global__ void hscan(const int* __restrict__ hist, int* __restrict__ hcur) {
    __shared__ int s[256];
    int v = hist[threadIdx.x];
    s[threadIdx.x] = v;
    __syncthreads();
    for (int off = 1; off < 256; off <<= 1) {
        int t = 0;
        if (threadIdx.x >= off) t = s[threadIdx.x - off];
        __syncthreads();
        if (threadIdx.x >= off) s[threadIdx.x] += t;
        __syncthreads();
    }
    hcur[threadIdx.x] = s[threadIdx.x] - v;  // exclusive
}

// ---------------- counting-sort placement, block-aggregated ----------------
__global__ __launch_bounds__(1024) void sortk(const unsigned long long* __restrict__ dc,
                                              int* __restrict__ hcur,
                                              int* __restrict__ order, int n) {
    __shared__ int lh[256];     // local histogram
    __shared__ int lbase[256];  // global base per bin for this block
    const int t = threadIdx.x;
    for (int b = t; b < 256; b += 1024) lh[b] = 0;
    __syncthreads();
    const int i = blockIdx.x * 1024 + t;
    int b = 0, lrank = 0;
    if (i < n) {
        b = min((int)(dc[i] >> DC_CNT_SHIFT), 255);
        lrank = atomicAdd(&lh[b], 1);  // LDS atomic: intra-block rank
    }
    __syncthreads();
    for (int bb = t; bb < 256; bb += 1024) {
        int c = lh[bb];
        lbase[bb] = (c > 0) ? atomicAdd(&hcur[bb], c) : 0;  // range reservation
    }
    __syncthreads();
    if (i < n) order[lbase[b] + lrank] = i;
}

// ---- layer1 GEMM via MFMA: G1 = bf16(dinv ⊙ (X[n,128] @ W1[128,64])) ----
__global__ __launch_bounds__(256) void gemm1_mfma(const void* __restrict__ x,
                                                  const void* __restrict__ W1,
                                                  const float* __restrict__ dinvp,
                                                  const int* __restrict__ flags,
                                                  unsigned short* __restrict__ G1,
                                                  int n) {
    const bool isbf = flags[0] != 0;
    __shared__ uint4 bfr[16 * 64];  // [ct*4+ks][lane], 16 KB
    for (int idx = threadIdx.x; idx < 16 * 64; idx += 256) {
        int lane = idx & 63, fr = idx >> 6;
        int ct = fr >> 2, ks = fr & 3;
        int k0 = ks * 32 + (lane >> 4) * 8;
        int col = ct * 16 + (lane & 15);
        unsigned short h[8];
#pragma unroll
        for (int j = 0; j < 8; ++j)
            h[j] = f2bfbits(ldf(W1, (size_t)(k0 + j) * 64 + col, isbf));
        bfr[idx] = make_uint4((unsigned)h[0] | ((unsigned)h[1] << 16),
                              (unsigned)h[2] | ((unsigned)h[3] << 16),
                              (unsigned)h[4] | ((unsigned)h[5] << 16),
                              (unsigned)h[6] | ((unsigned)h[7] << 16));
    }
    __syncthreads();

    const int lane = threadIdx.x & 63;
    const int m = lane & 15, q = lane >> 4;
    const int wid = (blockIdx.x * 256 + threadIdx.x) >> 6;
    const int nw  = (gridDim.x * 256) >> 6;
    const int nchunk = (n + 15) >> 4;

    for (int ch = wid; ch < nchunk; ch += nw) {
        const int row0 = ch * 16;
        const int rA = min(row0 + m, n - 1);
        V8 a[4];
        if (isbf) {
            const uint4* xr = (const uint4*)((const bf16*)x + (size_t)rA * 128);
#pragma unroll
            for (int ks = 0; ks < 4; ++ks) a[ks].u = xr[ks * 4 + q];
        } else {
            const float4* xr4 = (const float4*)((const float*)x + (size_t)rA * 128);
#pragma unroll
            for (int ks = 0; ks < 4; ++ks) {
                float4 v0 = xr4[ks * 8 + q * 2];
                float4 v1 = xr4[ks * 8 + q * 2 + 1];
                a[ks].u = make_uint4(pack2(v0.x, v0.y), pack2(v0.z, v0.w),
                                     pack2(v1.x, v1.y), pack2(v1.z, v1.w));
            }
        }
#pragma unroll
        for (int ct = 0; ct < 4; ++ct) {
            f32x4 acc = {0.f, 0.f, 0.f, 0.f};
#pragma unroll
            for (int ks = 0; ks < 4; ++ks) {
                V8 b; b.u = bfr[(ct * 4 + ks) * 64 + lane];
                acc = __builtin_amdgcn_mfma_f32_16x16x32_bf16(a[ks].v, b.v, acc, 0, 0, 0);
            }
#pragma unroll
            for (int r = 0; r < 4; ++r) {
                int row = row0 + q * 4 + r;
                if (row < n)
                    G1[(size_t)row * 64 + ct * 16 + m] = f2bfbits(dinvp[2 * (size_t)row] * acc[r]);
            }
        }
    }
}

// ---- gather core: 8 lanes/node, uint4/lane, depth-8 + epack prefetch ----
__device__ __forceinline__ void gacc8(const int* __restrict__ rp,
                                      const uint2* __restrict__ epack,
                                      const uint4* __restrict__ Gv,
                                      int node, int sub, float acc[8]) {
    uint4 self = Gv[(size_t)node * 8 + sub];
    acc[0] = lo16(self.x); acc[1] = hi16(self.x);
    acc[2] = lo16(self.y); acc[3] = hi16(self.y);
    acc[4] = lo16(self.z); acc[5] = hi16(self.z);
    acc[6] = lo16(self.w); acc[7] = hi16(self.w);

    const int s0 = rp[node], s1 = rp[node + 1];
    const uint2 fb = make_uint2((unsigned)node, 0u);
    int idx = s0 + sub;
    uint2 ld = (idx < s1) ? nt_ld2(&epack[idx]) : fb;
    for (int base = s0; base < s1; base += 8) {
        int nidx = base + 8 + sub;
        uint2 nld = (nidx < s1) ? nt_ld2(&epack[nidx]) : fb;  // prefetch next batch
        int rr[8]; float wv[8];
#pragma unroll
        for (int u = 0; u < 8; ++u) {
            rr[u] = __shfl((int)ld.x, u, 8);
            wv[u] = __uint_as_float((unsigned)__shfl((int)ld.y, u, 8));
        }
        uint4 gp[8];
#pragma unroll
        for (int u = 0; u < 8; ++u) gp[u] = Gv[(size_t)rr[u] * 8 + sub];
#pragma unroll
        for (int u = 0; u < 8; ++u) {
            acc[0] = fmaf(wv[u], lo16(gp[u].x), acc[0]);
            acc[1] = fmaf(wv[u], hi16(gp[u].x), acc[1]);
            acc[2] = fmaf(wv[u], lo16(gp[u].y), acc[2]);
            acc[3] = fmaf(wv[u], hi16(gp[u].y), acc[3]);
            acc[4] = fmaf(wv[u], lo16(gp[u].z), acc[4]);
            acc[5] = fmaf(wv[u], hi16(gp[u].z), acc[5]);
            acc[6] = fmaf(wv[u], lo16(gp[u].w), acc[6]);
            acc[7] = fmaf(wv[u], hi16(gp[u].w), acc[7]);
        }
        ld = nld;
    }
}

// ---- agg1: acc -> relu/bias/dinv -> G2 ----
// (256,4): the (256,8) bound forces VGPR<=32 and spills gp[8] (round 7: 2.5x slower)
__global__ __launch_bounds__(256, 4) void agg1(const int* __restrict__ rp,
                                               const uint2* __restrict__ epack,
                                               const int* __restrict__ order,
                                               const uint4* __restrict__ G1v,
                                               const float* __restrict__ dinvp,
                                               const void* __restrict__ b1,
                                               const int* __restrict__ flags,
                                               uint4* __restrict__ G2v, int n) {
    const bool isbf = flags[0] != 0;
    const int sub = threadIdx.x & 7;
    const int g   = (blockIdx.x * 256 + threadIdx.x) >> 3;
    if (g >= n) return;
    const int node = order[g];

    float acc[8];
    gacc8(rp, epack, G1v, node, sub, acc);

    const float dv = dinvp[2 * (size_t)node];
    unsigned o[4];
#pragma unroll
    for (int t = 0; t < 4; ++t) {
        float h0 = dv * acc[2 * t]     + ldf(b1, 8 * sub + 2 * t, isbf);
        float h1 = dv * acc[2 * t + 1] + ldf(b1, 8 * sub + 2 * t + 1, isbf);
        h0 = h0 > 0.f ? h0 : 0.f;
        h1 = h1 > 0.f ? h1 : 0.f;
        o[t] = pack2(dv * h0, dv * h1);
    }
    nt_st4(&G2v[(size_t)node * 8 + sub], make_uint4(o[0], o[1], o[2], o[3]));
}

// ---- agg2out: gather (agg2) fused with out = T @ W2 + b2 (outgemm) ----
__global__ __launch_bounds__(256, 4) void agg2out(const int* __restrict__ rp,
                                                  const uint2* __restrict__ epack,
                                                  const int* __restrict__ order,
                                                  const uint4* __restrict__ G2v,
                                                  const float* __restrict__ dinvp,
                                                  const void* __restrict__ W2,
                                                  const void* __restrict__ b2,
                                                  const int* __restrict__ flags,
                                                  void* __restrict__ outp, int n) {
    const bool isbf = flags[0] != 0;
    __shared__ uint4 bfr[16 * 64];   // W2 fragments [ct*2+ks][lane], 16 KB
    __shared__ float b2s[128];
    __shared__ uint4 tls[32 * 8];    // 32 node-rows of bf16 T, 4 KB
    __shared__ int   nds[32];
    for (int idx = threadIdx.x; idx < 16 * 64; idx += 256) {
        int lane = idx & 63, fr = idx >> 6;
        int ct = fr >> 1, ks = fr & 1;
        int k0 = ks * 32 + (lane >> 4) * 8;
        int col = ct * 16 + (lane & 15);
        unsigned short h[8];
#pragma unroll
        for (int j = 0; j < 8; ++j)
            h[j] = f2bfbits(ldf(W2, (size_t)(k0 + j) * 128 + col, isbf));
        bfr[idx] = make_uint4((unsigned)h[0] | ((unsigned)h[1] << 16),
                              (unsigned)h[2] | ((unsigned)h[3] << 16),
                              (unsigned)h[4] | ((unsigned)h[5] << 16),
                              (unsigned)h[6] | ((unsigned)h[7] << 16));
    }
    for (int i = threadIdx.x; i < 128; i += 256) b2s[i] = ldf(b2, i, isbf);
    __syncthreads();

    const int sub  = threadIdx.x & 7;
    const int lg   = threadIdx.x >> 3;         // local node 0..31
    const int lane = threadIdx.x & 63;
    const int m = lane & 15, q = lane >> 4;
    const int wid = threadIdx.x >> 6;          // wave 0..3
    const int ntile = (n + 31) >> 5;

    for (int tile = blockIdx.x; tile < ntile; tile += gridDim.x) {
        const int g = tile * 32 + lg;
        uint4 o = make_uint4(0u, 0u, 0u, 0u);
        int node = 0;
        if (g < n) {                            // group-uniform (8 lanes share g)
            node = order[g];
            float acc[8];
            gacc8(rp, epack, G2v, node, sub, acc);
            const float dv = dinvp[2 * (size_t)node];
            o.x = pack2(dv * acc[0], dv * acc[1]);
            o.y = pack2(dv * acc[2], dv * acc[3]);
            o.z = pack2(dv * acc[4], dv * acc[5]);
            o.w = pack2(dv * acc[6], dv * acc[7]);
        }
        tls[lg * 8 + sub] = o;
        if (sub == 0) nds[lg] = node;
        __syncthreads();

        // MFMA epilogue: waves 0,1 -> rows [0,16), waves 2,3 -> rows [16,32)
        const int chunk = wid >> 1;
        const int lrow  = chunk * 16 + m;
        V8 a0, a1;
        a0.u = tls[lrow * 8 + q];
        a1.u = tls[lrow * 8 + 4 + q];
#pragma unroll
        for (int c8 = 0; c8 < 4; ++c8) {
            const int ct = (wid & 1) * 4 + c8;
            f32x4 acc4 = {0.f, 0.f, 0.f, 0.f};
            V8 b0; b0.u = bfr[(ct * 2 + 0) * 64 + lane];
            acc4 = __builtin_amdgcn_mfma_f32_16x16x32_bf16(a0.v, b0.v, acc4, 0, 0, 0);
            V8 b1; b1.u = bfr[(ct * 2 + 1) * 64 + lane];
            acc4 = __builtin_amdgcn_mfma_f32_16x16x32_bf16(a1.v, b1.v, acc4, 0, 0, 0);
            const int col = ct * 16 + m;
            const float bb = b2s[col];
#pragma unroll
            for (int r = 0; r < 4; ++r) {
                int lr = chunk * 16 + q * 4 + r;
                int gg = tile * 32 + lr;
                if (gg < n) {
                    float ov = acc4[r] + bb;
                    int nd = nds[lr];
                    if (isbf) ((bf16*)outp)[(size_t)nd * 128 + col] = __float2bfloat16(ov);
                    else      ((float*)outp)[(size_t)nd * 128 + col] = ov;
                }
            }
        }
        __syncthreads();   // protect tls/nds for next tile
    }
}

extern "C" void kernel_launch(void* const* d_in, const int* in_sizes, int n_in,
                              void* d_out, int out_size, void* d_ws, size_t ws_size,
                              hipStream_t stream) {
    const void* x  = d_in[0];
    const void* ei = d_in[1];
    const void* ew = d_in[2];
    const void* W1 = d_in[3];
    const void* b1 = d_in[4];
    const void* W2 = d_in[5];
    const void* b2 = d_in[6];

    const int n = in_sizes[0] / 128;   // 100000
    const int e = in_sizes[2];         // 1600000
    const int nb = (n + 1023) / 1024;

    // ws layout (4B words) -- identical footprint to the round-4 passing build:
    // flags(8) | dc(2n, u64) | rp(n+1) | cursor(n) | bsum(1024) | bsx(1024)
    // | pad | epack(2e) | G1/T(32n) | G2(32n)
    // aliases: hist = bsum+512, hcur = bsx+512, bcnt = bsx+256, bbase = bsum;
    //          order = cursor (dead after fillB); stage = G1 region (G1+G2).
    int*   flags  = (int*)d_ws;
    unsigned long long* dc = (unsigned long long*)((int*)d_ws + 8);
    int*   rp     = (int*)d_ws + 8 + 2 * (size_t)n;
    int*   cursor = rp + n + 1;
    int*   bsum   = cursor + n;
    int*   bsx    = bsum + 1024;
    int*   hist   = bsum + 512;
    int*   hcur   = bsx + 512;
    int*   bcnt   = bsx + 256;
    int*   bbase  = bsum;                        // fastpath: scans don't use bsum
    int*   order  = cursor;                      // alias, valid post-fill
    size_t w_off  = (size_t)(8 + 4 * (size_t)n + 1 + 2048);
    w_off = (w_off + 3) & ~(size_t)3;            // 16B align
    uint2*    epack = (uint2*)((int*)d_ws + w_off);
    size_t g_off = w_off + 2 * (size_t)e;
    g_off = (g_off + 3) & ~(size_t)3;
    unsigned* G1 = (unsigned*)d_ws + g_off;      // 32n uints (bf16x2), 16B aligned
    unsigned* G2 = G1 + (size_t)n * 32;

    const float* dinvp = (const float*)dc;       // dinv at dinvp[2*node]
    uint2* stage = (uint2*)G1;                   // alias: G1+G2, dead until gemm1

    // bucket parameters: bucket = 2^k node range, beff buckets (<=256)
    int bs0 = (n + 255) / 256;
    int k = 0;
    while ((1 << k) < bs0) ++k;
    int beff = (n + (1 << k) - 1) >> k;          // <= 256
    int cap  = (int)((32 * (size_t)n) / (size_t)beff);   // stage records/bucket
    size_t mean = ((size_t)e + beff - 1) / beff;
    bool fastfill = (n <= (1 << 18)) && (k <= 12) &&
                    ((size_t)cap >= mean + mean / 2 + 1024);

    // gemm grid: ~1 chunk per wave, capped
    const int nchunk = (n + 15) >> 4;
    int ggrid = (nchunk + 3) / 4;
    if (ggrid > 2048) ggrid = 2048;
    if (ggrid < 192)  ggrid = 192;

    initk<<<fastfill ? 1 : (n + 255) / 256, 256, 0, stream>>>(
        dc, hist, bcnt, n, fastfill ? 0 : 1,
        (const unsigned*)W1, (const unsigned*)ei, flags);
    if (fastfill) {
        binA<<<(e + 4095) / 4096, 1024, 0, stream>>>(ei, ew, bcnt, stage, flags, e, n, k, cap);
        bscan<<<1, 256, 0, stream>>>(bcnt, bbase, rp, n, beff);
        degscanB<<<beff, 1024, 0, stream>>>(stage, bcnt, bbase, dc, rp, hist, n, k, cap);
        fillB<<<beff, 1024, 0, stream>>>(rp, stage, bcnt, epack, n, k, cap);
    } else {
        degcnt<<<(e + 255) / 256, 256, 0, stream>>>(ei, ew, dc, flags, e, n);
        scan1<<<nb, 1024, 0, stream>>>(dc, rp, bsum, n);
        scan2<<<1, 1024, 0, stream>>>(bsum, bsx, nb);
        scan3<<<nb, 1024, 0, stream>>>(rp, cursor, bsx, dc, hist, n, e);
        fill<<<(e + 255) / 256, 256, 0, stream>>>(ei, ew, cursor, epack, flags, e, n);
    }
    hscan<<<1, 256, 0, stream>>>(hist, hcur);
    sortk<<<nb, 1024, 0, stream>>>(dc, hcur, order, n);

    gemm1_mfma<<<ggrid, 256, 0, stream>>>(x, W1, dinvp, flags, (unsigned short*)G1, n);
    agg1<<<(n * 8 + 255) / 256, 256, 0, stream>>>(rp, epack, order, (const uint4*)G1,
                                                  dinvp, b1, flags, (uint4*)G2, n);
    int a2grid = (n + 31) / 32;
    if (a2grid > 1024) a2grid = 1024;            // grid-stride: stage W2 once/block
    agg2out<<<a2grid, 256, 0, stream>>>(rp, epack, order, (const uint4*)G2,
                                        dinvp, W2, b2, flags, d_out, n);
}

// Round 12
// 332.153 us; speedup vs baseline: 1.6743x; 1.0092x over previous
//
#include <hip/hip_runtime.h>
#include <hip/hip_bf16.h>

typedef __hip_bfloat16 bf16;
typedef __attribute__((ext_vector_type(8))) short short8;
typedef __attribute__((ext_vector_type(4))) float f32x4;
typedef __attribute__((ext_vector_type(2))) unsigned uv2;   // nontemporal-compatible
typedef __attribute__((ext_vector_type(4))) unsigned uv4;   // nontemporal-compatible
union V8 { uint4 u; short8 v; };

__device__ __forceinline__ float bf2f(bf16 v) { return __bfloat162float(v); }
__device__ __forceinline__ float lo16(unsigned u) { return __uint_as_float((u & 0xffffu) << 16); }
__device__ __forceinline__ float hi16(unsigned u) { return __uint_as_float(u & 0xffff0000u); }
__device__ __forceinline__ unsigned short f2bfbits(float f) {
    return (unsigned short)(__hip_bfloat16_raw(__float2bfloat16(f)).x);
}
__device__ __forceinline__ unsigned pack2(float a, float b) {
    return (unsigned)f2bfbits(a) | ((unsigned)f2bfbits(b) << 16);
}

// dtype-dispatching loads (flag-driven, uniform branch)
__device__ __forceinline__ float ldf(const void* p, size_t i, bool isbf) {
    return isbf ? bf2f(((const bf16*)p)[i]) : ((const float*)p)[i];
}
__device__ __forceinline__ int ldi(const void* p, size_t i, bool is64) {
    return is64 ? (int)((const long long*)p)[i] : ((const int*)p)[i];
}
__device__ __forceinline__ float sane(float v) {
    return (v == v && fabsf(v) < 1e30f) ? v : 0.f;
}

// nontemporal helpers over HIP vector structs
__device__ __forceinline__ uint2 nt_ld2(const uint2* p) {
    uv2 v = __builtin_nontemporal_load((const uv2*)p);
    return make_uint2(v.x, v.y);
}
__device__ __forceinline__ void nt_st4(uint4* p, uint4 v) {
    uv4 t; t.x = v.x; t.y = v.y; t.z = v.z; t.w = v.w;
    __builtin_nontemporal_store(t, (uv4*)p);
}

// dc[node] packed layout (built by degscanFill / legacy degcnt):
//   bits [44:63] : in-degree count (20 bits)
//   bits [ 0:43] : weighted degree, 22.22 unsigned fixed point
// After degscanFill/scan3:
//   bits [44:63] : in-degree count (still valid, for sortk)
//   bits [ 0:31] : dinv as f32 bits  -> readable as ((const float*)dc)[2*node]
#define DC_CNT_SHIFT 44
#define DC_FIX_MASK  0xFFFFFFFFFFFULL
#define DC_FIX_SCALE 4194304.0f   /* 2^22 */

// ---------------- init (+ fused dtype detection in block 0) ----------------
// In the fastpath initdc==0 -> launched with ONE block (only hist/bcnt/detect).
__global__ void initk(unsigned long long* __restrict__ dc, int* __restrict__ hist,
                      int* __restrict__ bcnt, int n, int initdc,
                      const unsigned* __restrict__ w1w, const unsigned* __restrict__ eiw,
                      int* __restrict__ flags) {
    int i = blockIdx.x * blockDim.x + threadIdx.x;
    if (initdc && i < n) dc[i] = (unsigned long long)(1u << 22);  // deg = 1.0
    if (i < 256) { hist[i] = 0; bcnt[i] = 0; }
    if (blockIdx.x == 0) {
        __shared__ int cnt[2];
        if (threadIdx.x < 2) cnt[threadIdx.x] = 0;
        __syncthreads();
        int c0 = 0;
        for (int j = threadIdx.x; j < 4096; j += 256) {
            unsigned u = w1w[j];
            unsigned e0 = (u >> 7) & 0xFFu, e1 = (u >> 23) & 0xFFu;
            if (e0 <= 125u && e1 <= 125u) c0++;
        }
        int c1 = 0;
        for (int j = threadIdx.x; j < 2048; j += 256)
            if (eiw[2 * j + 1] == 0u) c1++;
        atomicAdd(&cnt[0], c0);
        atomicAdd(&cnt[1], c1);
        __syncthreads();
        if (threadIdx.x == 0) {
            flags[0] = (cnt[0] >= 3072) ? 1 : 0;
            flags[1] = (cnt[1] >= 1024) ? 1 : 0;
        }
    }
}

// ------------- legacy degcnt (fallback path only): one u64 atomic/edge -------
__global__ void degcnt(const void* __restrict__ ei, const void* __restrict__ w,
                       unsigned long long* __restrict__ dc,
                       const int* __restrict__ flags, int e, int n) {
    const bool isbf = flags[0] != 0;
    const bool is64 = flags[1] != 0;
    int i = blockIdx.x * blockDim.x + threadIdx.x;
    if (i < e) {
        int c = ldi(ei, (size_t)e + i, is64);
        if ((unsigned)c < (unsigned)n) {
            float wv = sane(ldf(w, i, isbf));
            wv = fminf(fmaxf(wv, 0.f), 1024.f);   // keep fixed-point in range
            unsigned long long pk = (1ULL << DC_CNT_SHIFT)
                                  + (unsigned long long)llrintf(wv * DC_FIX_SCALE);
            atomicAdd(&dc[c], pk);
        }
    }
}

// ---------------- binA: bin edges by node-bucket, DIRECT stage writes --------
__global__ __launch_bounds__(1024) void binA(const void* __restrict__ ei,
                                             const void* __restrict__ w,
                                             int* __restrict__ bcnt,
                                             uint2* __restrict__ stage,
                                             const int* __restrict__ flags,
                                             int e, int n, int k, int cap) {
    __shared__ int lh[256], lbase[256];
    const bool isbf = flags[0] != 0;
    const bool is64 = flags[1] != 0;
    const int t = threadIdx.x;
    if (t < 256) lh[t] = 0;
    __syncthreads();

    int b_[4], lr_[4], valid_[4];
    uint2 rec_[4];
    const int base = blockIdx.x * 4096;
#pragma unroll
    for (int u = 0; u < 4; ++u) {
        int i = base + u * 1024 + t;
        valid_[u] = 0;
        if (i < e) {
            int r = ldi(ei, (size_t)i, is64);
            int c = ldi(ei, (size_t)e + i, is64);
            if ((unsigned)c < (unsigned)n) {
                bool rv = (unsigned)r < (unsigned)n;
                float wv = rv ? sane(ldf(w, i, isbf)) : 0.f;
                int b = c >> k;
                unsigned cloc = (unsigned)(c - (b << k));
                rec_[u] = make_uint2((cloc << 20) | (rv ? (unsigned)r : 0u),
                                     __float_as_uint(wv));
                b_[u] = b;
                lr_[u] = atomicAdd(&lh[b], 1);
                valid_[u] = 1;
            }
        }
    }
    __syncthreads();
    if (t < 256) {
        int c = lh[t];
        lbase[t] = (c > 0) ? atomicAdd(&bcnt[t], c) : 0;   // range reservation
    }
    __syncthreads();
#pragma unroll
    for (int u = 0; u < 4; ++u)
        if (valid_[u]) {
            unsigned gi = (unsigned)(lbase[b_[u]] + lr_[u]);
            if (gi < (unsigned)cap)                         // clamp (impossible)
                stage[(size_t)b_[u] * cap + gi] = rec_[u];
        }
}

// ---------------- bscan: bucket-level exclusive scan (1 block) ---------------
__global__ void bscan(const int* __restrict__ bcnt, int* __restrict__ bbase,
                      int* __restrict__ rp, int n, int beff) {
    __shared__ int s[256];
    const int t = threadIdx.x;
    int v = (t < beff) ? bcnt[t] : 0;
    s[t] = v;
    __syncthreads();
    for (int off = 1; off < 256; off <<= 1) {
        int x = 0;
        if (t >= off) x = s[t - off];
        __syncthreads();
        if (t >= off) s[t] += x;
        __syncthreads();
    }
    bbase[t] = s[t] - v;
    if (t == 255) rp[n] = s[255];
}

// ---- degscanFill: per-bucket count+degree + local prefix -> rp/dinv/hist,
// then CSR placement in the same kernel (old degscanB + fillB fused).
// The placement phase re-reads the bucket's 64KB stage slice L2-HOT and uses
// LDS cursors seeded from the freshly computed local rp values (no global
// rp re-read, no separate launch). ncur aliases dcl: all dcl reads complete
// before the prefix-scan barriers, so the reuse is race-free.
__global__ __launch_bounds__(1024) void degscanFill(const uint2* __restrict__ stage,
                                                    const int* __restrict__ bcnt,
                                                    const int* __restrict__ bbase,
                                                    unsigned long long* __restrict__ dc,
                                                    int* __restrict__ rp,
                                                    int* __restrict__ hist,
                                                    uint2* __restrict__ epack,
                                                    int n, int k, int cap) {
    __shared__ unsigned long long dcl[4096];
    __shared__ int pfx[1024];
    __shared__ int lh[256];
    const int b  = blockIdx.x;
    const int lo = b << k;
    const int hi = min(n, lo + (1 << k));
    const int bs = hi - lo;
    const int t  = threadIdx.x;
    if (t < 256) lh[t] = 0;
    for (int j = t; j < bs; j += 1024)
        dcl[j] = (unsigned long long)(1u << 22);   // self-loop: deg = 1.0
    __syncthreads();
    const uint2* sb = stage + (size_t)b * cap;
    const int cnt_b = min(bcnt[b], cap);
    for (int s = t; s < cnt_b; s += 1024) {
        uint2 rec = sb[s];
        int cloc  = (int)(rec.x >> 20);
        float wv  = __uint_as_float(rec.y);
        wv = fminf(fmaxf(wv, 0.f), 1024.f);
        unsigned long long pk = (1ULL << DC_CNT_SHIFT)
                              + (unsigned long long)llrintf(wv * DC_FIX_SCALE);
        atomicAdd(&dcl[cloc], pk);                 // LDS atomic, intra-CU
    }
    __syncthreads();

    // per-node: cnt, dinv pack, hist; thread-local sums for prefix scan
    int c[4];
    int lsum = 0;
    const int j0 = 4 * t;
#pragma unroll
    for (int i2 = 0; i2 < 4; ++i2) {
        int j = j0 + i2;
        int cv = 0;
        if (j < bs) {
            unsigned long long dv = dcl[j];
            cv = (int)(dv >> DC_CNT_SHIFT);
            float d  = (float)(dv & DC_FIX_MASK) * (1.0f / DC_FIX_SCALE);
            float di = d > 0.f ? rsqrtf(d) : 0.f;
            dc[lo + j] = (dv & ~DC_FIX_MASK) | (unsigned long long)__float_as_uint(di);
            atomicAdd(&lh[min(cv, 255)], 1);
        }
        c[i2] = cv;
        lsum += cv;
    }
    pfx[t] = lsum;
    __syncthreads();                 // <- after this, no thread reads dcl again
    for (int off = 1; off < 1024; off <<= 1) {
        int v = 0;
        if (t >= off) v = pfx[t - off];
        __syncthreads();
        if (t >= off) pfx[t] += v;
        __syncthreads();
    }
    int run = bbase[b] + pfx[t] - lsum;   // exclusive prefix for node j0
    int* ncur = (int*)dcl;                // safe alias (see header comment)
#pragma unroll
    for (int i2 = 0; i2 < 4; ++i2) {
        int j = j0 + i2;
        if (j < bs) { rp[lo + j] = run; ncur[j] = run; }
        run += c[i2];
    }
    __syncthreads();
    if (t < 256) {
        int cc = lh[t];
        if (cc > 0) atomicAdd(&hist[t], cc);       // one global atomic per bin
    }
    // placement phase (old fillB): stage slice is L2-hot from the count pass
    for (int s = t; s < cnt_b; s += 1024) {
        uint2 rec = sb[s];
        int cloc  = (int)(rec.x >> 20);
        unsigned r = rec.x & 0xFFFFFu;
        int pos = atomicAdd(&ncur[cloc], 1);
        epack[pos] = make_uint2(r, rec.y);
    }
}

// ---------------- scans (fallback path only) ----------------
__global__ __launch_bounds__(1024) void scan1(const unsigned long long* __restrict__ dc,
                                              int* __restrict__ rp,
                                              int* __restrict__ bsum, int n) {
    __shared__ int s[1024];
    int gid = blockIdx.x * 1024 + threadIdx.x;
    int v = (gid < n) ? (int)(((const unsigned*)dc)[2 * (size_t)gid + 1] >> (DC_CNT_SHIFT - 32)) : 0;
    s[threadIdx.x] = v;
    __syncthreads();
    for (int off = 1; off < 1024; off <<= 1) {
        int t = 0;
        if (threadIdx.x >= off) t = s[threadIdx.x - off];
        __syncthreads();
        if (threadIdx.x >= off) s[threadIdx.x] += t;
        __syncthreads();
    }
    if (gid < n) rp[gid] = s[threadIdx.x] - v;
    if (threadIdx.x == 1023) bsum[blockIdx.x] = s[1023];
}

__global__ __launch_bounds__(1024) void scan2(const int* __restrict__ bsum,
                                              int* __restrict__ bsx, int nb) {
    __shared__ int s[1024];
    int v = (threadIdx.x < nb) ? bsum[threadIdx.x] : 0;
    s[threadIdx.x] = v;
    __syncthreads();
    for (int off = 1; off < 1024; off <<= 1) {
        int t = 0;
        if (threadIdx.x >= off) t = s[threadIdx.x - off];
        __syncthreads();
        if (threadIdx.x >= off) s[threadIdx.x] += t;
        __syncthreads();
    }
    if (threadIdx.x < nb) bsx[threadIdx.x] = s[threadIdx.x] - v;
}

__global__ __launch_bounds__(1024) void scan3(int* __restrict__ rp, int* __restrict__ cursor,
                                              const int* __restrict__ bsx,
                                              unsigned long long* __restrict__ dc,
                                              int* __restrict__ hist,
                                              int n, int e) {
    __shared__ int lh[256];
    const int t = threadIdx.x;
    if (t < 256) lh[t] = 0;
    __syncthreads();
    int i = blockIdx.x * 1024 + t;
    if (i < n) {
        int v = rp[i] + bsx[i >> 10];
        rp[i] = v;
        cursor[i] = v;
        unsigned long long dv = dc[i];
        int c = (int)(dv >> DC_CNT_SHIFT);
        float d = (float)(dv & DC_FIX_MASK) * (1.0f / DC_FIX_SCALE);
        float di = d > 0.f ? rsqrtf(d) : 0.f;
        dc[i] = (dv & ~DC_FIX_MASK) | (unsigned long long)__float_as_uint(di);
        atomicAdd(&lh[min(c, 255)], 1);
    }
    __syncthreads();
    if (t < 256) {
        int c = lh[t];
        if (c > 0) atomicAdd(&hist[t], c);
    }
    if (i == 0) rp[n] = e;
}

// ---------------- fill CSR: legacy one-pass fallback ----------------
__global__ void fill(const void* __restrict__ ei, const void* __restrict__ w,
                     int* __restrict__ cursor, uint2* __restrict__ epack,
                     const int* __restrict__ flags, int e, int n) {
    const bool isbf = flags[0] != 0;
    const bool is64 = flags[1] != 0;
    int i = blockIdx.x * blockDim.x + threadIdx.x;
    if (i < e) {
        int r = ldi(ei, (size_t)i, is64);
        int c = ldi(ei, (size_t)e + i, is64);
        if ((unsigned)c < (unsigned)n) {
            bool rv = (unsigned)r < (unsigned)n;
            float wv = rv ? sane(ldf(w, i, isbf)) : 0.f;
            int pos = atomicAdd(&cursor[c], 1);
            epack[pos] = make_uint2(rv ? (unsigned)r : 0u, __float_as_uint(wv));
        }
    }
}

// ---------------- degree-bucket scan ----------------
__global__ void hscan(const int* __restrict__ hist, int* __restrict__ hcur) {
    __shared__ int s[256];
    int v = hist[threadIdx.x];
    s[threadIdx.x] = v;
    __syncthreads();
    for (int off = 1; off < 256; off <<= 1) {
        int t = 0;
        if (threadIdx.x >= off) t = s[threadIdx.x - off];
        __syncthreads();
        if (threadIdx.x >= off) s[threadIdx.x] += t;
        __syncthreads();
    }
    hcur[threadIdx.x] = s[threadIdx.x] - v;  // exclusive
}

// ---------------- counting-sort placement, block-aggregated ----------------
__global__ __launch_bounds__(1024) void sortk(const unsigned long long* __restrict__ dc,
                                              int* __restrict__ hcur,
                                              int* __restrict__ order, int n) {
    __shared__ int lh[256];     // local histogram
    __shared__ int lbase[256];  // global base per bin for this block
    const int t = threadIdx.x;
    for (int b = t; b < 256; b += 1024) lh[b] = 0;
    __syncthreads();
    const int i = blockIdx.x * 1024 + t;
    int b = 0, lrank = 0;
    if (i < n) {
        b = min((int)(dc[i] >> DC_CNT_SHIFT), 255);
        lrank = atomicAdd(&lh[b], 1);  // LDS atomic: intra-block rank
    }
    __syncthreads();
    for (int bb = t; bb < 256; bb += 1024) {
        int c = lh[bb];
        lbase[bb] = (c > 0) ? atomicAdd(&hcur[bb], c) : 0;  // range reservation
    }
    __syncthreads();
    if (i < n) order[lbase[b] + lrank] = i;
}

// ---- layer1 GEMM via MFMA: G1 = bf16(dinv ⊙ (X[n,128] @ W1[128,64])) ----
__global__ __launch_bounds__(256) void gemm1_mfma(const void* __restrict__ x,
                                                  const void* __restrict__ W1,
                                                  const float* __restrict__ dinvp,
                                                  const int* __restrict__ flags,
                                                  unsigned short* __restrict__ G1,
                                                  int n) {
    const bool isbf = flags[0] != 0;
    __shared__ uint4 bfr[16 * 64];  // [ct*4+ks][lane], 16 KB
    for (int idx = threadIdx.x; idx < 16 * 64; idx += 256) {
        int lane = idx & 63, fr = idx >> 6;
        int ct = fr >> 2, ks = fr & 3;
        int k0 = ks * 32 + (lane >> 4) * 8;
        int col = ct * 16 + (lane & 15);
        unsigned short h[8];
#pragma unroll
        for (int j = 0; j < 8; ++j)
            h[j] = f2bfbits(ldf(W1, (size_t)(k0 + j) * 64 + col, isbf));
        bfr[idx] = make_uint4((unsigned)h[0] | ((unsigned)h[1] << 16),
                              (unsigned)h[2] | ((unsigned)h[3] << 16),
                              (unsigned)h[4] | ((unsigned)h[5] << 16),
                              (unsigned)h[6] | ((unsigned)h[7] << 16));
    }
    __syncthreads();

    const int lane = threadIdx.x & 63;
    const int m = lane & 15, q = lane >> 4;
    const int wid = (blockIdx.x * 256 + threadIdx.x) >> 6;
    const int nw  = (gridDim.x * 256) >> 6;
    const int nchunk = (n + 15) >> 4;

    for (int ch = wid; ch < nchunk; ch += nw) {
        const int row0 = ch * 16;
        const int rA = min(row0 + m, n - 1);
        V8 a[4];
        if (isbf) {
            const uint4* xr = (const uint4*)((const bf16*)x + (size_t)rA * 128);
#pragma unroll
            for (int ks = 0; ks < 4; ++ks) a[ks].u = xr[ks * 4 + q];
        } else {
            const float4* xr4 = (const float4*)((const float*)x + (size_t)rA * 128);
#pragma unroll
            for (int ks = 0; ks < 4; ++ks) {
                float4 v0 = xr4[ks * 8 + q * 2];
                float4 v1 = xr4[ks * 8 + q * 2 + 1];
                a[ks].u = make_uint4(pack2(v0.x, v0.y), pack2(v0.z, v0.w),
                                     pack2(v1.x, v1.y), pack2(v1.z, v1.w));
            }
        }
#pragma unroll
        for (int ct = 0; ct < 4; ++ct) {
            f32x4 acc = {0.f, 0.f, 0.f, 0.f};
#pragma unroll
            for (int ks = 0; ks < 4; ++ks) {
                V8 b; b.u = bfr[(ct * 4 + ks) * 64 + lane];
                acc = __builtin_amdgcn_mfma_f32_16x16x32_bf16(a[ks].v, b.v, acc, 0, 0, 0);
            }
#pragma unroll
            for (int r = 0; r < 4; ++r) {
                int row = row0 + q * 4 + r;
                if (row < n)
                    G1[(size_t)row * 64 + ct * 16 + m] = f2bfbits(dinvp[2 * (size_t)row] * acc[r]);
            }
        }
    }
}

// ---- gather core: 8 lanes/node, uint4/lane, depth-8 + epack prefetch ----
__device__ __forceinline__ void gacc8(const int* __restrict__ rp,
                                      const uint2* __restrict__ epack,
                                      const uint4* __restrict__ Gv,
                                      int node, int sub, float acc[8]) {
    uint4 self = Gv[(size_t)node * 8 + sub];
    acc[0] = lo16(self.x); acc[1] = hi16(self.x);
    acc[2] = lo16(self.y); acc[3] = hi16(self.y);
    acc[4] = lo16(self.z); acc[5] = hi16(self.z);
    acc[6] = lo16(self.w); acc[7] = hi16(self.w);

    const int s0 = rp[node], s1 = rp[node + 1];
    const uint2 fb = make_uint2((unsigned)node, 0u);
    int idx = s0 + sub;
    uint2 ld = (idx < s1) ? nt_ld2(&epack[idx]) : fb;
    for (int base = s0; base < s1; base += 8) {
        int nidx = base + 8 + sub;
        uint2 nld = (nidx < s1) ? nt_ld2(&epack[nidx]) : fb;  // prefetch next batch
        int rr[8]; float wv[8];
#pragma unroll
        for (int u = 0; u < 8; ++u) {
            rr[u] = __shfl((int)ld.x, u, 8);
            wv[u] = __uint_as_float((unsigned)__shfl((int)ld.y, u, 8));
        }
        uint4 gp[8];
#pragma unroll
        for (int u = 0; u < 8; ++u) gp[u] = Gv[(size_t)rr[u] * 8 + sub];
#pragma unroll
        for (int u = 0; u < 8; ++u) {
            acc[0] = fmaf(wv[u], lo16(gp[u].x), acc[0]);
            acc[1] = fmaf(wv[u], hi16(gp[u].x), acc[1]);
            acc[2] = fmaf(wv[u], lo16(gp[u].y), acc[2]);
            acc[3] = fmaf(wv[u], hi16(gp[u].y), acc[3]);
            acc[4] = fmaf(wv[u], lo16(gp[u].z), acc[4]);
            acc[5] = fmaf(wv[u], hi16(gp[u].z), acc[5]);
            acc[6] = fmaf(wv[u], lo16(gp[u].w), acc[6]);
            acc[7] = fmaf(wv[u], hi16(gp[u].w), acc[7]);
        }
        ld = nld;
    }
}

// ---- agg1: acc -> relu/bias/dinv -> G2 ----
// (256,4): the (256,8) bound forces VGPR<=32 and spills gp[8] (round 7: 2.5x slower)
__global__ __launch_bounds__(256, 4) void agg1(const int* __restrict__ rp,
                                               const uint2* __restrict__ epack,
                                               const int* __restrict__ order,
                                               const uint4* __restrict__ G1v,
                                               const float* __restrict__ dinvp,
                                               const void* __restrict__ b1,
                                               const int* __restrict__ flags,
                                               uint4* __restrict__ G2v, int n) {
    const bool isbf = flags[0] != 0;
    const int sub = threadIdx.x & 7;
    const int g   = (blockIdx.x * 256 + threadIdx.x) >> 3;
    if (g >= n) return;
    const int node = order[g];

    float acc[8];
    gacc8(rp, epack, G1v, node, sub, acc);

    const float dv = dinvp[2 * (size_t)node];
    unsigned o[4];
#pragma unroll
    for (int t = 0; t < 4; ++t) {
        float h0 = dv * acc[2 * t]     + ldf(b1, 8 * sub + 2 * t, isbf);
        float h1 = dv * acc[2 * t + 1] + ldf(b1, 8 * sub + 2 * t + 1, isbf);
        h0 = h0 > 0.f ? h0 : 0.f;
        h1 = h1 > 0.f ? h1 : 0.f;
        o[t] = pack2(dv * h0, dv * h1);
    }
    nt_st4(&G2v[(size_t)node * 8 + sub], make_uint4(o[0], o[1], o[2], o[3]));
}

// ---- agg2out: gather (agg2) fused with out = T @ W2 + b2 (outgemm) ----
__global__ __launch_bounds__(256, 4) void agg2out(const int* __restrict__ rp,
                                                  const uint2* __restrict__ epack,
                                                  const int* __restrict__ order,
                                                  const uint4* __restrict__ G2v,
                                                  const float* __restrict__ dinvp,
                                                  const void* __restrict__ W2,
                                                  const void* __restrict__ b2,
                                                  const int* __restrict__ flags,
                                                  void* __restrict__ outp, int n) {
    const bool isbf = flags[0] != 0;
    __shared__ uint4 bfr[16 * 64];   // W2 fragments [ct*2+ks][lane], 16 KB
    __shared__ float b2s[128];
    __shared__ uint4 tls[32 * 8];    // 32 node-rows of bf16 T, 4 KB
    __shared__ int   nds[32];
    for (int idx = threadIdx.x; idx < 16 * 64; idx += 256) {
        int lane = idx & 63, fr = idx >> 6;
        int ct = fr >> 1, ks = fr & 1;
        int k0 = ks * 32 + (lane >> 4) * 8;
        int col = ct * 16 + (lane & 15);
        unsigned short h[8];
#pragma unroll
        for (int j = 0; j < 8; ++j)
            h[j] = f2bfbits(ldf(W2, (size_t)(k0 + j) * 128 + col, isbf));
        bfr[idx] = make_uint4((unsigned)h[0] | ((unsigned)h[1] << 16),
                              (unsigned)h[2] | ((unsigned)h[3] << 16),
                              (unsigned)h[4] | ((unsigned)h[5] << 16),
                              (unsigned)h[6] | ((unsigned)h[7] << 16));
    }
    for (int i = threadIdx.x; i < 128; i += 256) b2s[i] = ldf(b2, i, isbf);
    __syncthreads();

    const int sub  = threadIdx.x & 7;
    const int lg   = threadIdx.x >> 3;         // local node 0..31
    const int lane = threadIdx.x & 63;
    const int m = lane & 15, q = lane >> 4;
    const int wid = threadIdx.x >> 6;          // wave 0..3
    const int ntile = (n + 31) >> 5;

    for (int tile = blockIdx.x; tile < ntile; tile += gridDim.x) {
        const int g = tile * 32 + lg;
        uint4 o = make_uint4(0u, 0u, 0u, 0u);
        int node = 0;
        if (g < n) {                            // group-uniform (8 lanes share g)
            node = order[g];
            float acc[8];
            gacc8(rp, epack, G2v, node, sub, acc);
            const float dv = dinvp[2 * (size_t)node];
            o.x = pack2(dv * acc[0], dv * acc[1]);
            o.y = pack2(dv * acc[2], dv * acc[3]);
            o.z = pack2(dv * acc[4], dv * acc[5]);
            o.w = pack2(dv * acc[6], dv * acc[7]);
        }
        tls[lg * 8 + sub] = o;
        if (sub == 0) nds[lg] = node;
        __syncthreads();

        // MFMA epilogue: waves 0,1 -> rows [0,16), waves 2,3 -> rows [16,32)
        const int chunk = wid >> 1;
        const int lrow  = chunk * 16 + m;
        V8 a0, a1;
        a0.u = tls[lrow * 8 + q];
        a1.u = tls[lrow * 8 + 4 + q];
#pragma unroll
        for (int c8 = 0; c8 < 4; ++c8) {
            const int ct = (wid & 1) * 4 + c8;
            f32x4 acc4 = {0.f, 0.f, 0.f, 0.f};
            V8 b0; b0.u = bfr[(ct * 2 + 0) * 64 + lane];
            acc4 = __builtin_amdgcn_mfma_f32_16x16x32_bf16(a0.v, b0.v, acc4, 0, 0, 0);
            V8 b1; b1.u = bfr[(ct * 2 + 1) * 64 + lane];
            acc4 = __builtin_amdgcn_mfma_f32_16x16x32_bf16(a1.v, b1.v, acc4, 0, 0, 0);
            const int col = ct * 16 + m;
            const float bb = b2s[col];
#pragma unroll
            for (int r = 0; r < 4; ++r) {
                int lr = chunk * 16 + q * 4 + r;
                int gg = tile * 32 + lr;
                if (gg < n) {
                    float ov = acc4[r] + bb;
                    int nd = nds[lr];
                    if (isbf) ((bf16*)outp)[(size_t)nd * 128 + col] = __float2bfloat16(ov);
                    else      ((float*)outp)[(size_t)nd * 128 + col] = ov;
                }
            }
        }
        __syncthreads();   // protect tls/nds for next tile
    }
}

extern "C" void kernel_launch(void* const* d_in, const int* in_sizes, int n_in,
                              void* d_out, int out_size, void* d_ws, size_t ws_size,
                              hipStream_t stream) {
    const void* x  = d_in[0];
    const void* ei = d_in[1];
    const void* ew = d_in[2];
    const void* W1 = d_in[3];
    const void* b1 = d_in[4];
    const void* W2 = d_in[5];
    const void* b2 = d_in[6];

    const int n = in_sizes[0] / 128;   // 100000
    const int e = in_sizes[2];         // 1600000
    const int nb = (n + 1023) / 1024;

    // ws layout (4B words) -- identical footprint to the round-4 passing build:
    // flags(8) | dc(2n, u64) | rp(n+1) | cursor(n) | bsum(1024) | bsx(1024)
    // | pad | epack(2e) | G1/T(32n) | G2(32n)
    // aliases: hist = bsum+512, hcur = bsx+512, bcnt = bsx+256, bbase = bsum;
    //          order = cursor (dead in fastpath until sortk); stage = G1 region.
    int*   flags  = (int*)d_ws;
    unsigned long long* dc = (unsigned long long*)((int*)d_ws + 8);
    int*   rp     = (int*)d_ws + 8 + 2 * (size_t)n;
    int*   cursor = rp + n + 1;
    int*   bsum   = cursor + n;
    int*   bsx    = bsum + 1024;
    int*   hist   = bsum + 512;
    int*   hcur   = bsx + 512;
    int*   bcnt   = bsx + 256;
    int*   bbase  = bsum;                        // fastpath: scans don't use bsum
    int*   order  = cursor;                      // alias, valid post-fill
    size_t w_off  = (size_t)(8 + 4 * (size_t)n + 1 + 2048);
    w_off = (w_off + 3) & ~(size_t)3;            // 16B align
    uint2*    epack = (uint2*)((int*)d_ws + w_off);
    size_t g_off = w_off + 2 * (size_t)e;
    g_off = (g_off + 3) & ~(size_t)3;
    unsigned* G1 = (unsigned*)d_ws + g_off;      // 32n uints (bf16x2), 16B aligned
    unsigned* G2 = G1 + (size_t)n * 32;

    const float* dinvp = (const float*)dc;       // dinv at dinvp[2*node]
    uint2* stage = (uint2*)G1;                   // alias: G1+G2, dead until gemm1

    // bucket parameters: bucket = 2^k node range, beff buckets (<=256)
    int bs0 = (n + 255) / 256;
    int k = 0;
    while ((1 << k) < bs0) ++k;
    int beff = (n + (1 << k) - 1) >> k;          // <= 256
    int cap  = (int)((32 * (size_t)n) / (size_t)beff);   // stage records/bucket
    size_t mean = ((size_t)e + beff - 1) / beff;
    bool fastfill = (n <= (1 << 18)) && (k <= 12) &&
                    ((size_t)cap >= mean + mean / 2 + 1024);

    // gemm grid: ~1 chunk per wave, capped
    const int nchunk = (n + 15) >> 4;
    int ggrid = (nchunk + 3) / 4;
    if (ggrid > 2048) ggrid = 2048;
    if (ggrid < 192)  ggrid = 192;

    initk<<<fastfill ? 1 : (n + 255) / 256, 256, 0, stream>>>(
        dc, hist, bcnt, n, fastfill ? 0 : 1,
        (const unsigned*)W1, (const unsigned*)ei, flags);
    if (fastfill) {
        binA<<<(e + 4095) / 4096, 1024, 0, stream>>>(ei, ew, bcnt, stage, flags, e, n, k, cap);
        bscan<<<1, 256, 0, stream>>>(bcnt, bbase, rp, n, beff);
        degscanFill<<<beff, 1024, 0, stream>>>(stage, bcnt, bbase, dc, rp, hist,
                                               epack, n, k, cap);
    } else {
        degcnt<<<(e + 255) / 256, 256, 0, stream>>>(ei, ew, dc, flags, e, n);
        scan1<<<nb, 1024, 0, stream>>>(dc, rp, bsum, n);
        scan2<<<1, 1024, 0, stream>>>(bsum, bsx, nb);
        scan3<<<nb, 1024, 0, stream>>>(rp, cursor, bsx, dc, hist, n, e);
        fill<<<(e + 255) / 256, 256, 0, stream>>>(ei, ew, cursor, epack, flags, e, n);
    }
    hscan<<<1, 256, 0, stream>>>(hist, hcur);
    sortk<<<nb, 1024, 0, stream>>>(dc, hcur, order, n);

    gemm1_mfma<<<ggrid, 256, 0, stream>>>(x, W1, dinvp, flags, (unsigned short*)G1, n);
    agg1<<<(n * 8 + 255) / 256, 256, 0, stream>>>(rp, epack, order, (const uint4*)G1,
                                                  dinvp, b1, flags, (uint4*)G2, n);
    int a2grid = (n + 31) / 32;
    if (a2grid > 1024) a2grid = 1024;            // grid-stride: stage W2 once/block
    agg2out<<<a2grid, 256, 0, stream>>>(rp, epack, order, (const uint4*)G2,
                                        dinvp, W2, b2, flags, d_out, n);
}

// Round 13
// 327.707 us; speedup vs baseline: 1.6970x; 1.0136x over previous
//
#include <hip/hip_runtime.h>
#include <hip/hip_bf16.h>

typedef __hip_bfloat16 bf16;
typedef __attribute__((ext_vector_type(8))) short short8;
typedef __attribute__((ext_vector_type(4))) float f32x4;
typedef __attribute__((ext_vector_type(2))) unsigned uv2;   // nontemporal-compatible
typedef __attribute__((ext_vector_type(4))) unsigned uv4;   // nontemporal-compatible
union V8 { uint4 u; short8 v; };

__device__ __forceinline__ float bf2f(bf16 v) { return __bfloat162float(v); }
__device__ __forceinline__ float lo16(unsigned u) { return __uint_as_float((u & 0xffffu) << 16); }
__device__ __forceinline__ float hi16(unsigned u) { return __uint_as_float(u & 0xffff0000u); }
__device__ __forceinline__ unsigned short f2bfbits(float f) {
    return (unsigned short)(__hip_bfloat16_raw(__float2bfloat16(f)).x);
}
__device__ __forceinline__ unsigned pack2(float a, float b) {
    return (unsigned)f2bfbits(a) | ((unsigned)f2bfbits(b) << 16);
}

// dtype-dispatching loads (flag-driven, uniform branch)
__device__ __forceinline__ float ldf(const void* p, size_t i, bool isbf) {
    return isbf ? bf2f(((const bf16*)p)[i]) : ((const float*)p)[i];
}
__device__ __forceinline__ int ldi(const void* p, size_t i, bool is64) {
    return is64 ? (int)((const long long*)p)[i] : ((const int*)p)[i];
}
__device__ __forceinline__ float sane(float v) {
    return (v == v && fabsf(v) < 1e30f) ? v : 0.f;
}

// nontemporal helpers over HIP vector structs
__device__ __forceinline__ uint2 nt_ld2(const uint2* p) {
    uv2 v = __builtin_nontemporal_load((const uv2*)p);
    return make_uint2(v.x, v.y);
}
__device__ __forceinline__ void nt_st4(uint4* p, uint4 v) {
    uv4 t; t.x = v.x; t.y = v.y; t.z = v.z; t.w = v.w;
    __builtin_nontemporal_store(t, (uv4*)p);
}

// dc[node] packed layout (built by degscanFill / legacy degcnt):
//   bits [44:63] : in-degree count (20 bits)
//   bits [ 0:43] : weighted degree, 22.22 unsigned fixed point
// After degscanFill/scan3:
//   bits [44:63] : in-degree count (still valid, for sortk)
//   bits [ 0:31] : dinv as f32 bits  -> readable as ((const float*)dc)[2*node]
#define DC_CNT_SHIFT 44
#define DC_FIX_MASK  0xFFFFFFFFFFFULL
#define DC_FIX_SCALE 4194304.0f   /* 2^22 */

// ---------------- init (+ fused dtype detection in block 0) ----------------
// In the fastpath initdc==0 -> launched with ONE block (only hist/bcnt/detect).
__global__ void initk(unsigned long long* __restrict__ dc, int* __restrict__ hist,
                      int* __restrict__ bcnt, int n, int initdc,
                      const unsigned* __restrict__ w1w, const unsigned* __restrict__ eiw,
                      int* __restrict__ flags) {
    int i = blockIdx.x * blockDim.x + threadIdx.x;
    if (initdc && i < n) dc[i] = (unsigned long long)(1u << 22);  // deg = 1.0
    if (i < 256) { hist[i] = 0; bcnt[i] = 0; }
    if (blockIdx.x == 0) {
        __shared__ int cnt[2];
        if (threadIdx.x < 2) cnt[threadIdx.x] = 0;
        __syncthreads();
        int c0 = 0;
        for (int j = threadIdx.x; j < 4096; j += 256) {
            unsigned u = w1w[j];
            unsigned e0 = (u >> 7) & 0xFFu, e1 = (u >> 23) & 0xFFu;
            if (e0 <= 125u && e1 <= 125u) c0++;
        }
        int c1 = 0;
        for (int j = threadIdx.x; j < 2048; j += 256)
            if (eiw[2 * j + 1] == 0u) c1++;
        atomicAdd(&cnt[0], c0);
        atomicAdd(&cnt[1], c1);
        __syncthreads();
        if (threadIdx.x == 0) {
            flags[0] = (cnt[0] >= 3072) ? 1 : 0;
            flags[1] = (cnt[1] >= 1024) ? 1 : 0;
        }
    }
}

// ------------- legacy degcnt (fallback path only): one u64 atomic/edge -------
__global__ void degcnt(const void* __restrict__ ei, const void* __restrict__ w,
                       unsigned long long* __restrict__ dc,
                       const int* __restrict__ flags, int e, int n) {
    const bool isbf = flags[0] != 0;
    const bool is64 = flags[1] != 0;
    int i = blockIdx.x * blockDim.x + threadIdx.x;
    if (i < e) {
        int c = ldi(ei, (size_t)e + i, is64);
        if ((unsigned)c < (unsigned)n) {
            float wv = sane(ldf(w, i, isbf));
            wv = fminf(fmaxf(wv, 0.f), 1024.f);   // keep fixed-point in range
            unsigned long long pk = (1ULL << DC_CNT_SHIFT)
                                  + (unsigned long long)llrintf(wv * DC_FIX_SCALE);
            atomicAdd(&dc[c], pk);
        }
    }
}

// ---------------- binA: bin edges by node-bucket, LDS-reordered flush --------
// Round-13 A/B: the round-11 "direct scatter" wrote 8B records at random
// bucket frontiers from all 8 XCDs -> partial-line writebacks (~64B/record,
// ~100MB, the original `fill` pathology). This restores the round-10 flush:
// records grouped by bucket in LDS, then written as contiguous runs ->
// full-line writebacks (~14MB). Target addressing stays cap-based.
__global__ __launch_bounds__(1024) void binA(const void* __restrict__ ei,
                                             const void* __restrict__ w,
                                             int* __restrict__ bcnt,
                                             uint2* __restrict__ stage,
                                             const int* __restrict__ flags,
                                             int e, int n, int k, int cap) {
    __shared__ uint2 recs[4096];
    __shared__ unsigned tgt[4096];
    __shared__ int lh[256], loff[256], lbase[256];
    const bool isbf = flags[0] != 0;
    const bool is64 = flags[1] != 0;
    const int t = threadIdx.x;
    if (t < 256) lh[t] = 0;
    __syncthreads();

    int b_[4], lr_[4], valid_[4];
    uint2 rec_[4];
    const int base = blockIdx.x * 4096;
#pragma unroll
    for (int u = 0; u < 4; ++u) {
        int i = base + u * 1024 + t;
        valid_[u] = 0;
        if (i < e) {
            int r = ldi(ei, (size_t)i, is64);
            int c = ldi(ei, (size_t)e + i, is64);
            if ((unsigned)c < (unsigned)n) {
                bool rv = (unsigned)r < (unsigned)n;
                float wv = rv ? sane(ldf(w, i, isbf)) : 0.f;
                int b = c >> k;
                unsigned cloc = (unsigned)(c - (b << k));
                rec_[u] = make_uint2((cloc << 20) | (rv ? (unsigned)r : 0u),
                                     __float_as_uint(wv));
                b_[u] = b;
                lr_[u] = atomicAdd(&lh[b], 1);
                valid_[u] = 1;
            }
        }
    }
    __syncthreads();

    // exclusive scan of lh -> loff; reserve per-bucket global ranges
    if (t < 256) loff[t] = lh[t];
    __syncthreads();
    for (int off = 1; off < 256; off <<= 1) {
        int v = 0;
        if (t < 256 && t >= off) v = loff[t - off];
        __syncthreads();
        if (t < 256 && t >= off) loff[t] += v;
        __syncthreads();
    }
    if (t < 256) {
        int c = lh[t];
        loff[t] -= c;  // inclusive -> exclusive
        lbase[t] = (c > 0) ? atomicAdd(&bcnt[t], c) : 0;
    }
    __syncthreads();

    // place records grouped by bucket in LDS; remember global target
#pragma unroll
    for (int u = 0; u < 4; ++u)
        if (valid_[u]) {
            int slot = loff[b_[u]] + lr_[u];
            recs[slot] = rec_[u];
            unsigned gi = (unsigned)(lbase[b_[u]] + lr_[u]);
            tgt[slot] = (gi < (unsigned)cap)
                          ? (unsigned)((size_t)b_[u] * cap + gi)
                          : 0xFFFFFFFFu;   // clamp: drop on (impossible) overflow
        }
    __syncthreads();

    // flush: consecutive slots within a bucket-run -> consecutive global addrs
    const int total = loff[255] + lh[255];
    for (int s = t; s < total; s += 1024) {
        unsigned g = tgt[s];
        if (g != 0xFFFFFFFFu) stage[g] = recs[s];
    }
}

// ---------------- bscan: bucket-level exclusive scan (1 block) ---------------
__global__ void bscan(const int* __restrict__ bcnt, int* __restrict__ bbase,
                      int* __restrict__ rp, int n, int beff) {
    __shared__ int s[256];
    const int t = threadIdx.x;
    int v = (t < beff) ? bcnt[t] : 0;
    s[t] = v;
    __syncthreads();
    for (int off = 1; off < 256; off <<= 1) {
        int x = 0;
        if (t >= off) x = s[t - off];
        __syncthreads();
        if (t >= off) s[t] += x;
        __syncthreads();
    }
    bbase[t] = s[t] - v;
    if (t == 255) rp[n] = s[255];
}

// ---- degscanFill: per-bucket count+degree + local prefix -> rp/dinv/hist,
// then CSR placement in the same kernel. ncur aliases dcl (race-free: all
// dcl reads complete before the prefix-scan barriers).
__global__ __launch_bounds__(1024) void degscanFill(const uint2* __restrict__ stage,
                                                    const int* __restrict__ bcnt,
                                                    const int* __restrict__ bbase,
                                                    unsigned long long* __restrict__ dc,
                                                    int* __restrict__ rp,
                                                    int* __restrict__ hist,
                                                    uint2* __restrict__ epack,
                                                    int n, int k, int cap) {
    __shared__ unsigned long long dcl[4096];
    __shared__ int pfx[1024];
    __shared__ int lh[256];
    const int b  = blockIdx.x;
    const int lo = b << k;
    const int hi = min(n, lo + (1 << k));
    const int bs = hi - lo;
    const int t  = threadIdx.x;
    if (t < 256) lh[t] = 0;
    for (int j = t; j < bs; j += 1024)
        dcl[j] = (unsigned long long)(1u << 22);   // self-loop: deg = 1.0
    __syncthreads();
    const uint2* sb = stage + (size_t)b * cap;
    const int cnt_b = min(bcnt[b], cap);
    for (int s = t; s < cnt_b; s += 1024) {
        uint2 rec = sb[s];
        int cloc  = (int)(rec.x >> 20);
        float wv  = __uint_as_float(rec.y);
        wv = fminf(fmaxf(wv, 0.f), 1024.f);
        unsigned long long pk = (1ULL << DC_CNT_SHIFT)
                              + (unsigned long long)llrintf(wv * DC_FIX_SCALE);
        atomicAdd(&dcl[cloc], pk);                 // LDS atomic, intra-CU
    }
    __syncthreads();

    // per-node: cnt, dinv pack, hist; thread-local sums for prefix scan
    int c[4];
    int lsum = 0;
    const int j0 = 4 * t;
#pragma unroll
    for (int i2 = 0; i2 < 4; ++i2) {
        int j = j0 + i2;
        int cv = 0;
        if (j < bs) {
            unsigned long long dv = dcl[j];
            cv = (int)(dv >> DC_CNT_SHIFT);
            float d  = (float)(dv & DC_FIX_MASK) * (1.0f / DC_FIX_SCALE);
            float di = d > 0.f ? rsqrtf(d) : 0.f;
            dc[lo + j] = (dv & ~DC_FIX_MASK) | (unsigned long long)__float_as_uint(di);
            atomicAdd(&lh[min(cv, 255)], 1);
        }
        c[i2] = cv;
        lsum += cv;
    }
    pfx[t] = lsum;
    __syncthreads();                 // <- after this, no thread reads dcl again
    for (int off = 1; off < 1024; off <<= 1) {
        int v = 0;
        if (t >= off) v = pfx[t - off];
        __syncthreads();
        if (t >= off) pfx[t] += v;
        __syncthreads();
    }
    int run = bbase[b] + pfx[t] - lsum;   // exclusive prefix for node j0
    int* ncur = (int*)dcl;                // safe alias (see header comment)
#pragma unroll
    for (int i2 = 0; i2 < 4; ++i2) {
        int j = j0 + i2;
        if (j < bs) { rp[lo + j] = run; ncur[j] = run; }
        run += c[i2];
    }
    __syncthreads();
    if (t < 256) {
        int cc = lh[t];
        if (cc > 0) atomicAdd(&hist[t], cc);       // one global atomic per bin
    }
    // placement phase (old fillB): stage slice is L2-hot from the count pass
    for (int s = t; s < cnt_b; s += 1024) {
        uint2 rec = sb[s];
        int cloc  = (int)(rec.x >> 20);
        unsigned r = rec.x & 0xFFFFFu;
        int pos = atomicAdd(&ncur[cloc], 1);
        epack[pos] = make_uint2(r, rec.y);
    }
}

// ---------------- scans (fallback path only) ----------------
__global__ __launch_bounds__(1024) void scan1(const unsigned long long* __restrict__ dc,
                                              int* __restrict__ rp,
                                              int* __restrict__ bsum, int n) {
    __shared__ int s[1024];
    int gid = blockIdx.x * 1024 + threadIdx.x;
    int v = (gid < n) ? (int)(((const unsigned*)dc)[2 * (size_t)gid + 1] >> (DC_CNT_SHIFT - 32)) : 0;
    s[threadIdx.x] = v;
    __syncthreads();
    for (int off = 1; off < 1024; off <<= 1) {
        int t = 0;
        if (threadIdx.x >= off) t = s[threadIdx.x - off];
        __syncthreads();
        if (threadIdx.x >= off) s[threadIdx.x] += t;
        __syncthreads();
    }
    if (gid < n) rp[gid] = s[threadIdx.x] - v;
    if (threadIdx.x == 1023) bsum[blockIdx.x] = s[1023];
}

__global__ __launch_bounds__(1024) void scan2(const int* __restrict__ bsum,
                                              int* __restrict__ bsx, int nb) {
    __shared__ int s[1024];
    int v = (threadIdx.x < nb) ? bsum[threadIdx.x] : 0;
    s[threadIdx.x] = v;
    __syncthreads();
    for (int off = 1; off < 1024; off <<= 1) {
        int t = 0;
        if (threadIdx.x >= off) t = s[threadIdx.x - off];
        __syncthreads();
        if (threadIdx.x >= off) s[threadIdx.x] += t;
        __syncthreads();
    }
    if (threadIdx.x < nb) bsx[threadIdx.x] = s[threadIdx.x] - v;
}

__global__ __launch_bounds__(1024) void scan3(int* __restrict__ rp, int* __restrict__ cursor,
                                              const int* __restrict__ bsx,
                                              unsigned long long* __restrict__ dc,
                                              int* __restrict__ hist,
                                              int n, int e) {
    __shared__ int lh[256];
    const int t = threadIdx.x;
    if (t < 256) lh[t] = 0;
    __syncthreads();
    int i = blockIdx.x * 1024 + t;
    if (i < n) {
        int v = rp[i] + bsx[i >> 10];
        rp[i] = v;
        cursor[i] = v;
        unsigned long long dv = dc[i];
        int c = (int)(dv >> DC_CNT_SHIFT);
        float d = (float)(dv & DC_FIX_MASK) * (1.0f / DC_FIX_SCALE);
        float di = d > 0.f ? rsqrtf(d) : 0.f;
        dc[i] = (dv & ~DC_FIX_MASK) | (unsigned long long)__float_as_uint(di);
        atomicAdd(&lh[min(c, 255)], 1);
    }
    __syncthreads();
    if (t < 256) {
        int c = lh[t];
        if (c > 0) atomicAdd(&hist[t], c);
    }
    if (i == 0) rp[n] = e;
}

// ---------------- fill CSR: legacy one-pass fallback ----------------
__global__ void fill(const void* __restrict__ ei, const void* __restrict__ w,
                     int* __restrict__ cursor, uint2* __restrict__ epack,
                     const int* __restrict__ flags, int e, int n) {
    const bool isbf = flags[0] != 0;
    const bool is64 = flags[1] != 0;
    int i = blockIdx.x * blockDim.x + threadIdx.x;
    if (i < e) {
        int r = ldi(ei, (size_t)i, is64);
        int c = ldi(ei, (size_t)e + i, is64);
        if ((unsigned)c < (unsigned)n) {
            bool rv = (unsigned)r < (unsigned)n;
            float wv = rv ? sane(ldf(w, i, isbf)) : 0.f;
            int pos = atomicAdd(&cursor[c], 1);
            epack[pos] = make_uint2(rv ? (unsigned)r : 0u, __float_as_uint(wv));
        }
    }
}

// ---------------- degree-bucket scan ----------------
__global__ void hscan(const int* __restrict__ hist, int* __restrict__ hcur) {
    __shared__ int s[256];
    int v = hist[threadIdx.x];
    s[threadIdx.x] = v;
    __syncthreads();
    for (int off = 1; off < 256; off <<= 1) {
        int t = 0;
        if (threadIdx.x >= off) t = s[threadIdx.x - off];
        __syncthreads();
        if (threadIdx.x >= off) s[threadIdx.x] += t;
        __syncthreads();
    }
    hcur[threadIdx.x] = s[threadIdx.x] - v;  // exclusive
}

// ---------------- counting-sort placement, block-aggregated ----------------
__global__ __launch_bounds__(1024) void sortk(const unsigned long long* __restrict__ dc,
                                              int* __restrict__ hcur,
                                              int* __restrict__ order, int n) {
    __shared__ int lh[256];     // local histogram
    __shared__ int lbase[256];  // global base per bin for this block
    const int t = threadIdx.x;
    for (int b = t; b < 256; b += 1024) lh[b] = 0;
    __syncthreads();
    const int i = blockIdx.x * 1024 + t;
    int b = 0, lrank = 0;
    if (i < n) {
        b = min((int)(dc[i] >> DC_CNT_SHIFT), 255);
        lrank = atomicAdd(&lh[b], 1);  // LDS atomic: intra-block rank
    }
    __syncthreads();
    for (int bb = t; bb < 256; bb += 1024) {
        int c = lh[bb];
        lbase[bb] = (c > 0) ? atomicAdd(&hcur[bb], c) : 0;  // range reservation
    }
    __syncthreads();
    if (i < n) order[lbase[b] + lrank] = i;
}

// ---- layer1 GEMM via MFMA: G1 = bf16(dinv ⊙ (X[n,128] @ W1[128,64])) ----
__global__ __launch_bounds__(256) void gemm1_mfma(const void* __restrict__ x,
                                                  const void* __restrict__ W1,
                                                  const float* __restrict__ dinvp,
                                                  const int* __restrict__ flags,
                                                  unsigned short* __restrict__ G1,
                                                  int n) {
    const bool isbf = flags[0] != 0;
    __shared__ uint4 bfr[16 * 64];  // [ct*4+ks][lane], 16 KB
    for (int idx = threadIdx.x; idx < 16 * 64; idx += 256) {
        int lane = idx & 63, fr = idx >> 6;
        int ct = fr >> 2, ks = fr & 3;
        int k0 = ks * 32 + (lane >> 4) * 8;
        int col = ct * 16 + (lane & 15);
        unsigned short h[8];
#pragma unroll
        for (int j = 0; j < 8; ++j)
            h[j] = f2bfbits(ldf(W1, (size_t)(k0 + j) * 64 + col, isbf));
        bfr[idx] = make_uint4((unsigned)h[0] | ((unsigned)h[1] << 16),
                              (unsigned)h[2] | ((unsigned)h[3] << 16),
                              (unsigned)h[4] | ((unsigned)h[5] << 16),
                              (unsigned)h[6] | ((unsigned)h[7] << 16));
    }
    __syncthreads();

    const int lane = threadIdx.x & 63;
    const int m = lane & 15, q = lane >> 4;
    const int wid = (blockIdx.x * 256 + threadIdx.x) >> 6;
    const int nw  = (gridDim.x * 256) >> 6;
    const int nchunk = (n + 15) >> 4;

    for (int ch = wid; ch < nchunk; ch += nw) {
        const int row0 = ch * 16;
        const int rA = min(row0 + m, n - 1);
        V8 a[4];
        if (isbf) {
            const uint4* xr = (const uint4*)((const bf16*)x + (size_t)rA * 128);
#pragma unroll
            for (int ks = 0; ks < 4; ++ks) a[ks].u = xr[ks * 4 + q];
        } else {
            const float4* xr4 = (const float4*)((const float*)x + (size_t)rA * 128);
#pragma unroll
            for (int ks = 0; ks < 4; ++ks) {
                float4 v0 = xr4[ks * 8 + q * 2];
                float4 v1 = xr4[ks * 8 + q * 2 + 1];
                a[ks].u = make_uint4(pack2(v0.x, v0.y), pack2(v0.z, v0.w),
                                     pack2(v1.x, v1.y), pack2(v1.z, v1.w));
            }
        }
#pragma unroll
        for (int ct = 0; ct < 4; ++ct) {
            f32x4 acc = {0.f, 0.f, 0.f, 0.f};
#pragma unroll
            for (int ks = 0; ks < 4; ++ks) {
                V8 b; b.u = bfr[(ct * 4 + ks) * 64 + lane];
                acc = __builtin_amdgcn_mfma_f32_16x16x32_bf16(a[ks].v, b.v, acc, 0, 0, 0);
            }
#pragma unroll
            for (int r = 0; r < 4; ++r) {
                int row = row0 + q * 4 + r;
                if (row < n)
                    G1[(size_t)row * 64 + ct * 16 + m] = f2bfbits(dinvp[2 * (size_t)row] * acc[r]);
            }
        }
    }
}

// ---- gather core: 8 lanes/node, uint4/lane, depth-8 + epack prefetch ----
__device__ __forceinline__ void gacc8(const int* __restrict__ rp,
                                      const uint2* __restrict__ epack,
                                      const uint4* __restrict__ Gv,
                                      int node, int sub, float acc[8]) {
    uint4 self = Gv[(size_t)node * 8 + sub];
    acc[0] = lo16(self.x); acc[1] = hi16(self.x);
    acc[2] = lo16(self.y); acc[3] = hi16(self.y);
    acc[4] = lo16(self.z); acc[5] = hi16(self.z);
    acc[6] = lo16(self.w); acc[7] = hi16(self.w);

    const int s0 = rp[node], s1 = rp[node + 1];
    const uint2 fb = make_uint2((unsigned)node, 0u);
    int idx = s0 + sub;
    uint2 ld = (idx < s1) ? nt_ld2(&epack[idx]) : fb;
    for (int base = s0; base < s1; base += 8) {
        int nidx = base + 8 + sub;
        uint2 nld = (nidx < s1) ? nt_ld2(&epack[nidx]) : fb;  // prefetch next batch
        int rr[8]; float wv[8];
#pragma unroll
        for (int u = 0; u < 8; ++u) {
            rr[u] = __shfl((int)ld.x, u, 8);
            wv[u] = __uint_as_float((unsigned)__shfl((int)ld.y, u, 8));
        }
        uint4 gp[8];
#pragma unroll
        for (int u = 0; u < 8; ++u) gp[u] = Gv[(size_t)rr[u] * 8 + sub];
#pragma unroll
        for (int u = 0; u < 8; ++u) {
            acc[0] = fmaf(wv[u], lo16(gp[u].x), acc[0]);
            acc[1] = fmaf(wv[u], hi16(gp[u].x), acc[1]);
            acc[2] = fmaf(wv[u], lo16(gp[u].y), acc[2]);
            acc[3] = fmaf(wv[u], hi16(gp[u].y), acc[3]);
            acc[4] = fmaf(wv[u], lo16(gp[u].z), acc[4]);
            acc[5] = fmaf(wv[u], hi16(gp[u].z), acc[5]);
            acc[6] = fmaf(wv[u], lo16(gp[u].w), acc[6]);
            acc[7] = fmaf(wv[u], hi16(gp[u].w), acc[7]);
        }
        ld = nld;
    }
}

// ---- agg1: acc -> relu/bias/dinv -> G2 ----
// (256,4): the (256,8) bound forces VGPR<=32 and spills gp[8] (round 7: 2.5x slower)
__global__ __launch_bounds__(256, 4) void agg1(const int* __restrict__ rp,
                                               const uint2* __restrict__ epack,
                                               const int* __restrict__ order,
                                               const uint4* __restrict__ G1v,
                                               const float* __restrict__ dinvp,
                                               const void* __restrict__ b1,
                                               const int* __restrict__ flags,
                                               uint4* __restrict__ G2v, int n) {
    const bool isbf = flags[0] != 0;
    const int sub = threadIdx.x & 7;
    const int g   = (blockIdx.x * 256 + threadIdx.x) >> 3;
    if (g >= n) return;
    const int node = order[g];

    float acc[8];
    gacc8(rp, epack, G1v, node, sub, acc);

    const float dv = dinvp[2 * (size_t)node];
    unsigned o[4];
#pragma unroll
    for (int t = 0; t < 4; ++t) {
        float h0 = dv * acc[2 * t]     + ldf(b1, 8 * sub + 2 * t, isbf);
        float h1 = dv * acc[2 * t + 1] + ldf(b1, 8 * sub + 2 * t + 1, isbf);
        h0 = h0 > 0.f ? h0 : 0.f;
        h1 = h1 > 0.f ? h1 : 0.f;
        o[t] = pack2(dv * h0, dv * h1);
    }
    nt_st4(&G2v[(size_t)node * 8 + sub], make_uint4(o[0], o[1], o[2], o[3]));
}

// ---- agg2out: gather (agg2) fused with out = T @ W2 + b2 (outgemm) ----
__global__ __launch_bounds__(256, 4) void agg2out(const int* __restrict__ rp,
                                                  const uint2* __restrict__ epack,
                                                  const int* __restrict__ order,
                                                  const uint4* __restrict__ G2v,
                                                  const float* __restrict__ dinvp,
                                                  const void* __restrict__ W2,
                                                  const void* __restrict__ b2,
                                                  const int* __restrict__ flags,
                                                  void* __restrict__ outp, int n) {
    const bool isbf = flags[0] != 0;
    __shared__ uint4 bfr[16 * 64];   // W2 fragments [ct*2+ks][lane], 16 KB
    __shared__ float b2s[128];
    __shared__ uint4 tls[32 * 8];    // 32 node-rows of bf16 T, 4 KB
    __shared__ int   nds[32];
    for (int idx = threadIdx.x; idx < 16 * 64; idx += 256) {
        int lane = idx & 63, fr = idx >> 6;
        int ct = fr >> 1, ks = fr & 1;
        int k0 = ks * 32 + (lane >> 4) * 8;
        int col = ct * 16 + (lane & 15);
        unsigned short h[8];
#pragma unroll
        for (int j = 0; j < 8; ++j)
            h[j] = f2bfbits(ldf(W2, (size_t)(k0 + j) * 128 + col, isbf));
        bfr[idx] = make_uint4((unsigned)h[0] | ((unsigned)h[1] << 16),
                              (unsigned)h[2] | ((unsigned)h[3] << 16),
                              (unsigned)h[4] | ((unsigned)h[5] << 16),
                              (unsigned)h[6] | ((unsigned)h[7] << 16));
    }
    for (int i = threadIdx.x; i < 128; i += 256) b2s[i] = ldf(b2, i, isbf);
    __syncthreads();

    const int sub  = threadIdx.x & 7;
    const int lg   = threadIdx.x >> 3;         // local node 0..31
    const int lane = threadIdx.x & 63;
    const int m = lane & 15, q = lane >> 4;
    const int wid = threadIdx.x >> 6;          // wave 0..3
    const int ntile = (n + 31) >> 5;

    for (int tile = blockIdx.x; tile < ntile; tile += gridDim.x) {
        const int g = tile * 32 + lg;
        uint4 o = make_uint4(0u, 0u, 0u, 0u);
        int node = 0;
        if (g < n) {                            // group-uniform (8 lanes share g)
            node = order[g];
            float acc[8];
            gacc8(rp, epack, G2v, node, sub, acc);
            const float dv = dinvp[2 * (size_t)node];
            o.x = pack2(dv * acc[0], dv * acc[1]);
            o.y = pack2(dv * acc[2], dv * acc[3]);
            o.z = pack2(dv * acc[4], dv * acc[5]);
            o.w = pack2(dv * acc[6], dv * acc[7]);
        }
        tls[lg * 8 + sub] = o;
        if (sub == 0) nds[lg] = node;
        __syncthreads();

        // MFMA epilogue: waves 0,1 -> rows [0,16), waves 2,3 -> rows [16,32)
        const int chunk = wid >> 1;
        const int lrow  = chunk * 16 + m;
        V8 a0, a1;
        a0.u = tls[lrow * 8 + q];
        a1.u = tls[lrow * 8 + 4 + q];
#pragma unroll
        for (int c8 = 0; c8 < 4; ++c8) {
            const int ct = (wid & 1) * 4 + c8;
            f32x4 acc4 = {0.f, 0.f, 0.f, 0.f};
            V8 b0; b0.u = bfr[(ct * 2 + 0) * 64 + lane];
            acc4 = __builtin_amdgcn_mfma_f32_16x16x32_bf16(a0.v, b0.v, acc4, 0, 0, 0);
            V8 b1; b1.u = bfr[(ct * 2 + 1) * 64 + lane];
            acc4 = __builtin_amdgcn_mfma_f32_16x16x32_bf16(a1.v, b1.v, acc4, 0, 0, 0);
            const int col = ct * 16 + m;
            const float bb = b2s[col];
#pragma unroll
            for (int r = 0; r < 4; ++r) {
                int lr = chunk * 16 + q * 4 + r;
                int gg = tile * 32 + lr;
                if (gg < n) {
                    float ov = acc4[r] + bb;
                    int nd = nds[lr];
                    if (isbf) ((bf16*)outp)[(size_t)nd * 128 + col] = __float2bfloat16(ov);
                    else      ((float*)outp)[(size_t)nd * 128 + col] = ov;
                }
            }
        }
        __syncthreads();   // protect tls/nds for next tile
    }
}

extern "C" void kernel_launch(void* const* d_in, const int* in_sizes, int n_in,
                              void* d_out, int out_size, void* d_ws, size_t ws_size,
                              hipStream_t stream) {
    const void* x  = d_in[0];
    const void* ei = d_in[1];
    const void* ew = d_in[2];
    const void* W1 = d_in[3];
    const void* b1 = d_in[4];
    const void* W2 = d_in[5];
    const void* b2 = d_in[6];

    const int n = in_sizes[0] / 128;   // 100000
    const int e = in_sizes[2];         // 1600000
    const int nb = (n + 1023) / 1024;

    // ws layout (4B words) -- identical footprint to the round-4 passing build:
    // flags(8) | dc(2n, u64) | rp(n+1) | cursor(n) | bsum(1024) | bsx(1024)
    // | pad | epack(2e) | G1/T(32n) | G2(32n)
    // aliases: hist = bsum+512, hcur = bsx+512, bcnt = bsx+256, bbase = bsum;
    //          order = cursor; stage = G1 region (G1+G2, dead until gemm1).
    int*   flags  = (int*)d_ws;
    unsigned long long* dc = (unsigned long long*)((int*)d_ws + 8);
    int*   rp     = (int*)d_ws + 8 + 2 * (size_t)n;
    int*   cursor = rp + n + 1;
    int*   bsum   = cursor + n;
    int*   bsx    = bsum + 1024;
    int*   hist   = bsum + 512;
    int*   hcur   = bsx + 512;
    int*   bcnt   = bsx + 256;
    int*   bbase  = bsum;                        // fastpath: scans don't use bsum
    int*   order  = cursor;                      // alias, valid post-fill
    size_t w_off  = (size_t)(8 + 4 * (size_t)n + 1 + 2048);
    w_off = (w_off + 3) & ~(size_t)3;            // 16B align
    uint2*    epack = (uint2*)((int*)d_ws + w_off);
    size_t g_off = w_off + 2 * (size_t)e;
    g_off = (g_off + 3) & ~(size_t)3;
    unsigned* G1 = (unsigned*)d_ws + g_off;      // 32n uints (bf16x2), 16B aligned
    unsigned* G2 = G1 + (size_t)n * 32;

    const float* dinvp = (const float*)dc;       // dinv at dinvp[2*node]
    uint2* stage = (uint2*)G1;                   // alias: G1+G2, dead until gemm1

    // bucket parameters: bucket = 2^k node range, beff buckets (<=256)
    int bs0 = (n + 255) / 256;
    int k = 0;
    while ((1 << k) < bs0) ++k;
    int beff = (n + (1 << k) - 1) >> k;          // <= 256
    int cap  = (int)((32 * (size_t)n) / (size_t)beff);   // stage records/bucket
    size_t mean = ((size_t)e + beff - 1) / beff;
    bool fastfill = (n <= (1 << 18)) && (k <= 12) &&
                    ((size_t)cap >= mean + mean / 2 + 1024);

    // gemm grid: ~1 chunk per wave, capped
    const int nchunk = (n + 15) >> 4;
    int ggrid = (nchunk + 3) / 4;
    if (ggrid > 2048) ggrid = 2048;
    if (ggrid < 192)  ggrid = 192;

    initk<<<fastfill ? 1 : (n + 255) / 256, 256, 0, stream>>>(
        dc, hist, bcnt, n, fastfill ? 0 : 1,
        (const unsigned*)W1, (const unsigned*)ei, flags);
    if (fastfill) {
        binA<<<(e + 4095) / 4096, 1024, 0, stream>>>(ei, ew, bcnt, stage, flags, e, n, k, cap);
        bscan<<<1, 256, 0, stream>>>(bcnt, bbase, rp, n, beff);
        degscanFill<<<beff, 1024, 0, stream>>>(stage, bcnt, bbase, dc, rp, hist,
                                               epack, n, k, cap);
    } else {
        degcnt<<<(e + 255) / 256, 256, 0, stream>>>(ei, ew, dc, flags, e, n);
        scan1<<<nb, 1024, 0, stream>>>(dc, rp, bsum, n);
        scan2<<<1, 1024, 0, stream>>>(bsum, bsx, nb);
        scan3<<<nb, 1024, 0, stream>>>(rp, cursor, bsx, dc, hist, n, e);
        fill<<<(e + 255) / 256, 256, 0, stream>>>(ei, ew, cursor, epack, flags, e, n);
    }
    hscan<<<1, 256, 0, stream>>>(hist, hcur);
    sortk<<<nb, 1024, 0, stream>>>(dc, hcur, order, n);

    gemm1_mfma<<<ggrid, 256, 0, stream>>>(x, W1, dinvp, flags, (unsigned short*)G1, n);
    agg1<<<(n * 8 + 255) / 256, 256, 0, stream>>>(rp, epack, order, (const uint4*)G1,
                                                  dinvp, b1, flags, (uint4*)G2, n);
    int a2grid = (n + 31) / 32;
    if (a2grid > 1024) a2grid = 1024;            // grid-stride: stage W2 once/block
    agg2out<<<a2grid, 256, 0, stream>>>(rp, epack, order, (const uint4*)G2,
                                        dinvp, W2, b2, flags, d_out, n);
}